// Round 6
// baseline (2200.340 us; speedup 1.0000x reference)
//
#include <hip/hip_runtime.h>

#define NU 100000
#define NM 50000

__device__ __forceinline__ float bcastf(float v, int lane) {
  return __int_as_float(__builtin_amdgcn_readlane(__float_as_int(v), lane));
}
__device__ __forceinline__ unsigned short f2bf(float f) {
  unsigned u = __float_as_uint(f);
  u = u + 0x7FFF + ((u >> 16) & 1);  // round-to-nearest-even
  return (unsigned short)(u >> 16);
}
__device__ __forceinline__ float bf2f(unsigned short b) {
  return __uint_as_float(((unsigned)b) << 16);
}

__global__ void k_count(const int* __restrict__ src, const int* __restrict__ dst,
                        int* cnt_u, int* cnt_m, int E) {
  int e = blockIdx.x * blockDim.x + threadIdx.x;
  if (e < E) {
    atomicAdd(&cnt_u[src[e]], 1);
    atomicAdd(&cnt_m[dst[e]], 1);
  }
}

__global__ void k_count_q(const int* __restrict__ eu, int* cnt, int L) {
  int l = blockIdx.x * blockDim.x + threadIdx.x;
  if (l < L) atomicAdd(&cnt[eu[l]], 1);
}

__global__ void k_scan_part(const int* __restrict__ cnt, int* __restrict__ off,
                            int* __restrict__ bsum, int n) {
  __shared__ int wsum[4];
  int t = threadIdx.x;
  int base = blockIdx.x * 1024 + t * 4;
  int v0 = (base + 0 < n) ? cnt[base + 0] : 0;
  int v1 = (base + 1 < n) ? cnt[base + 1] : 0;
  int v2 = (base + 2 < n) ? cnt[base + 2] : 0;
  int v3 = (base + 3 < n) ? cnt[base + 3] : 0;
  int s = v0 + v1 + v2 + v3;
  int lane = t & 63;
  int inc = s;
  #pragma unroll
  for (int d = 1; d < 64; d <<= 1) {
    int x = __shfl_up(inc, d);
    if (lane >= d) inc += x;
  }
  int wid = t >> 6;
  if (lane == 63) wsum[wid] = inc;
  __syncthreads();
  int woff = 0;
  for (int i = 0; i < wid; i++) woff += wsum[i];
  int excl = woff + inc - s;
  if (base + 0 < n) off[base + 0] = excl;
  if (base + 1 < n) off[base + 1] = excl + v0;
  if (base + 2 < n) off[base + 2] = excl + v0 + v1;
  if (base + 3 < n) off[base + 3] = excl + v0 + v1 + v2;
  if (t == 255) bsum[blockIdx.x] = woff + inc;
}

__global__ void k_scan_top(int* bsum, int nb) {
  int lane = threadIdx.x;  // block of 64
  int carry = 0;
  for (int base = 0; base < nb; base += 64) {
    int i = base + lane;
    int v = (i < nb) ? bsum[i] : 0;
    int inc = v;
    #pragma unroll
    for (int d = 1; d < 64; d <<= 1) {
      int x = __shfl_up(inc, d);
      if (lane >= d) inc += x;
    }
    if (i < nb) bsum[i] = carry + inc - v;
    carry += __shfl(inc, 63);
  }
}

__global__ void k_scan_add(int* __restrict__ off, int* __restrict__ cur,
                           const int* __restrict__ bsum, int n, int total) {
  int i = blockIdx.x * blockDim.x + threadIdx.x;
  if (i < n) {
    int v = off[i] + bsum[i >> 10];
    off[i] = v;
    cur[i] = v;
  } else if (i == n) {
    off[n] = total;
  }
}

__global__ void k_scatter(const int* __restrict__ src, const int* __restrict__ dst,
                          int* cur_u, int* cur_m,
                          int* __restrict__ nbr_u, int* __restrict__ nbr_m, int E) {
  int e = blockIdx.x * blockDim.x + threadIdx.x;
  if (e < E) {
    int s = src[e], d = dst[e];
    int pu = atomicAdd(&cur_u[s], 1);
    nbr_u[pu] = d;
    int pm = atomicAdd(&cur_m[d], 1);
    nbr_m[pm] = s;
  }
}

__global__ void k_scatter_q(const int* __restrict__ eu, const int* __restrict__ em,
                            int* cur, int* __restrict__ qm, int* __restrict__ qpos,
                            int L) {
  int l = blockIdx.x * blockDim.x + threadIdx.x;
  if (l < L) {
    int p = atomicAdd(&cur[eu[l]], 1);
    qm[p] = em[l];
    qpos[p] = l;
  }
}

// f32 -> bf16 table conversion, 4 elems/thread
__global__ void k_tobf4(const float4* __restrict__ in, unsigned short* __restrict__ out, int n4) {
  int i = blockIdx.x * blockDim.x + threadIdx.x;
  if (i < n4) {
    float4 v = in[i];
    ushort4 o;
    o.x = f2bf(v.x); o.y = f2bf(v.y); o.z = f2bf(v.z); o.w = f2bf(v.w);
    *(ushort4*)(out + (size_t)i * 4) = o;
  }
}

// x_movie(bf16) = movie_x @ lin_W.T + lin_b + movie_emb  (wave per movie, lane = h)
__global__ void k_movie_init(const float* __restrict__ movie_x,
                             const float* __restrict__ lin_W,
                             const float* __restrict__ lin_b,
                             const float* __restrict__ movie_emb,
                             unsigned short* __restrict__ x_movie) {
  int w = (blockIdx.x * blockDim.x + threadIdx.x) >> 6;
  int h = threadIdx.x & 63;
  if (w >= NM) return;
  float acc = lin_b[h] + movie_emb[(size_t)w * 64 + h];
  const float* mx = movie_x + (size_t)w * 20;
  const float* lw = lin_W + (size_t)h * 20;
  #pragma unroll
  for (int f = 0; f < 20; f++) acc += mx[f] * lw[f];
  x_movie[(size_t)w * 64 + h] = f2bf(acc);
}

// Single-relation aggregation, one wave per destination node.
// Packed gather: lane l = (row-slot g=l>>3, 16B-chunk i=l&7); one dwordx4
// gathers 8 neighbor rows. Split per relation so the randomly-accessed
// source table's working set is minimal (user-dest phase: 6.4MB movie
// table, ~1.6x one XCD L2) -- diagnostic for L2-residency governing the
// random-row service rate.
template <int RELU>
__global__ void __launch_bounds__(256)
k_agg(const unsigned short* __restrict__ xsrc, const unsigned short* __restrict__ xdst,
      const int* __restrict__ nbr, const int* __restrict__ off,
      const float* __restrict__ Wl, const float* __restrict__ Wr,
      const float* __restrict__ bias, unsigned short* __restrict__ out, int ndst) {
  int w = (blockIdx.x * blockDim.x + threadIdx.x) >> 6;
  int lane = threadIdx.x & 63;
  if (w >= ndst) return;  // wave-uniform
  int g = lane >> 3;   // row slot within chunk
  int i = lane & 7;    // 16B sub-offset within row
  int s = off[w], e = off[w + 1];
  float aa[8];
  #pragma unroll
  for (int k = 0; k < 8; k++) aa[k] = 0.f;

  for (int base = s; base < e; base += 64) {
    int cnw = e - base;
    if (cnw > 64) cnw = 64;
    int lim = cnw - 1;
    int my = nbr[base + (lane < cnw ? lane : 0)];  // coalesced window load
    uint4 d0, d1, d2, d3, d4, d5, d6, d7;
    int j0 = __shfl(my, min(0 * 8 + g, lim));
    int j1 = __shfl(my, min(1 * 8 + g, lim));
    int j2 = __shfl(my, min(2 * 8 + g, lim));
    int j3 = __shfl(my, min(3 * 8 + g, lim));
    d0 = *(const uint4*)(xsrc + (size_t)j0 * 64 + i * 8);
    d1 = *(const uint4*)(xsrc + (size_t)j1 * 64 + i * 8);
    d2 = *(const uint4*)(xsrc + (size_t)j2 * 64 + i * 8);
    d3 = *(const uint4*)(xsrc + (size_t)j3 * 64 + i * 8);
    bool hi = cnw > 32;
    if (hi) {
      int j4 = __shfl(my, min(4 * 8 + g, lim));
      int j5 = __shfl(my, min(5 * 8 + g, lim));
      int j6 = __shfl(my, min(6 * 8 + g, lim));
      int j7 = __shfl(my, min(7 * 8 + g, lim));
      d4 = *(const uint4*)(xsrc + (size_t)j4 * 64 + i * 8);
      d5 = *(const uint4*)(xsrc + (size_t)j5 * 64 + i * 8);
      d6 = *(const uint4*)(xsrc + (size_t)j6 * 64 + i * 8);
      d7 = *(const uint4*)(xsrc + (size_t)j7 * 64 + i * 8);
    }
    #define CONSUME(dd, c)                                              \
      {                                                                 \
        float mc = ((c) * 8 + g < cnw) ? 1.f : 0.f;                     \
        aa[0] = fmaf(__uint_as_float(dd.x << 16), mc, aa[0]);           \
        aa[1] = fmaf(__uint_as_float(dd.x & 0xFFFF0000u), mc, aa[1]);   \
        aa[2] = fmaf(__uint_as_float(dd.y << 16), mc, aa[2]);           \
        aa[3] = fmaf(__uint_as_float(dd.y & 0xFFFF0000u), mc, aa[3]);   \
        aa[4] = fmaf(__uint_as_float(dd.z << 16), mc, aa[4]);           \
        aa[5] = fmaf(__uint_as_float(dd.z & 0xFFFF0000u), mc, aa[5]);   \
        aa[6] = fmaf(__uint_as_float(dd.w << 16), mc, aa[6]);           \
        aa[7] = fmaf(__uint_as_float(dd.w & 0xFFFF0000u), mc, aa[7]);   \
      }
    CONSUME(d0, 0)
    CONSUME(d1, 1)
    CONSUME(d2, 2)
    CONSUME(d3, 3)
    if (hi) {
      CONSUME(d4, 4)
      CONSUME(d5, 5)
      CONSUME(d6, 6)
      CONSUME(d7, 7)
    }
    #undef CONSUME
  }
  // cross-row-slot reduce: sum over g (lane bits 3..5)
  #pragma unroll
  for (int m = 8; m <= 32; m <<= 1) {
    #pragma unroll
    for (int k = 0; k < 8; k++) aa[k] += __shfl_xor(aa[k], m);
  }
  float inv = 1.0f / fmaxf((float)(e - s), 1.0f);
  #pragma unroll
  for (int k = 0; k < 8; k++) aa[k] *= inv;  // mean; lane holds f=8*(lane&7)+k
  float dv = bf2f(xdst[(size_t)w * 64 + lane]);

  float acc = bias[lane];
  const float4* wl4 = (const float4*)(Wl + (size_t)lane * 64);
  const float4* wr4 = (const float4*)(Wr + (size_t)lane * 64);
  #pragma unroll
  for (int blk = 0; blk < 16; blk++) {
    float4 a4 = wl4[blk];
    float4 c4 = wr4[blk];
    acc += bcastf(aa[(4 * blk + 0) & 7], (4 * blk + 0) >> 3) * a4.x;
    acc += bcastf(aa[(4 * blk + 1) & 7], (4 * blk + 1) >> 3) * a4.y;
    acc += bcastf(aa[(4 * blk + 2) & 7], (4 * blk + 2) >> 3) * a4.z;
    acc += bcastf(aa[(4 * blk + 3) & 7], (4 * blk + 3) >> 3) * a4.w;
    acc += bcastf(dv, 4 * blk + 0) * c4.x;
    acc += bcastf(dv, 4 * blk + 1) * c4.y;
    acc += bcastf(dv, 4 * blk + 2) * c4.z;
    acc += bcastf(dv, 4 * blk + 3) * c4.w;
  }
  if (RELU) acc = fmaxf(acc, 0.0f);
  out[(size_t)w * 64 + lane] = f2bf(acc);
}

// User-grouped classifier: one wave per user; u2 row loaded once, only
// m2 rows (6.4MB bf16 table) gathered randomly -> 1M random rows vs 2M.
// 4 independent query chains; full-wave shfl_xor reduce; result parked in
// lane q, one scattered store per query via qpos.
__global__ void __launch_bounds__(256)
k_dot_g(const unsigned short* __restrict__ u2, const unsigned short* __restrict__ m2,
        const int* __restrict__ qm, const int* __restrict__ qpos,
        const int* __restrict__ qoff, float* __restrict__ out) {
  int u = (blockIdx.x * blockDim.x + threadIdx.x) >> 6;
  int lane = threadIdx.x & 63;
  if (u >= NU) return;
  int s = qoff[u], e = qoff[u + 1];
  if (s >= e) return;
  float uv = bf2f(u2[(size_t)u * 64 + lane]);
  for (int base = s; base < e; base += 64) {
    int cn = e - base;
    if (cn > 64) cn = 64;
    int lim = cn - 1;
    int idx = base + (lane < cn ? lane : 0);
    int myM = qm[idx];
    int myP = qpos[idx];
    float res = 0.f;
    for (int q = 0; q < cn; q += 4) {
      int m0 = __shfl(myM, min(q + 0, lim));
      int m1 = __shfl(myM, min(q + 1, lim));
      int m2i = __shfl(myM, min(q + 2, lim));
      int m3 = __shfl(myM, min(q + 3, lim));
      float v0 = bf2f(m2[(size_t)m0 * 64 + lane]) * uv;
      float v1 = bf2f(m2[(size_t)m1 * 64 + lane]) * uv;
      float v2 = bf2f(m2[(size_t)m2i * 64 + lane]) * uv;
      float v3 = bf2f(m2[(size_t)m3 * 64 + lane]) * uv;
      #pragma unroll
      for (int d = 1; d <= 32; d <<= 1) {
        v0 += __shfl_xor(v0, d);
        v1 += __shfl_xor(v1, d);
        v2 += __shfl_xor(v2, d);
        v3 += __shfl_xor(v3, d);
      }
      res = (lane == q + 0) ? v0 : res;
      res = (lane == q + 1) ? v1 : res;
      res = (lane == q + 2) ? v2 : res;
      res = (lane == q + 3) ? v3 : res;
    }
    if (lane < cn) out[myP] = res;
  }
}

extern "C" void kernel_launch(void* const* d_in, const int* in_sizes, int n_in,
                              void* d_out, int out_size, void* d_ws, size_t ws_size,
                              hipStream_t stream) {
  const float* movie_x   = (const float*)d_in[2];
  const int*   esrc      = (const int*)d_in[3];
  const int*   edst      = (const int*)d_in[4];
  const int*   eli_u     = (const int*)d_in[5];
  const int*   eli_m     = (const int*)d_in[6];
  const float* user_emb  = (const float*)d_in[7];
  const float* movie_emb = (const float*)d_in[8];
  const float* lin_W     = (const float*)d_in[9];
  const float* lin_b     = (const float*)d_in[10];
  const float* W1um_l = (const float*)d_in[11];
  const float* W1um_r = (const float*)d_in[12];
  const float* W1mu_l = (const float*)d_in[13];
  const float* W1mu_r = (const float*)d_in[14];
  const float* W2um_l = (const float*)d_in[15];
  const float* W2um_r = (const float*)d_in[16];
  const float* W2mu_l = (const float*)d_in[17];
  const float* W2mu_r = (const float*)d_in[18];
  const float* b1um = (const float*)d_in[19];
  const float* b1mu = (const float*)d_in[20];
  const float* b2um = (const float*)d_in[21];
  const float* b2mu = (const float*)d_in[22];
  const int E = in_sizes[3];
  const int L = in_sizes[5];

  char* ws = (char*)d_ws;
  size_t o = 0;
  auto alloc = [&](size_t bytes) -> void* {
    void* p = ws + o;
    o = (o + bytes + 255) & ~(size_t)255;
    return p;
  };
  unsigned short* uemb_bf   = (unsigned short*)alloc((size_t)NU * 64 * 2);
  unsigned short* xmovie_bf = (unsigned short*)alloc((size_t)NM * 64 * 2);
  unsigned short* m1_bf     = (unsigned short*)alloc((size_t)NM * 64 * 2);
  unsigned short* u1_bf     = (unsigned short*)alloc((size_t)NU * 64 * 2);
  unsigned short* m2_bf     = (unsigned short*)alloc((size_t)NM * 64 * 2);
  unsigned short* u2_bf     = (unsigned short*)alloc((size_t)NU * 64 * 2);
  int* cnt_m = (int*)alloc((size_t)NM * 4);
  int* cnt_u = (int*)alloc((size_t)NU * 4);
  int* cnt_q = (int*)alloc((size_t)NU * 4);
  int* off_m = (int*)alloc((size_t)(NM + 1) * 4);
  int* off_u = (int*)alloc((size_t)(NU + 1) * 4);
  int* off_q = (int*)alloc((size_t)(NU + 1) * 4);
  int* cur_m = (int*)alloc((size_t)NM * 4);
  int* cur_u = (int*)alloc((size_t)NU * 4);
  int* cur_q = (int*)alloc((size_t)NU * 4);
  int* bs_m  = (int*)alloc(4096);
  int* bs_u  = (int*)alloc(4096);
  int* bs_q  = (int*)alloc(4096);
  int* nbr_m = (int*)alloc((size_t)E * 4);
  int* nbr_u = (int*)alloc((size_t)E * 4);
  int* qm    = (int*)alloc((size_t)L * 4);
  int* qpos  = (int*)alloc((size_t)L * 4);

  hipMemsetAsync(cnt_m, 0, (size_t)NM * 4, stream);
  hipMemsetAsync(cnt_u, 0, (size_t)NU * 4, stream);
  hipMemsetAsync(cnt_q, 0, (size_t)NU * 4, stream);

  int gE = (E + 255) / 256;
  int gL = (L + 255) / 256;
  k_count<<<gE, 256, 0, stream>>>(esrc, edst, cnt_u, cnt_m, E);
  k_count_q<<<gL, 256, 0, stream>>>(eli_u, cnt_q, L);

  int nbm = (NM + 1023) / 1024, nbu = (NU + 1023) / 1024;
  k_scan_part<<<nbm, 256, 0, stream>>>(cnt_m, off_m, bs_m, NM);
  k_scan_part<<<nbu, 256, 0, stream>>>(cnt_u, off_u, bs_u, NU);
  k_scan_part<<<nbu, 256, 0, stream>>>(cnt_q, off_q, bs_q, NU);
  k_scan_top<<<1, 64, 0, stream>>>(bs_m, nbm);
  k_scan_top<<<1, 64, 0, stream>>>(bs_u, nbu);
  k_scan_top<<<1, 64, 0, stream>>>(bs_q, nbu);
  k_scan_add<<<(NM + 1 + 255) / 256, 256, 0, stream>>>(off_m, cur_m, bs_m, NM, E);
  k_scan_add<<<(NU + 1 + 255) / 256, 256, 0, stream>>>(off_u, cur_u, bs_u, NU, E);
  k_scan_add<<<(NU + 1 + 255) / 256, 256, 0, stream>>>(off_q, cur_q, bs_q, NU, L);
  k_scatter<<<gE, 256, 0, stream>>>(esrc, edst, cur_u, cur_m, nbr_u, nbr_m, E);
  k_scatter_q<<<gL, 256, 0, stream>>>(eli_u, eli_m, cur_q, qm, qpos, L);

  // bf16 gather tables
  int n4u = NU * 16;  // NU*64/4
  k_tobf4<<<(n4u + 255) / 256, 256, 0, stream>>>((const float4*)user_emb, uemb_bf, n4u);
  k_movie_init<<<(NM + 3) / 4, 256, 0, stream>>>(movie_x, lin_W, lin_b, movie_emb, xmovie_bf);

  int gM = (NM + 3) / 4, gU = (NU + 3) / 4;
  // layer 1 (ReLU) -- split per relation (working-set diagnostic)
  k_agg<1><<<gM, 256, 0, stream>>>(uemb_bf, xmovie_bf, nbr_m, off_m,
                                   W1um_l, W1um_r, b1um, m1_bf, NM);
  k_agg<1><<<gU, 256, 0, stream>>>(xmovie_bf, uemb_bf, nbr_u, off_u,
                                   W1mu_l, W1mu_r, b1mu, u1_bf, NU);
  // layer 2 (no activation)
  k_agg<0><<<gM, 256, 0, stream>>>(u1_bf, m1_bf, nbr_m, off_m,
                                   W2um_l, W2um_r, b2um, m2_bf, NM);
  k_agg<0><<<gU, 256, 0, stream>>>(m1_bf, u1_bf, nbr_u, off_u,
                                   W2mu_l, W2mu_r, b2mu, u2_bf, NU);

  k_dot_g<<<gU, 256, 0, stream>>>(u2_bf, m2_bf, qm, qpos, off_q, (float*)d_out);
}

// Round 7
// 1856.559 us; speedup vs baseline: 1.1852x; 1.1852x over previous
//
#include <hip/hip_runtime.h>

#define NU 100000
#define NM 50000
#define RM 4   // sub-ranges of the user table (12.8MB bf16 -> 4 x 3.2MB)
#define RU 2   // sub-ranges of the movie table (6.4MB bf16 -> 2 x 3.2MB)

__device__ __forceinline__ float bcastf(float v, int lane) {
  return __int_as_float(__builtin_amdgcn_readlane(__float_as_int(v), lane));
}
__device__ __forceinline__ unsigned short f2bf(float f) {
  unsigned u = __float_as_uint(f);
  u = u + 0x7FFF + ((u >> 16) & 1);  // round-to-nearest-even
  return (unsigned short)(u >> 16);
}
__device__ __forceinline__ float bf2f(unsigned short b) {
  return __uint_as_float(((unsigned)b) << 16);
}

// counts keyed by (node, src-table sub-range)
__global__ void k_count2(const int* __restrict__ src, const int* __restrict__ dst,
                         int* cnt_m, int* cnt_u, int E) {
  int e = blockIdx.x * blockDim.x + threadIdx.x;
  if (e < E) {
    int s = src[e], d = dst[e];
    atomicAdd(&cnt_m[d * RM + (unsigned)s / 25000u], 1);
    atomicAdd(&cnt_u[s * RU + (unsigned)d / 25000u], 1);
  }
}

__global__ void k_scan_part(const int* __restrict__ cnt, int* __restrict__ off,
                            int* __restrict__ bsum, int n) {
  __shared__ int wsum[4];
  int t = threadIdx.x;
  int base = blockIdx.x * 1024 + t * 4;
  int v0 = (base + 0 < n) ? cnt[base + 0] : 0;
  int v1 = (base + 1 < n) ? cnt[base + 1] : 0;
  int v2 = (base + 2 < n) ? cnt[base + 2] : 0;
  int v3 = (base + 3 < n) ? cnt[base + 3] : 0;
  int s = v0 + v1 + v2 + v3;
  int lane = t & 63;
  int inc = s;
  #pragma unroll
  for (int d = 1; d < 64; d <<= 1) {
    int x = __shfl_up(inc, d);
    if (lane >= d) inc += x;
  }
  int wid = t >> 6;
  if (lane == 63) wsum[wid] = inc;
  __syncthreads();
  int woff = 0;
  for (int i = 0; i < wid; i++) woff += wsum[i];
  int excl = woff + inc - s;
  if (base + 0 < n) off[base + 0] = excl;
  if (base + 1 < n) off[base + 1] = excl + v0;
  if (base + 2 < n) off[base + 2] = excl + v0 + v1;
  if (base + 3 < n) off[base + 3] = excl + v0 + v1 + v2;
  if (t == 255) bsum[blockIdx.x] = woff + inc;
}

__global__ void k_scan_top(int* bsum, int nb) {
  int lane = threadIdx.x;  // block of 64
  int carry = 0;
  for (int base = 0; base < nb; base += 64) {
    int i = base + lane;
    int v = (i < nb) ? bsum[i] : 0;
    int inc = v;
    #pragma unroll
    for (int d = 1; d < 64; d <<= 1) {
      int x = __shfl_up(inc, d);
      if (lane >= d) inc += x;
    }
    if (i < nb) bsum[i] = carry + inc - v;
    carry += __shfl(inc, 63);
  }
}

__global__ void k_scan_add(int* __restrict__ off, int* __restrict__ cur,
                           const int* __restrict__ bsum, int n, int total) {
  int i = blockIdx.x * blockDim.x + threadIdx.x;
  if (i < n) {
    int v = off[i] + bsum[i >> 10];
    off[i] = v;
    cur[i] = v;
  } else if (i == n) {
    off[n] = total;
  }
}

// XCD-phased scatter: blocks sharing (blockIdx&7) presumably land on the same
// XCD (round-robin dispatch heuristic); each handles only edges whose
// destination id falls in that XCD's 1/8 range, so each output region
// (~2.5MB) is written by a single XCD -> lines fill in its L2 before
// eviction -> full-line writebacks instead of 64B-per-4B partials.
// Falls back to correct (just slower) behavior if the mapping differs.
__global__ void k_scatter_x(const int* __restrict__ src, const int* __restrict__ dst,
                            int* cur_m, int* cur_u,
                            int* __restrict__ nbr_m, int* __restrict__ nbr_u,
                            int E, int nchunk) {
  int lane8 = blockIdx.x & 7;
  int chunk = blockIdx.x >> 3;
  int m_lo = lane8 * (NM / 8), m_hi = m_lo + (NM / 8);
  int u_lo = lane8 * (NU / 8), u_hi = u_lo + (NU / 8);
  int per = (E + nchunk - 1) / nchunk;
  int beg = chunk * per;
  int end = min(beg + per, E);
  for (int e = beg + (int)threadIdx.x; e < end; e += (int)blockDim.x) {
    int s = src[e], d = dst[e];
    if (d >= m_lo && d < m_hi) {
      int p = atomicAdd(&cur_m[d * RM + (unsigned)s / 25000u], 1);
      nbr_m[p] = s;
    }
    if (s >= u_lo && s < u_hi) {
      int p = atomicAdd(&cur_u[s * RU + (unsigned)d / 25000u], 1);
      nbr_u[p] = d;
    }
  }
}

// f32 -> bf16 table conversion, 4 elems/thread
__global__ void k_tobf4(const float4* __restrict__ in, unsigned short* __restrict__ out, int n4) {
  int i = blockIdx.x * blockDim.x + threadIdx.x;
  if (i < n4) {
    float4 v = in[i];
    ushort4 o;
    o.x = f2bf(v.x); o.y = f2bf(v.y); o.z = f2bf(v.z); o.w = f2bf(v.w);
    *(ushort4*)(out + (size_t)i * 4) = o;
  }
}

// x_movie(bf16) = movie_x @ lin_W.T + lin_b + movie_emb  (wave per movie, lane = h)
__global__ void k_movie_init(const float* __restrict__ movie_x,
                             const float* __restrict__ lin_W,
                             const float* __restrict__ lin_b,
                             const float* __restrict__ movie_emb,
                             unsigned short* __restrict__ x_movie) {
  int w = (blockIdx.x * blockDim.x + threadIdx.x) >> 6;
  int h = threadIdx.x & 63;
  if (w >= NM) return;
  float acc = lin_b[h] + movie_emb[(size_t)w * 64 + h];
  const float* mx = movie_x + (size_t)w * 20;
  const float* lw = lin_W + (size_t)h * 20;
  #pragma unroll
  for (int f = 0; f < 20; f++) acc += mx[f] * lw[f];
  x_movie[(size_t)w * 64 + h] = f2bf(acc);
}

// Single-relation aggregation, one wave per destination node.
// Neighbor lists are sub-ordered by source-table range (R segments of
// 3.2MB each, fitting one XCD L2 as a read-only replica). All waves walk
// segment 0 first, then 1, ... so gathers temporally cluster on an
// L2-resident slice. Packed gather: lane l = (row-slot g=l>>3, chunk
// i=l&7); one dwordx4 gathers 8 neighbor rows.
template <int RELU, int R>
__global__ void __launch_bounds__(256)
k_agg(const unsigned short* __restrict__ xsrc, const unsigned short* __restrict__ xdst,
      const int* __restrict__ nbr, const int* __restrict__ off,
      const float* __restrict__ Wl, const float* __restrict__ Wr,
      const float* __restrict__ bias, unsigned short* __restrict__ out, int ndst) {
  int w = (blockIdx.x * blockDim.x + threadIdx.x) >> 6;
  int lane = threadIdx.x & 63;
  if (w >= ndst) return;  // wave-uniform
  int g = lane >> 3;   // row slot within chunk
  int i = lane & 7;    // 16B sub-offset within row
  float aa[8];
  #pragma unroll
  for (int k = 0; k < 8; k++) aa[k] = 0.f;

  int s0 = off[w * R];
  int eN = off[(w + 1) * R];
  for (int r = 0; r < R; ++r) {
    int sseg = off[w * R + r], eseg = off[w * R + r + 1];
    for (int base = sseg; base < eseg; base += 64) {
      int cnw = eseg - base;
      if (cnw > 64) cnw = 64;
      int lim = cnw - 1;
      int my = nbr[base + (lane < cnw ? lane : 0)];  // coalesced window load
      uint4 d0, d1, d2, d3, d4, d5, d6, d7;
      int j0 = __shfl(my, min(0 * 8 + g, lim));
      int j1 = __shfl(my, min(1 * 8 + g, lim));
      d0 = *(const uint4*)(xsrc + (size_t)j0 * 64 + i * 8);
      d1 = *(const uint4*)(xsrc + (size_t)j1 * 64 + i * 8);
      bool mid = cnw > 16;
      bool hi = cnw > 32;
      if (mid) {
        int j2 = __shfl(my, min(2 * 8 + g, lim));
        int j3 = __shfl(my, min(3 * 8 + g, lim));
        d2 = *(const uint4*)(xsrc + (size_t)j2 * 64 + i * 8);
        d3 = *(const uint4*)(xsrc + (size_t)j3 * 64 + i * 8);
      }
      if (hi) {
        int j4 = __shfl(my, min(4 * 8 + g, lim));
        int j5 = __shfl(my, min(5 * 8 + g, lim));
        int j6 = __shfl(my, min(6 * 8 + g, lim));
        int j7 = __shfl(my, min(7 * 8 + g, lim));
        d4 = *(const uint4*)(xsrc + (size_t)j4 * 64 + i * 8);
        d5 = *(const uint4*)(xsrc + (size_t)j5 * 64 + i * 8);
        d6 = *(const uint4*)(xsrc + (size_t)j6 * 64 + i * 8);
        d7 = *(const uint4*)(xsrc + (size_t)j7 * 64 + i * 8);
      }
      #define CONSUME(dd, c)                                              \
        {                                                                 \
          float mc = ((c) * 8 + g < cnw) ? 1.f : 0.f;                     \
          aa[0] = fmaf(__uint_as_float(dd.x << 16), mc, aa[0]);           \
          aa[1] = fmaf(__uint_as_float(dd.x & 0xFFFF0000u), mc, aa[1]);   \
          aa[2] = fmaf(__uint_as_float(dd.y << 16), mc, aa[2]);           \
          aa[3] = fmaf(__uint_as_float(dd.y & 0xFFFF0000u), mc, aa[3]);   \
          aa[4] = fmaf(__uint_as_float(dd.z << 16), mc, aa[4]);           \
          aa[5] = fmaf(__uint_as_float(dd.z & 0xFFFF0000u), mc, aa[5]);   \
          aa[6] = fmaf(__uint_as_float(dd.w << 16), mc, aa[6]);           \
          aa[7] = fmaf(__uint_as_float(dd.w & 0xFFFF0000u), mc, aa[7]);   \
        }
      CONSUME(d0, 0)
      CONSUME(d1, 1)
      if (mid) {
        CONSUME(d2, 2)
        CONSUME(d3, 3)
      }
      if (hi) {
        CONSUME(d4, 4)
        CONSUME(d5, 5)
        CONSUME(d6, 6)
        CONSUME(d7, 7)
      }
      #undef CONSUME
    }
  }
  // cross-row-slot reduce: sum over g (lane bits 3..5)
  #pragma unroll
  for (int m = 8; m <= 32; m <<= 1) {
    #pragma unroll
    for (int k = 0; k < 8; k++) aa[k] += __shfl_xor(aa[k], m);
  }
  float inv = 1.0f / fmaxf((float)(eN - s0), 1.0f);
  #pragma unroll
  for (int k = 0; k < 8; k++) aa[k] *= inv;  // mean; lane holds f=8*(lane&7)+k
  float dv = bf2f(xdst[(size_t)w * 64 + lane]);

  float acc = bias[lane];
  const float4* wl4 = (const float4*)(Wl + (size_t)lane * 64);
  const float4* wr4 = (const float4*)(Wr + (size_t)lane * 64);
  #pragma unroll
  for (int blk = 0; blk < 16; blk++) {
    float4 a4 = wl4[blk];
    float4 c4 = wr4[blk];
    acc += bcastf(aa[(4 * blk + 0) & 7], (4 * blk + 0) >> 3) * a4.x;
    acc += bcastf(aa[(4 * blk + 1) & 7], (4 * blk + 1) >> 3) * a4.y;
    acc += bcastf(aa[(4 * blk + 2) & 7], (4 * blk + 2) >> 3) * a4.z;
    acc += bcastf(aa[(4 * blk + 3) & 7], (4 * blk + 3) >> 3) * a4.w;
    acc += bcastf(dv, 4 * blk + 0) * c4.x;
    acc += bcastf(dv, 4 * blk + 1) * c4.y;
    acc += bcastf(dv, 4 * blk + 2) * c4.z;
    acc += bcastf(dv, 4 * blk + 3) * c4.w;
  }
  if (RELU) acc = fmaxf(acc, 0.0f);
  out[(size_t)w * 64 + lane] = f2bf(acc);
}

// 16 lanes per edge on bf16 rows (128B contiguous per row), shfl_xor
// reduce within the 16-lane group. 16 edges per 256-thread block.
__global__ void __launch_bounds__(256)
k_dot(const unsigned short* __restrict__ u2, const unsigned short* __restrict__ m2,
      const int* __restrict__ eu, const int* __restrict__ em,
      float* __restrict__ out, int L) {
  int wave = (blockIdx.x * blockDim.x + threadIdx.x) >> 6;
  int lane = threadIdx.x & 63;
  int sub = lane & 15;
  int l = wave * 4 + (lane >> 4);
  int lc = l < L ? l : (L - 1);
  int iu = eu[lc], im = em[lc];
  uint2 a = *(const uint2*)(u2 + (size_t)iu * 64 + sub * 4);
  uint2 b = *(const uint2*)(m2 + (size_t)im * 64 + sub * 4);
  float s = __uint_as_float(a.x << 16) * __uint_as_float(b.x << 16)
          + __uint_as_float(a.x & 0xFFFF0000u) * __uint_as_float(b.x & 0xFFFF0000u)
          + __uint_as_float(a.y << 16) * __uint_as_float(b.y << 16)
          + __uint_as_float(a.y & 0xFFFF0000u) * __uint_as_float(b.y & 0xFFFF0000u);
  s += __shfl_xor(s, 1);
  s += __shfl_xor(s, 2);
  s += __shfl_xor(s, 4);
  s += __shfl_xor(s, 8);
  if (sub == 0 && l < L) out[l] = s;
}

extern "C" void kernel_launch(void* const* d_in, const int* in_sizes, int n_in,
                              void* d_out, int out_size, void* d_ws, size_t ws_size,
                              hipStream_t stream) {
  const float* movie_x   = (const float*)d_in[2];
  const int*   esrc      = (const int*)d_in[3];
  const int*   edst      = (const int*)d_in[4];
  const int*   eli_u     = (const int*)d_in[5];
  const int*   eli_m     = (const int*)d_in[6];
  const float* user_emb  = (const float*)d_in[7];
  const float* movie_emb = (const float*)d_in[8];
  const float* lin_W     = (const float*)d_in[9];
  const float* lin_b     = (const float*)d_in[10];
  const float* W1um_l = (const float*)d_in[11];
  const float* W1um_r = (const float*)d_in[12];
  const float* W1mu_l = (const float*)d_in[13];
  const float* W1mu_r = (const float*)d_in[14];
  const float* W2um_l = (const float*)d_in[15];
  const float* W2um_r = (const float*)d_in[16];
  const float* W2mu_l = (const float*)d_in[17];
  const float* W2mu_r = (const float*)d_in[18];
  const float* b1um = (const float*)d_in[19];
  const float* b1mu = (const float*)d_in[20];
  const float* b2um = (const float*)d_in[21];
  const float* b2mu = (const float*)d_in[22];
  const int E = in_sizes[3];
  const int L = in_sizes[5];

  char* ws = (char*)d_ws;
  size_t o = 0;
  auto alloc = [&](size_t bytes) -> void* {
    void* p = ws + o;
    o = (o + bytes + 255) & ~(size_t)255;
    return p;
  };
  unsigned short* uemb_bf   = (unsigned short*)alloc((size_t)NU * 64 * 2);
  unsigned short* xmovie_bf = (unsigned short*)alloc((size_t)NM * 64 * 2);
  unsigned short* m1_bf     = (unsigned short*)alloc((size_t)NM * 64 * 2);
  unsigned short* u1_bf     = (unsigned short*)alloc((size_t)NU * 64 * 2);
  unsigned short* m2_bf     = (unsigned short*)alloc((size_t)NM * 64 * 2);
  unsigned short* u2_bf     = (unsigned short*)alloc((size_t)NU * 64 * 2);
  const int NKM = NM * RM;  // keys for movie-dest CSR
  const int NKU = NU * RU;  // keys for user-dest CSR
  int* cnt_m = (int*)alloc((size_t)NKM * 4);
  int* cnt_u = (int*)alloc((size_t)NKU * 4);
  int* off_m = (int*)alloc((size_t)(NKM + 1) * 4);
  int* off_u = (int*)alloc((size_t)(NKU + 1) * 4);
  int* cur_m = (int*)alloc((size_t)NKM * 4);
  int* cur_u = (int*)alloc((size_t)NKU * 4);
  int* bs_m  = (int*)alloc(4096);
  int* bs_u  = (int*)alloc(4096);
  int* nbr_m = (int*)alloc((size_t)E * 4);
  int* nbr_u = (int*)alloc((size_t)E * 4);

  hipMemsetAsync(cnt_m, 0, (size_t)NKM * 4, stream);
  hipMemsetAsync(cnt_u, 0, (size_t)NKU * 4, stream);

  int gE = (E + 255) / 256;
  k_count2<<<gE, 256, 0, stream>>>(esrc, edst, cnt_m, cnt_u, E);

  int nbm = (NKM + 1023) / 1024, nbu = (NKU + 1023) / 1024;
  k_scan_part<<<nbm, 256, 0, stream>>>(cnt_m, off_m, bs_m, NKM);
  k_scan_part<<<nbu, 256, 0, stream>>>(cnt_u, off_u, bs_u, NKU);
  k_scan_top<<<1, 64, 0, stream>>>(bs_m, nbm);
  k_scan_top<<<1, 64, 0, stream>>>(bs_u, nbu);
  k_scan_add<<<(NKM + 1 + 255) / 256, 256, 0, stream>>>(off_m, cur_m, bs_m, NKM, E);
  k_scan_add<<<(NKU + 1 + 255) / 256, 256, 0, stream>>>(off_u, cur_u, bs_u, NKU, E);

  // XCD-phased scatter: 256 chunks x 8 XCD-lanes
  int nchunk = 256;
  k_scatter_x<<<nchunk * 8, 256, 0, stream>>>(esrc, edst, cur_m, cur_u,
                                              nbr_m, nbr_u, E, nchunk);

  // bf16 gather tables
  int n4u = NU * 16;  // NU*64/4
  k_tobf4<<<(n4u + 255) / 256, 256, 0, stream>>>((const float4*)user_emb, uemb_bf, n4u);
  k_movie_init<<<(NM + 3) / 4, 256, 0, stream>>>(movie_x, lin_W, lin_b, movie_emb, xmovie_bf);

  int gM = (NM + 3) / 4, gU = (NU + 3) / 4;
  // layer 1 (ReLU)
  k_agg<1, RM><<<gM, 256, 0, stream>>>(uemb_bf, xmovie_bf, nbr_m, off_m,
                                       W1um_l, W1um_r, b1um, m1_bf, NM);
  k_agg<1, RU><<<gU, 256, 0, stream>>>(xmovie_bf, uemb_bf, nbr_u, off_u,
                                       W1mu_l, W1mu_r, b1mu, u1_bf, NU);
  // layer 2 (no activation)
  k_agg<0, RM><<<gM, 256, 0, stream>>>(u1_bf, m1_bf, nbr_m, off_m,
                                       W2um_l, W2um_r, b2um, m2_bf, NM);
  k_agg<0, RU><<<gU, 256, 0, stream>>>(m1_bf, u1_bf, nbr_u, off_u,
                                       W2mu_l, W2mu_r, b2mu, u2_bf, NU);

  // 16 edges per 256-thread block
  k_dot<<<(L + 15) / 16, 256, 0, stream>>>(u2_bf, m2_bf, eli_u, eli_m, (float*)d_out, L);
}

// Round 8
// 1034.456 us; speedup vs baseline: 2.1271x; 1.7947x over previous
//
#include <hip/hip_runtime.h>

#define NU 100000
#define NM 50000
#define RM 4   // sub-ranges of the user table (12.8MB bf16 -> 4 x 3.2MB)
#define RU 2   // sub-ranges of the movie table (6.4MB bf16 -> 2 x 3.2MB)

__device__ __forceinline__ float bcastf(float v, int lane) {
  return __int_as_float(__builtin_amdgcn_readlane(__float_as_int(v), lane));
}
__device__ __forceinline__ unsigned short f2bf(float f) {
  unsigned u = __float_as_uint(f);
  u = u + 0x7FFF + ((u >> 16) & 1);  // round-to-nearest-even
  return (unsigned short)(u >> 16);
}
__device__ __forceinline__ float bf2f(unsigned short b) {
  return __uint_as_float(((unsigned)b) << 16);
}

// counts keyed by (node, src-table sub-range)
__global__ void k_count2(const int* __restrict__ src, const int* __restrict__ dst,
                         int* cnt_m, int* cnt_u, int E) {
  int e = blockIdx.x * blockDim.x + threadIdx.x;
  if (e < E) {
    int s = src[e], d = dst[e];
    atomicAdd(&cnt_m[d * RM + (unsigned)s / 25000u], 1);
    atomicAdd(&cnt_u[s * RU + (unsigned)d / 25000u], 1);
  }
}

__global__ void k_scan_part(const int* __restrict__ cnt, int* __restrict__ off,
                            int* __restrict__ bsum, int n) {
  __shared__ int wsum[4];
  int t = threadIdx.x;
  int base = blockIdx.x * 1024 + t * 4;
  int v0 = (base + 0 < n) ? cnt[base + 0] : 0;
  int v1 = (base + 1 < n) ? cnt[base + 1] : 0;
  int v2 = (base + 2 < n) ? cnt[base + 2] : 0;
  int v3 = (base + 3 < n) ? cnt[base + 3] : 0;
  int s = v0 + v1 + v2 + v3;
  int lane = t & 63;
  int inc = s;
  #pragma unroll
  for (int d = 1; d < 64; d <<= 1) {
    int x = __shfl_up(inc, d);
    if (lane >= d) inc += x;
  }
  int wid = t >> 6;
  if (lane == 63) wsum[wid] = inc;
  __syncthreads();
  int woff = 0;
  for (int i = 0; i < wid; i++) woff += wsum[i];
  int excl = woff + inc - s;
  if (base + 0 < n) off[base + 0] = excl;
  if (base + 1 < n) off[base + 1] = excl + v0;
  if (base + 2 < n) off[base + 2] = excl + v0 + v1;
  if (base + 3 < n) off[base + 3] = excl + v0 + v1 + v2;
  if (t == 255) bsum[blockIdx.x] = woff + inc;
}

__global__ void k_scan_top(int* bsum, int nb) {
  int lane = threadIdx.x;  // block of 64
  int carry = 0;
  for (int base = 0; base < nb; base += 64) {
    int i = base + lane;
    int v = (i < nb) ? bsum[i] : 0;
    int inc = v;
    #pragma unroll
    for (int d = 1; d < 64; d <<= 1) {
      int x = __shfl_up(inc, d);
      if (lane >= d) inc += x;
    }
    if (i < nb) bsum[i] = carry + inc - v;
    carry += __shfl(inc, 63);
  }
}

__global__ void k_scan_add(int* __restrict__ off, int* __restrict__ cur,
                           const int* __restrict__ bsum, int n, int total) {
  int i = blockIdx.x * blockDim.x + threadIdx.x;
  if (i < n) {
    int v = off[i] + bsum[i >> 10];
    off[i] = v;
    cur[i] = v;
  } else if (i == n) {
    off[n] = total;
  }
}

// XCD-phased scatter (see round 7): each XCD lane writes only its 1/8
// destination range so output lines fill within one L2 before writeback.
__global__ void k_scatter_x(const int* __restrict__ src, const int* __restrict__ dst,
                            int* cur_m, int* cur_u,
                            int* __restrict__ nbr_m, int* __restrict__ nbr_u,
                            int E, int nchunk) {
  int lane8 = blockIdx.x & 7;
  int chunk = blockIdx.x >> 3;
  int m_lo = lane8 * (NM / 8), m_hi = m_lo + (NM / 8);
  int u_lo = lane8 * (NU / 8), u_hi = u_lo + (NU / 8);
  int per = (E + nchunk - 1) / nchunk;
  int beg = chunk * per;
  int end = min(beg + per, E);
  for (int e = beg + (int)threadIdx.x; e < end; e += (int)blockDim.x) {
    int s = src[e], d = dst[e];
    if (d >= m_lo && d < m_hi) {
      int p = atomicAdd(&cur_m[d * RM + (unsigned)s / 25000u], 1);
      nbr_m[p] = s;
    }
    if (s >= u_lo && s < u_hi) {
      int p = atomicAdd(&cur_u[s * RU + (unsigned)d / 25000u], 1);
      nbr_u[p] = d;
    }
  }
}

// f32 -> bf16 table conversion, 4 elems/thread
__global__ void k_tobf4(const float4* __restrict__ in, unsigned short* __restrict__ out, int n4) {
  int i = blockIdx.x * blockDim.x + threadIdx.x;
  if (i < n4) {
    float4 v = in[i];
    ushort4 o;
    o.x = f2bf(v.x); o.y = f2bf(v.y); o.z = f2bf(v.z); o.w = f2bf(v.w);
    *(ushort4*)(out + (size_t)i * 4) = o;
  }
}

// x_movie(bf16) = movie_x @ lin_W.T + lin_b + movie_emb  (wave per movie, lane = h)
// lin_W staged transposed in LDS (pitch 65) once per block: per-wave global
// weight reloads had a 64-distinct-line per instruction TA cost.
__global__ void k_movie_init(const float* __restrict__ movie_x,
                             const float* __restrict__ lin_W,
                             const float* __restrict__ lin_b,
                             const float* __restrict__ movie_emb,
                             unsigned short* __restrict__ x_movie) {
  __shared__ float lwT[20 * 65];
  for (int gidx = threadIdx.x; gidx < 64 * 20; gidx += 256) {
    int h = gidx / 20;
    int f = gidx - h * 20;
    lwT[f * 65 + h] = lin_W[gidx];
  }
  __syncthreads();
  int w = (blockIdx.x * blockDim.x + threadIdx.x) >> 6;
  int h = threadIdx.x & 63;
  if (w >= NM) return;
  float acc = lin_b[h] + movie_emb[(size_t)w * 64 + h];
  const float* mx = movie_x + (size_t)w * 20;  // wave-uniform row (2 lines)
  #pragma unroll
  for (int f = 0; f < 20; f++) acc += mx[f] * lwT[f * 65 + h];
  x_movie[(size_t)w * 64 + h] = f2bf(acc);
}

// Single-relation aggregation, one wave per destination node, segment-ordered
// CSR (R source sub-ranges, each ~3.2MB = L2-resident replica).
// Packed gather: lane l = (row-slot g=l>>3, chunk i=l&7); one dwordx4 gathers
// 8 neighbor rows.
// EPILOGUE FIX (round 8): both weight matrices staged TRANSPOSED in LDS once
// per block (coalesced global reads; pitch-65 padding -> conflict-free writes
// AND reads: bank=(k+lane)%32 distinct). Previous per-wave global weight
// loads cost ~2048 distinct L1 lines per wave (64 lines x 32 instrs) -- the
// TA wall that made agg time invariant to all gather-side optimizations.
template <int RELU, int R>
__global__ void __launch_bounds__(256)
k_agg(const unsigned short* __restrict__ xsrc, const unsigned short* __restrict__ xdst,
      const int* __restrict__ nbr, const int* __restrict__ off,
      const float* __restrict__ Wl, const float* __restrict__ Wr,
      const float* __restrict__ bias, unsigned short* __restrict__ out, int ndst) {
  __shared__ float wT[2 * 64 * 65];
  for (int gidx = threadIdx.x; gidx < 4096; gidx += 256) {
    int h = gidx >> 6, k = gidx & 63;
    wT[k * 65 + h] = Wl[gidx];
    wT[64 * 65 + k * 65 + h] = Wr[gidx];
  }
  __syncthreads();

  int w = (blockIdx.x * blockDim.x + threadIdx.x) >> 6;
  int lane = threadIdx.x & 63;
  if (w >= ndst) return;  // wave-uniform
  int g = lane >> 3;   // row slot within chunk
  int i = lane & 7;    // 16B sub-offset within row
  float aa[8];
  #pragma unroll
  for (int k = 0; k < 8; k++) aa[k] = 0.f;

  int s0 = off[w * R];
  int eN = off[(w + 1) * R];
  for (int r = 0; r < R; ++r) {
    int sseg = off[w * R + r], eseg = off[w * R + r + 1];
    for (int base = sseg; base < eseg; base += 64) {
      int cnw = eseg - base;
      if (cnw > 64) cnw = 64;
      int lim = cnw - 1;
      int my = nbr[base + (lane < cnw ? lane : 0)];  // coalesced window load
      uint4 d0, d1, d2, d3, d4, d5, d6, d7;
      int j0 = __shfl(my, min(0 * 8 + g, lim));
      int j1 = __shfl(my, min(1 * 8 + g, lim));
      d0 = *(const uint4*)(xsrc + (size_t)j0 * 64 + i * 8);
      d1 = *(const uint4*)(xsrc + (size_t)j1 * 64 + i * 8);
      bool mid = cnw > 16;
      bool hi = cnw > 32;
      if (mid) {
        int j2 = __shfl(my, min(2 * 8 + g, lim));
        int j3 = __shfl(my, min(3 * 8 + g, lim));
        d2 = *(const uint4*)(xsrc + (size_t)j2 * 64 + i * 8);
        d3 = *(const uint4*)(xsrc + (size_t)j3 * 64 + i * 8);
      }
      if (hi) {
        int j4 = __shfl(my, min(4 * 8 + g, lim));
        int j5 = __shfl(my, min(5 * 8 + g, lim));
        int j6 = __shfl(my, min(6 * 8 + g, lim));
        int j7 = __shfl(my, min(7 * 8 + g, lim));
        d4 = *(const uint4*)(xsrc + (size_t)j4 * 64 + i * 8);
        d5 = *(const uint4*)(xsrc + (size_t)j5 * 64 + i * 8);
        d6 = *(const uint4*)(xsrc + (size_t)j6 * 64 + i * 8);
        d7 = *(const uint4*)(xsrc + (size_t)j7 * 64 + i * 8);
      }
      #define CONSUME(dd, c)                                              \
        {                                                                 \
          float mc = ((c) * 8 + g < cnw) ? 1.f : 0.f;                     \
          aa[0] = fmaf(__uint_as_float(dd.x << 16), mc, aa[0]);           \
          aa[1] = fmaf(__uint_as_float(dd.x & 0xFFFF0000u), mc, aa[1]);   \
          aa[2] = fmaf(__uint_as_float(dd.y << 16), mc, aa[2]);           \
          aa[3] = fmaf(__uint_as_float(dd.y & 0xFFFF0000u), mc, aa[3]);   \
          aa[4] = fmaf(__uint_as_float(dd.z << 16), mc, aa[4]);           \
          aa[5] = fmaf(__uint_as_float(dd.z & 0xFFFF0000u), mc, aa[5]);   \
          aa[6] = fmaf(__uint_as_float(dd.w << 16), mc, aa[6]);           \
          aa[7] = fmaf(__uint_as_float(dd.w & 0xFFFF0000u), mc, aa[7]);   \
        }
      CONSUME(d0, 0)
      CONSUME(d1, 1)
      if (mid) {
        CONSUME(d2, 2)
        CONSUME(d3, 3)
      }
      if (hi) {
        CONSUME(d4, 4)
        CONSUME(d5, 5)
        CONSUME(d6, 6)
        CONSUME(d7, 7)
      }
      #undef CONSUME
    }
  }
  // cross-row-slot reduce: sum over g (lane bits 3..5)
  #pragma unroll
  for (int m = 8; m <= 32; m <<= 1) {
    #pragma unroll
    for (int k = 0; k < 8; k++) aa[k] += __shfl_xor(aa[k], m);
  }
  float inv = 1.0f / fmaxf((float)(eN - s0), 1.0f);
  #pragma unroll
  for (int k = 0; k < 8; k++) aa[k] *= inv;  // mean; lane holds f=8*(lane&7)+k
  float dv = bf2f(xdst[(size_t)w * 64 + lane]);

  // transform epilogue: LDS-resident transposed weights, conflict-free reads
  float acc = bias[lane];
  #pragma unroll
  for (int k = 0; k < 64; k++) {
    float mk = bcastf(aa[k & 7], k >> 3);
    acc = fmaf(mk, wT[k * 65 + lane], acc);
  }
  #pragma unroll
  for (int k = 0; k < 64; k++) {
    float dk = bcastf(dv, k);
    acc = fmaf(dk, wT[64 * 65 + k * 65 + lane], acc);
  }
  if (RELU) acc = fmaxf(acc, 0.0f);
  out[(size_t)w * 64 + lane] = f2bf(acc);
}

// 16 lanes per edge on bf16 rows (128B contiguous per row), shfl_xor
// reduce within the 16-lane group. 16 edges per 256-thread block.
__global__ void __launch_bounds__(256)
k_dot(const unsigned short* __restrict__ u2, const unsigned short* __restrict__ m2,
      const int* __restrict__ eu, const int* __restrict__ em,
      float* __restrict__ out, int L) {
  int wave = (blockIdx.x * blockDim.x + threadIdx.x) >> 6;
  int lane = threadIdx.x & 63;
  int sub = lane & 15;
  int l = wave * 4 + (lane >> 4);
  int lc = l < L ? l : (L - 1);
  int iu = eu[lc], im = em[lc];
  uint2 a = *(const uint2*)(u2 + (size_t)iu * 64 + sub * 4);
  uint2 b = *(const uint2*)(m2 + (size_t)im * 64 + sub * 4);
  float s = __uint_as_float(a.x << 16) * __uint_as_float(b.x << 16)
          + __uint_as_float(a.x & 0xFFFF0000u) * __uint_as_float(b.x & 0xFFFF0000u)
          + __uint_as_float(a.y << 16) * __uint_as_float(b.y << 16)
          + __uint_as_float(a.y & 0xFFFF0000u) * __uint_as_float(b.y & 0xFFFF0000u);
  s += __shfl_xor(s, 1);
  s += __shfl_xor(s, 2);
  s += __shfl_xor(s, 4);
  s += __shfl_xor(s, 8);
  if (sub == 0 && l < L) out[l] = s;
}

extern "C" void kernel_launch(void* const* d_in, const int* in_sizes, int n_in,
                              void* d_out, int out_size, void* d_ws, size_t ws_size,
                              hipStream_t stream) {
  const float* movie_x   = (const float*)d_in[2];
  const int*   esrc      = (const int*)d_in[3];
  const int*   edst      = (const int*)d_in[4];
  const int*   eli_u     = (const int*)d_in[5];
  const int*   eli_m     = (const int*)d_in[6];
  const float* user_emb  = (const float*)d_in[7];
  const float* movie_emb = (const float*)d_in[8];
  const float* lin_W     = (const float*)d_in[9];
  const float* lin_b     = (const float*)d_in[10];
  const float* W1um_l = (const float*)d_in[11];
  const float* W1um_r = (const float*)d_in[12];
  const float* W1mu_l = (const float*)d_in[13];
  const float* W1mu_r = (const float*)d_in[14];
  const float* W2um_l = (const float*)d_in[15];
  const float* W2um_r = (const float*)d_in[16];
  const float* W2mu_l = (const float*)d_in[17];
  const float* W2mu_r = (const float*)d_in[18];
  const float* b1um = (const float*)d_in[19];
  const float* b1mu = (const float*)d_in[20];
  const float* b2um = (const float*)d_in[21];
  const float* b2mu = (const float*)d_in[22];
  const int E = in_sizes[3];
  const int L = in_sizes[5];

  char* ws = (char*)d_ws;
  size_t o = 0;
  auto alloc = [&](size_t bytes) -> void* {
    void* p = ws + o;
    o = (o + bytes + 255) & ~(size_t)255;
    return p;
  };
  unsigned short* uemb_bf   = (unsigned short*)alloc((size_t)NU * 64 * 2);
  unsigned short* xmovie_bf = (unsigned short*)alloc((size_t)NM * 64 * 2);
  unsigned short* m1_bf     = (unsigned short*)alloc((size_t)NM * 64 * 2);
  unsigned short* u1_bf     = (unsigned short*)alloc((size_t)NU * 64 * 2);
  unsigned short* m2_bf     = (unsigned short*)alloc((size_t)NM * 64 * 2);
  unsigned short* u2_bf     = (unsigned short*)alloc((size_t)NU * 64 * 2);
  const int NKM = NM * RM;  // keys for movie-dest CSR
  const int NKU = NU * RU;  // keys for user-dest CSR
  int* cnt_m = (int*)alloc((size_t)NKM * 4);
  int* cnt_u = (int*)alloc((size_t)NKU * 4);
  int* off_m = (int*)alloc((size_t)(NKM + 1) * 4);
  int* off_u = (int*)alloc((size_t)(NKU + 1) * 4);
  int* cur_m = (int*)alloc((size_t)NKM * 4);
  int* cur_u = (int*)alloc((size_t)NKU * 4);
  int* bs_m  = (int*)alloc(4096);
  int* bs_u  = (int*)alloc(4096);
  int* nbr_m = (int*)alloc((size_t)E * 4);
  int* nbr_u = (int*)alloc((size_t)E * 4);

  hipMemsetAsync(cnt_m, 0, (size_t)NKM * 4, stream);
  hipMemsetAsync(cnt_u, 0, (size_t)NKU * 4, stream);

  int gE = (E + 255) / 256;
  k_count2<<<gE, 256, 0, stream>>>(esrc, edst, cnt_m, cnt_u, E);

  int nbm = (NKM + 1023) / 1024, nbu = (NKU + 1023) / 1024;
  k_scan_part<<<nbm, 256, 0, stream>>>(cnt_m, off_m, bs_m, NKM);
  k_scan_part<<<nbu, 256, 0, stream>>>(cnt_u, off_u, bs_u, NKU);
  k_scan_top<<<1, 64, 0, stream>>>(bs_m, nbm);
  k_scan_top<<<1, 64, 0, stream>>>(bs_u, nbu);
  k_scan_add<<<(NKM + 1 + 255) / 256, 256, 0, stream>>>(off_m, cur_m, bs_m, NKM, E);
  k_scan_add<<<(NKU + 1 + 255) / 256, 256, 0, stream>>>(off_u, cur_u, bs_u, NKU, E);

  // XCD-phased scatter: 256 chunks x 8 XCD-lanes
  int nchunk = 256;
  k_scatter_x<<<nchunk * 8, 256, 0, stream>>>(esrc, edst, cur_m, cur_u,
                                              nbr_m, nbr_u, E, nchunk);

  // bf16 gather tables
  int n4u = NU * 16;  // NU*64/4
  k_tobf4<<<(n4u + 255) / 256, 256, 0, stream>>>((const float4*)user_emb, uemb_bf, n4u);
  k_movie_init<<<(NM + 3) / 4, 256, 0, stream>>>(movie_x, lin_W, lin_b, movie_emb, xmovie_bf);

  int gM = (NM + 3) / 4, gU = (NU + 3) / 4;
  // layer 1 (ReLU)
  k_agg<1, RM><<<gM, 256, 0, stream>>>(uemb_bf, xmovie_bf, nbr_m, off_m,
                                       W1um_l, W1um_r, b1um, m1_bf, NM);
  k_agg<1, RU><<<gU, 256, 0, stream>>>(xmovie_bf, uemb_bf, nbr_u, off_u,
                                       W1mu_l, W1mu_r, b1mu, u1_bf, NU);
  // layer 2 (no activation)
  k_agg<0, RM><<<gM, 256, 0, stream>>>(u1_bf, m1_bf, nbr_m, off_m,
                                       W2um_l, W2um_r, b2um, m2_bf, NM);
  k_agg<0, RU><<<gU, 256, 0, stream>>>(m1_bf, u1_bf, nbr_u, off_u,
                                       W2mu_l, W2mu_r, b2mu, u2_bf, NU);

  // 16 edges per 256-thread block
  k_dot<<<(L + 15) / 16, 256, 0, stream>>>(u2_bf, m2_bf, eli_u, eli_m, (float*)d_out, L);
}

// Round 9
// 720.980 us; speedup vs baseline: 3.0519x; 1.4348x over previous
//
#include <hip/hip_runtime.h>

#define NU 100000
#define NM 50000
#define RM 4    // sub-ranges of the user table (gather source for movie-dest)
#define RU 2    // sub-ranges of the movie table (gather source for user-dest)
#define NBLK 256  // partition blocks
#define NBKT 196  // coarse buckets (50000>>8 -> 196, 100000>>9 -> 196)

__device__ __forceinline__ float bcastf(float v, int lane) {
  return __int_as_float(__builtin_amdgcn_readlane(__float_as_int(v), lane));
}
__device__ __forceinline__ unsigned short f2bf(float f) {
  unsigned u = __float_as_uint(f);
  u = u + 0x7FFF + ((u >> 16) & 1);  // round-to-nearest-even
  return (unsigned short)(u >> 16);
}
__device__ __forceinline__ float bf2f(unsigned short b) {
  return __uint_as_float(((unsigned)b) << 16);
}

// ---------- scan machinery (1024 elems/block) ----------
__global__ void k_scan_part(const int* __restrict__ cnt, int* __restrict__ off,
                            int* __restrict__ bsum, int n) {
  __shared__ int wsum[4];
  int t = threadIdx.x;
  int base = blockIdx.x * 1024 + t * 4;
  int v0 = (base + 0 < n) ? cnt[base + 0] : 0;
  int v1 = (base + 1 < n) ? cnt[base + 1] : 0;
  int v2 = (base + 2 < n) ? cnt[base + 2] : 0;
  int v3 = (base + 3 < n) ? cnt[base + 3] : 0;
  int s = v0 + v1 + v2 + v3;
  int lane = t & 63;
  int inc = s;
  #pragma unroll
  for (int d = 1; d < 64; d <<= 1) {
    int x = __shfl_up(inc, d);
    if (lane >= d) inc += x;
  }
  int wid = t >> 6;
  if (lane == 63) wsum[wid] = inc;
  __syncthreads();
  int woff = 0;
  for (int i = 0; i < wid; i++) woff += wsum[i];
  int excl = woff + inc - s;
  if (base + 0 < n) off[base + 0] = excl;
  if (base + 1 < n) off[base + 1] = excl + v0;
  if (base + 2 < n) off[base + 2] = excl + v0 + v1;
  if (base + 3 < n) off[base + 3] = excl + v0 + v1 + v2;
  if (t == 255) bsum[blockIdx.x] = woff + inc;
}

__global__ void k_scan_top(int* bsum, int nb) {
  int lane = threadIdx.x;  // block of 64
  int carry = 0;
  for (int base = 0; base < nb; base += 64) {
    int i = base + lane;
    int v = (i < nb) ? bsum[i] : 0;
    int inc = v;
    #pragma unroll
    for (int d = 1; d < 64; d <<= 1) {
      int x = __shfl_up(inc, d);
      if (lane >= d) inc += x;
    }
    if (i < nb) bsum[i] = carry + inc - v;
    carry += __shfl(inc, 63);
  }
}

__global__ void k_scan_add(int* __restrict__ off, int* __restrict__ cur,
                           const int* __restrict__ bsum, int n, int total) {
  int i = blockIdx.x * blockDim.x + threadIdx.x;
  if (i < n) {
    int v = off[i] + bsum[i >> 10];
    off[i] = v;
    cur[i] = v;
  } else if (i == n) {
    off[n] = total;
  }
}

// ---------- radix-partition CSR build ----------
// P1: per-(bucket, block) histogram of coarse key (node >> SH)
template <int SH>
__global__ void __launch_bounds__(256)
k_hist(const int* __restrict__ keys, int* __restrict__ hmat, int E) {
  __shared__ int h[256];
  int t = threadIdx.x;
  h[t] = 0;
  __syncthreads();
  int chunk = (E + NBLK - 1) / NBLK;
  int beg = blockIdx.x * chunk;
  int end = min(beg + chunk, E);
  for (int e = beg + t; e < end; e += 256)
    atomicAdd(&h[keys[e] >> SH], 1);
  __syncthreads();
  for (int b = t; b < NBKT; b += 256) hmat[b * NBLK + blockIdx.x] = h[b];
}

// P3: partition records into bucket-major order; each (bucket,block) run is
// contiguous (~300B) -> full-line writebacks.
template <int SH>
__global__ void __launch_bounds__(256)
k_part(const int* __restrict__ keys, const int* __restrict__ pays,
       const int* __restrict__ base, uint2* __restrict__ rec, int E) {
  __shared__ int cur[NBKT];
  int t = threadIdx.x;
  for (int b = t; b < NBKT; b += 256) cur[b] = base[b * NBLK + blockIdx.x];
  __syncthreads();
  int chunk = (E + NBLK - 1) / NBLK;
  int beg = blockIdx.x * chunk;
  int end = min(beg + chunk, E);
  for (int e = beg + t; e < end; e += 256) {
    int k = keys[e], p = pays[e];
    int pos = atomicAdd(&cur[k >> SH], 1);
    rec[pos] = make_uint2((unsigned)k, (unsigned)p);
  }
}

// P4: per-bucket fine counts in LDS window, coalesced writeout.
template <int R, int SH>
__global__ void __launch_bounds__(256)
k_bcount(const uint2* __restrict__ rec, const int* __restrict__ bstart,
         int* __restrict__ cnt, int N) {
  __shared__ int lcnt[1024];
  int b = blockIdx.x, t = threadIdx.x;
  int node_lo = b << SH;
  int wlen = (min(N - node_lo, 1 << SH)) * R;
  for (int i = t; i < wlen; i += 256) lcnt[i] = 0;
  __syncthreads();
  int rs = bstart[b * NBLK];
  int re = bstart[(b + 1) * NBLK];
  for (int r = rs + t; r < re; r += 256) {
    uint2 q = rec[r];
    atomicAdd(&lcnt[((int)q.x - node_lo) * R + (int)(q.y / 25000u)], 1);
  }
  __syncthreads();
  for (int i = t; i < wlen; i += 256) cnt[node_lo * R + i] = lcnt[i];
}

// P6: per-bucket scatter with LDS cursors; nbr writes land in an
// L2-resident ~100KB CSR window.
template <int R, int SH>
__global__ void __launch_bounds__(256)
k_bscatter(const uint2* __restrict__ rec, const int* __restrict__ bstart,
           const int* __restrict__ off, int* __restrict__ nbr, int N) {
  __shared__ int lcur[1024];
  int b = blockIdx.x, t = threadIdx.x;
  int node_lo = b << SH;
  int wlen = (min(N - node_lo, 1 << SH)) * R;
  for (int i = t; i < wlen; i += 256) lcur[i] = off[node_lo * R + i];
  __syncthreads();
  int rs = bstart[b * NBLK];
  int re = bstart[(b + 1) * NBLK];
  for (int r = rs + t; r < re; r += 256) {
    uint2 q = rec[r];
    int key = ((int)q.x - node_lo) * R + (int)(q.y / 25000u);
    int p = atomicAdd(&lcur[key], 1);
    nbr[p] = (int)q.y;
  }
}

// ---------- feature prep ----------
__global__ void k_tobf4(const float4* __restrict__ in, unsigned short* __restrict__ out, int n4) {
  int i = blockIdx.x * blockDim.x + threadIdx.x;
  if (i < n4) {
    float4 v = in[i];
    ushort4 o;
    o.x = f2bf(v.x); o.y = f2bf(v.y); o.z = f2bf(v.z); o.w = f2bf(v.w);
    *(ushort4*)(out + (size_t)i * 4) = o;
  }
}

__global__ void k_movie_init(const float* __restrict__ movie_x,
                             const float* __restrict__ lin_W,
                             const float* __restrict__ lin_b,
                             const float* __restrict__ movie_emb,
                             unsigned short* __restrict__ x_movie) {
  __shared__ float lwT[20 * 65];
  for (int gidx = threadIdx.x; gidx < 64 * 20; gidx += 256) {
    int h = gidx / 20;
    int f = gidx - h * 20;
    lwT[f * 65 + h] = lin_W[gidx];
  }
  __syncthreads();
  int w = (blockIdx.x * blockDim.x + threadIdx.x) >> 6;
  int h = threadIdx.x & 63;
  if (w >= NM) return;
  float acc = lin_b[h] + movie_emb[(size_t)w * 64 + h];
  const float* mx = movie_x + (size_t)w * 20;  // wave-uniform row (2 lines)
  #pragma unroll
  for (int f = 0; f < 20; f++) acc += mx[f] * lwT[f * 65 + h];
  x_movie[(size_t)w * 64 + h] = f2bf(acc);
}

// ---------- aggregation (unchanged from round 8) ----------
template <int RELU, int R>
__global__ void __launch_bounds__(256)
k_agg(const unsigned short* __restrict__ xsrc, const unsigned short* __restrict__ xdst,
      const int* __restrict__ nbr, const int* __restrict__ off,
      const float* __restrict__ Wl, const float* __restrict__ Wr,
      const float* __restrict__ bias, unsigned short* __restrict__ out, int ndst) {
  __shared__ float wT[2 * 64 * 65];
  for (int gidx = threadIdx.x; gidx < 4096; gidx += 256) {
    int h = gidx >> 6, k = gidx & 63;
    wT[k * 65 + h] = Wl[gidx];
    wT[64 * 65 + k * 65 + h] = Wr[gidx];
  }
  __syncthreads();

  int w = (blockIdx.x * blockDim.x + threadIdx.x) >> 6;
  int lane = threadIdx.x & 63;
  if (w >= ndst) return;  // wave-uniform
  int g = lane >> 3;   // row slot within chunk
  int i = lane & 7;    // 16B sub-offset within row
  float aa[8];
  #pragma unroll
  for (int k = 0; k < 8; k++) aa[k] = 0.f;

  int s0 = off[w * R];
  int eN = off[(w + 1) * R];
  for (int r = 0; r < R; ++r) {
    int sseg = off[w * R + r], eseg = off[w * R + r + 1];
    for (int base = sseg; base < eseg; base += 64) {
      int cnw = eseg - base;
      if (cnw > 64) cnw = 64;
      int lim = cnw - 1;
      int my = nbr[base + (lane < cnw ? lane : 0)];  // coalesced window load
      uint4 d0, d1, d2, d3, d4, d5, d6, d7;
      int j0 = __shfl(my, min(0 * 8 + g, lim));
      int j1 = __shfl(my, min(1 * 8 + g, lim));
      d0 = *(const uint4*)(xsrc + (size_t)j0 * 64 + i * 8);
      d1 = *(const uint4*)(xsrc + (size_t)j1 * 64 + i * 8);
      bool mid = cnw > 16;
      bool hi = cnw > 32;
      if (mid) {
        int j2 = __shfl(my, min(2 * 8 + g, lim));
        int j3 = __shfl(my, min(3 * 8 + g, lim));
        d2 = *(const uint4*)(xsrc + (size_t)j2 * 64 + i * 8);
        d3 = *(const uint4*)(xsrc + (size_t)j3 * 64 + i * 8);
      }
      if (hi) {
        int j4 = __shfl(my, min(4 * 8 + g, lim));
        int j5 = __shfl(my, min(5 * 8 + g, lim));
        int j6 = __shfl(my, min(6 * 8 + g, lim));
        int j7 = __shfl(my, min(7 * 8 + g, lim));
        d4 = *(const uint4*)(xsrc + (size_t)j4 * 64 + i * 8);
        d5 = *(const uint4*)(xsrc + (size_t)j5 * 64 + i * 8);
        d6 = *(const uint4*)(xsrc + (size_t)j6 * 64 + i * 8);
        d7 = *(const uint4*)(xsrc + (size_t)j7 * 64 + i * 8);
      }
      #define CONSUME(dd, c)                                              \
        {                                                                 \
          float mc = ((c) * 8 + g < cnw) ? 1.f : 0.f;                     \
          aa[0] = fmaf(__uint_as_float(dd.x << 16), mc, aa[0]);           \
          aa[1] = fmaf(__uint_as_float(dd.x & 0xFFFF0000u), mc, aa[1]);   \
          aa[2] = fmaf(__uint_as_float(dd.y << 16), mc, aa[2]);           \
          aa[3] = fmaf(__uint_as_float(dd.y & 0xFFFF0000u), mc, aa[3]);   \
          aa[4] = fmaf(__uint_as_float(dd.z << 16), mc, aa[4]);           \
          aa[5] = fmaf(__uint_as_float(dd.z & 0xFFFF0000u), mc, aa[5]);   \
          aa[6] = fmaf(__uint_as_float(dd.w << 16), mc, aa[6]);           \
          aa[7] = fmaf(__uint_as_float(dd.w & 0xFFFF0000u), mc, aa[7]);   \
        }
      CONSUME(d0, 0)
      CONSUME(d1, 1)
      if (mid) {
        CONSUME(d2, 2)
        CONSUME(d3, 3)
      }
      if (hi) {
        CONSUME(d4, 4)
        CONSUME(d5, 5)
        CONSUME(d6, 6)
        CONSUME(d7, 7)
      }
      #undef CONSUME
    }
  }
  // cross-row-slot reduce: sum over g (lane bits 3..5)
  #pragma unroll
  for (int m = 8; m <= 32; m <<= 1) {
    #pragma unroll
    for (int k = 0; k < 8; k++) aa[k] += __shfl_xor(aa[k], m);
  }
  float inv = 1.0f / fmaxf((float)(eN - s0), 1.0f);
  #pragma unroll
  for (int k = 0; k < 8; k++) aa[k] *= inv;  // mean; lane holds f=8*(lane&7)+k
  float dv = bf2f(xdst[(size_t)w * 64 + lane]);

  // transform epilogue: LDS-resident transposed weights, conflict-free reads
  float acc = bias[lane];
  #pragma unroll
  for (int k = 0; k < 64; k++) {
    float mk = bcastf(aa[k & 7], k >> 3);
    acc = fmaf(mk, wT[k * 65 + lane], acc);
  }
  #pragma unroll
  for (int k = 0; k < 64; k++) {
    float dk = bcastf(dv, k);
    acc = fmaf(dk, wT[64 * 65 + k * 65 + lane], acc);
  }
  if (RELU) acc = fmaxf(acc, 0.0f);
  out[(size_t)w * 64 + lane] = f2bf(acc);
}

// 16 lanes per edge on bf16 rows; shfl_xor reduce within 16-lane group.
__global__ void __launch_bounds__(256)
k_dot(const unsigned short* __restrict__ u2, const unsigned short* __restrict__ m2,
      const int* __restrict__ eu, const int* __restrict__ em,
      float* __restrict__ out, int L) {
  int wave = (blockIdx.x * blockDim.x + threadIdx.x) >> 6;
  int lane = threadIdx.x & 63;
  int sub = lane & 15;
  int l = wave * 4 + (lane >> 4);
  int lc = l < L ? l : (L - 1);
  int iu = eu[lc], im = em[lc];
  uint2 a = *(const uint2*)(u2 + (size_t)iu * 64 + sub * 4);
  uint2 b = *(const uint2*)(m2 + (size_t)im * 64 + sub * 4);
  float s = __uint_as_float(a.x << 16) * __uint_as_float(b.x << 16)
          + __uint_as_float(a.x & 0xFFFF0000u) * __uint_as_float(b.x & 0xFFFF0000u)
          + __uint_as_float(a.y << 16) * __uint_as_float(b.y << 16)
          + __uint_as_float(a.y & 0xFFFF0000u) * __uint_as_float(b.y & 0xFFFF0000u);
  s += __shfl_xor(s, 1);
  s += __shfl_xor(s, 2);
  s += __shfl_xor(s, 4);
  s += __shfl_xor(s, 8);
  if (sub == 0 && l < L) out[l] = s;
}

extern "C" void kernel_launch(void* const* d_in, const int* in_sizes, int n_in,
                              void* d_out, int out_size, void* d_ws, size_t ws_size,
                              hipStream_t stream) {
  const float* movie_x   = (const float*)d_in[2];
  const int*   esrc      = (const int*)d_in[3];
  const int*   edst      = (const int*)d_in[4];
  const int*   eli_u     = (const int*)d_in[5];
  const int*   eli_m     = (const int*)d_in[6];
  const float* user_emb  = (const float*)d_in[7];
  const float* movie_emb = (const float*)d_in[8];
  const float* lin_W     = (const float*)d_in[9];
  const float* lin_b     = (const float*)d_in[10];
  const float* W1um_l = (const float*)d_in[11];
  const float* W1um_r = (const float*)d_in[12];
  const float* W1mu_l = (const float*)d_in[13];
  const float* W1mu_r = (const float*)d_in[14];
  const float* W2um_l = (const float*)d_in[15];
  const float* W2um_r = (const float*)d_in[16];
  const float* W2mu_l = (const float*)d_in[17];
  const float* W2mu_r = (const float*)d_in[18];
  const float* b1um = (const float*)d_in[19];
  const float* b1mu = (const float*)d_in[20];
  const float* b2um = (const float*)d_in[21];
  const float* b2mu = (const float*)d_in[22];
  const int E = in_sizes[3];
  const int L = in_sizes[5];

  char* ws = (char*)d_ws;
  size_t o = 0;
  auto alloc = [&](size_t bytes) -> void* {
    void* p = ws + o;
    o = (o + bytes + 255) & ~(size_t)255;
    return p;
  };
  unsigned short* uemb_bf   = (unsigned short*)alloc((size_t)NU * 64 * 2);
  unsigned short* xmovie_bf = (unsigned short*)alloc((size_t)NM * 64 * 2);
  unsigned short* m1_bf     = (unsigned short*)alloc((size_t)NM * 64 * 2);
  unsigned short* u1_bf     = (unsigned short*)alloc((size_t)NU * 64 * 2);
  unsigned short* m2_bf     = (unsigned short*)alloc((size_t)NM * 64 * 2);
  unsigned short* u2_bf     = (unsigned short*)alloc((size_t)NU * 64 * 2);
  const int NKM = NM * RM;
  const int NKU = NU * RU;
  int* cnt_m = (int*)alloc((size_t)NKM * 4);
  int* cnt_u = (int*)alloc((size_t)NKU * 4);
  int* off_m = (int*)alloc((size_t)(NKM + 1) * 4);
  int* off_u = (int*)alloc((size_t)(NKU + 1) * 4);
  int* cur_m = (int*)alloc((size_t)NKM * 4);   // scan_add dummy
  int* cur_u = (int*)alloc((size_t)NKU * 4);   // scan_add dummy
  int* bs    = (int*)alloc(4096);
  int* nbr_m = (int*)alloc((size_t)E * 4);
  int* nbr_u = (int*)alloc((size_t)E * 4);
  const int NH = NBKT * NBLK;  // 50176
  int* hmat  = (int*)alloc((size_t)(NH + 1) * 4);
  int* hbase = (int*)alloc((size_t)(NH + 1) * 4);
  // rec (E x 8B = 20MB) overlays uemb/xmovie/m1 region -- dead until after
  // both CSR builds; feature prep runs after the builds.
  uint2* rec = (uint2*)uemb_bf;

  int gScanH = (NH + 1 + 255) / 256;
  int nbH = (NH + 1023) / 1024;  // 49

  // ===== build movie-dest CSR (key=d, payload=s) =====
  k_hist<8><<<NBLK, 256, 0, stream>>>(edst, hmat, E);
  k_scan_part<<<nbH, 256, 0, stream>>>(hmat, hbase, bs, NH);
  k_scan_top<<<1, 64, 0, stream>>>(bs, nbH);
  k_scan_add<<<gScanH, 256, 0, stream>>>(hbase, hbase, bs, NH, E);
  k_part<8><<<NBLK, 256, 0, stream>>>(edst, esrc, hbase, rec, E);
  k_bcount<RM, 8><<<NBKT, 256, 0, stream>>>(rec, hbase, cnt_m, NM);
  {
    int nb = (NKM + 1023) / 1024;
    k_scan_part<<<nb, 256, 0, stream>>>(cnt_m, off_m, bs, NKM);
    k_scan_top<<<1, 64, 0, stream>>>(bs, nb);
    k_scan_add<<<(NKM + 1 + 255) / 256, 256, 0, stream>>>(off_m, cur_m, bs, NKM, E);
  }
  k_bscatter<RM, 8><<<NBKT, 256, 0, stream>>>(rec, hbase, off_m, nbr_m, NM);

  // ===== build user-dest CSR (key=s, payload=d) =====
  k_hist<9><<<NBLK, 256, 0, stream>>>(esrc, hmat, E);
  k_scan_part<<<nbH, 256, 0, stream>>>(hmat, hbase, bs, NH);
  k_scan_top<<<1, 64, 0, stream>>>(bs, nbH);
  k_scan_add<<<gScanH, 256, 0, stream>>>(hbase, hbase, bs, NH, E);
  k_part<9><<<NBLK, 256, 0, stream>>>(esrc, edst, hbase, rec, E);
  k_bcount<RU, 9><<<NBKT, 256, 0, stream>>>(rec, hbase, cnt_u, NU);
  {
    int nb = (NKU + 1023) / 1024;
    k_scan_part<<<nb, 256, 0, stream>>>(cnt_u, off_u, bs, NKU);
    k_scan_top<<<1, 64, 0, stream>>>(bs, nb);
    k_scan_add<<<(NKU + 1 + 255) / 256, 256, 0, stream>>>(off_u, cur_u, bs, NKU, E);
  }
  k_bscatter<RU, 9><<<NBKT, 256, 0, stream>>>(rec, hbase, off_u, nbr_u, NU);

  // ===== feature prep (after builds: rec overlays these tables) =====
  int n4u = NU * 16;
  k_tobf4<<<(n4u + 255) / 256, 256, 0, stream>>>((const float4*)user_emb, uemb_bf, n4u);
  k_movie_init<<<(NM + 3) / 4, 256, 0, stream>>>(movie_x, lin_W, lin_b, movie_emb, xmovie_bf);

  int gM = (NM + 3) / 4, gU = (NU + 3) / 4;
  // layer 1 (ReLU)
  k_agg<1, RM><<<gM, 256, 0, stream>>>(uemb_bf, xmovie_bf, nbr_m, off_m,
                                       W1um_l, W1um_r, b1um, m1_bf, NM);
  k_agg<1, RU><<<gU, 256, 0, stream>>>(xmovie_bf, uemb_bf, nbr_u, off_u,
                                       W1mu_l, W1mu_r, b1mu, u1_bf, NU);
  // layer 2 (no activation)
  k_agg<0, RM><<<gM, 256, 0, stream>>>(u1_bf, m1_bf, nbr_m, off_m,
                                       W2um_l, W2um_r, b2um, m2_bf, NM);
  k_agg<0, RU><<<gU, 256, 0, stream>>>(m1_bf, u1_bf, nbr_u, off_u,
                                       W2mu_l, W2mu_r, b2mu, u2_bf, NU);

  // 16 edges per 256-thread block
  k_dot<<<(L + 15) / 16, 256, 0, stream>>>(u2_bf, m2_bf, eli_u, eli_m, (float*)d_out, L);
}

// Round 10
// 530.029 us; speedup vs baseline: 4.1514x; 1.3603x over previous
//
#include <hip/hip_runtime.h>

#define NU 100000
#define NM 50000
#define RM 4    // sub-ranges of the user table (gather source for movie-dest)
#define RU 2    // sub-ranges of the movie table (gather source for user-dest)
#define NBLK 256  // partition blocks
#define NBKT 196  // coarse buckets (50000>>8 -> 196, 100000>>9 -> 196)

typedef __attribute__((ext_vector_type(8))) short bf16x8;
typedef __attribute__((ext_vector_type(4))) float f32x4;

__device__ __forceinline__ unsigned short f2bf(float f) {
  unsigned u = __float_as_uint(f);
  u = u + 0x7FFF + ((u >> 16) & 1);  // round-to-nearest-even
  return (unsigned short)(u >> 16);
}
__device__ __forceinline__ float bf2f(unsigned short b) {
  return __uint_as_float(((unsigned)b) << 16);
}
__device__ __forceinline__ unsigned pk2(float a, float b) {
  return (unsigned)f2bf(a) | ((unsigned)f2bf(b) << 16);
}

// ---------- scan machinery (1024 elems/block) ----------
__global__ void k_scan_part(const int* __restrict__ cnt, int* __restrict__ off,
                            int* __restrict__ bsum, int n) {
  __shared__ int wsum[4];
  int t = threadIdx.x;
  int base = blockIdx.x * 1024 + t * 4;
  int v0 = (base + 0 < n) ? cnt[base + 0] : 0;
  int v1 = (base + 1 < n) ? cnt[base + 1] : 0;
  int v2 = (base + 2 < n) ? cnt[base + 2] : 0;
  int v3 = (base + 3 < n) ? cnt[base + 3] : 0;
  int s = v0 + v1 + v2 + v3;
  int lane = t & 63;
  int inc = s;
  #pragma unroll
  for (int d = 1; d < 64; d <<= 1) {
    int x = __shfl_up(inc, d);
    if (lane >= d) inc += x;
  }
  int wid = t >> 6;
  if (lane == 63) wsum[wid] = inc;
  __syncthreads();
  int woff = 0;
  for (int i = 0; i < wid; i++) woff += wsum[i];
  int excl = woff + inc - s;
  if (base + 0 < n) off[base + 0] = excl;
  if (base + 1 < n) off[base + 1] = excl + v0;
  if (base + 2 < n) off[base + 2] = excl + v0 + v1;
  if (base + 3 < n) off[base + 3] = excl + v0 + v1 + v2;
  if (t == 255) bsum[blockIdx.x] = woff + inc;
}

__global__ void k_scan_top(int* bsum, int nb) {
  int lane = threadIdx.x;  // block of 64
  int carry = 0;
  for (int base = 0; base < nb; base += 64) {
    int i = base + lane;
    int v = (i < nb) ? bsum[i] : 0;
    int inc = v;
    #pragma unroll
    for (int d = 1; d < 64; d <<= 1) {
      int x = __shfl_up(inc, d);
      if (lane >= d) inc += x;
    }
    if (i < nb) bsum[i] = carry + inc - v;
    carry += __shfl(inc, 63);
  }
}

__global__ void k_scan_add(int* __restrict__ off, int* __restrict__ cur,
                           const int* __restrict__ bsum, int n, int total) {
  int i = blockIdx.x * blockDim.x + threadIdx.x;
  if (i < n) {
    int v = off[i] + bsum[i >> 10];
    off[i] = v;
    cur[i] = v;
  } else if (i == n) {
    off[n] = total;
  }
}

// ---------- radix-partition CSR build ----------
template <int SH>
__global__ void __launch_bounds__(256)
k_hist(const int* __restrict__ keys, int* __restrict__ hmat, int E) {
  __shared__ int h[256];
  int t = threadIdx.x;
  h[t] = 0;
  __syncthreads();
  int chunk = (E + NBLK - 1) / NBLK;
  int beg = blockIdx.x * chunk;
  int end = min(beg + chunk, E);
  for (int e = beg + t; e < end; e += 256)
    atomicAdd(&h[keys[e] >> SH], 1);
  __syncthreads();
  for (int b = t; b < NBKT; b += 256) hmat[b * NBLK + blockIdx.x] = h[b];
}

template <int SH>
__global__ void __launch_bounds__(256)
k_part(const int* __restrict__ keys, const int* __restrict__ pays,
       const int* __restrict__ base, uint2* __restrict__ rec, int E) {
  __shared__ int cur[NBKT];
  int t = threadIdx.x;
  for (int b = t; b < NBKT; b += 256) cur[b] = base[b * NBLK + blockIdx.x];
  __syncthreads();
  int chunk = (E + NBLK - 1) / NBLK;
  int beg = blockIdx.x * chunk;
  int end = min(beg + chunk, E);
  for (int e = beg + t; e < end; e += 256) {
    int k = keys[e], p = pays[e];
    int pos = atomicAdd(&cur[k >> SH], 1);
    rec[pos] = make_uint2((unsigned)k, (unsigned)p);
  }
}

template <int R, int SH>
__global__ void __launch_bounds__(256)
k_bcount(const uint2* __restrict__ rec, const int* __restrict__ bstart,
         int* __restrict__ cnt, int N) {
  __shared__ int lcnt[1024];
  int b = blockIdx.x, t = threadIdx.x;
  int node_lo = b << SH;
  int wlen = (min(N - node_lo, 1 << SH)) * R;
  for (int i = t; i < wlen; i += 256) lcnt[i] = 0;
  __syncthreads();
  int rs = bstart[b * NBLK];
  int re = bstart[(b + 1) * NBLK];
  for (int r = rs + t; r < re; r += 256) {
    uint2 q = rec[r];
    atomicAdd(&lcnt[((int)q.x - node_lo) * R + (int)(q.y / 25000u)], 1);
  }
  __syncthreads();
  for (int i = t; i < wlen; i += 256) cnt[node_lo * R + i] = lcnt[i];
}

template <int R, int SH>
__global__ void __launch_bounds__(256)
k_bscatter(const uint2* __restrict__ rec, const int* __restrict__ bstart,
           const int* __restrict__ off, int* __restrict__ nbr, int N) {
  __shared__ int lcur[1024];
  int b = blockIdx.x, t = threadIdx.x;
  int node_lo = b << SH;
  int wlen = (min(N - node_lo, 1 << SH)) * R;
  for (int i = t; i < wlen; i += 256) lcur[i] = off[node_lo * R + i];
  __syncthreads();
  int rs = bstart[b * NBLK];
  int re = bstart[(b + 1) * NBLK];
  for (int r = rs + t; r < re; r += 256) {
    uint2 q = rec[r];
    int key = ((int)q.x - node_lo) * R + (int)(q.y / 25000u);
    int p = atomicAdd(&lcur[key], 1);
    nbr[p] = (int)q.y;
  }
}

// ---------- feature prep ----------
__global__ void k_tobf4(const float4* __restrict__ in, unsigned short* __restrict__ out, int n4) {
  int i = blockIdx.x * blockDim.x + threadIdx.x;
  if (i < n4) {
    float4 v = in[i];
    ushort4 o;
    o.x = f2bf(v.x); o.y = f2bf(v.y); o.z = f2bf(v.z); o.w = f2bf(v.w);
    *(ushort4*)(out + (size_t)i * 4) = o;
  }
}

__global__ void k_movie_init(const float* __restrict__ movie_x,
                             const float* __restrict__ lin_W,
                             const float* __restrict__ lin_b,
                             const float* __restrict__ movie_emb,
                             unsigned short* __restrict__ x_movie) {
  __shared__ float lwT[20 * 65];
  for (int gidx = threadIdx.x; gidx < 64 * 20; gidx += 256) {
    int h = gidx / 20;
    int f = gidx - h * 20;
    lwT[f * 65 + h] = lin_W[gidx];
  }
  __syncthreads();
  int w = (blockIdx.x * blockDim.x + threadIdx.x) >> 6;
  int h = threadIdx.x & 63;
  if (w >= NM) return;
  float acc = lin_b[h] + movie_emb[(size_t)w * 64 + h];
  const float* mx = movie_x + (size_t)w * 20;
  #pragma unroll
  for (int f = 0; f < 20; f++) acc += mx[f] * lwT[f * 65 + h];
  x_movie[(size_t)w * 64 + h] = f2bf(acc);
}

// pack [Wl|Wr] (f32 64x64 each) into bf16 Wcat[64][128]
__global__ void k_wcat(const float* __restrict__ Wl, const float* __restrict__ Wr,
                       unsigned short* __restrict__ Wc) {
  int i = blockIdx.x * 256 + threadIdx.x;  // 64*128
  if (i >= 8192) return;
  int h = i >> 7, k = i & 127;
  float v = (k < 64) ? Wl[h * 64 + k] : Wr[h * 64 + (k - 64)];
  Wc[i] = f2bf(v);
}

// ---------- mean-gather (no transform): one wave per destination node ----------
// Packed gather: lane l = (row-slot g=l>>3, 16B-chunk i=l&7); one dwordx4
// gathers 8 neighbor rows. Segment-ordered CSR (R source sub-ranges, each
// ~3.2MB L2-resident). Writes mean as bf16 row (lanes g==0, 128B contig).
template <int R>
__global__ void __launch_bounds__(256)
k_gmean(const unsigned short* __restrict__ xsrc, const int* __restrict__ nbr,
        const int* __restrict__ off, unsigned short* __restrict__ meanT, int ndst) {
  int w = (blockIdx.x * blockDim.x + threadIdx.x) >> 6;
  int lane = threadIdx.x & 63;
  if (w >= ndst) return;  // wave-uniform
  int g = lane >> 3;
  int i = lane & 7;
  float aa[8];
  #pragma unroll
  for (int k = 0; k < 8; k++) aa[k] = 0.f;

  int s0 = off[w * R];
  int eN = off[(w + 1) * R];
  for (int r = 0; r < R; ++r) {
    int sseg = off[w * R + r], eseg = off[w * R + r + 1];
    for (int base = sseg; base < eseg; base += 64) {
      int cnw = eseg - base;
      if (cnw > 64) cnw = 64;
      int lim = cnw - 1;
      int my = nbr[base + (lane < cnw ? lane : 0)];
      uint4 d0, d1, d2, d3, d4, d5, d6, d7;
      int j0 = __shfl(my, min(0 * 8 + g, lim));
      int j1 = __shfl(my, min(1 * 8 + g, lim));
      d0 = *(const uint4*)(xsrc + (size_t)j0 * 64 + i * 8);
      d1 = *(const uint4*)(xsrc + (size_t)j1 * 64 + i * 8);
      bool mid = cnw > 16;
      bool hi = cnw > 32;
      if (mid) {
        int j2 = __shfl(my, min(2 * 8 + g, lim));
        int j3 = __shfl(my, min(3 * 8 + g, lim));
        d2 = *(const uint4*)(xsrc + (size_t)j2 * 64 + i * 8);
        d3 = *(const uint4*)(xsrc + (size_t)j3 * 64 + i * 8);
      }
      if (hi) {
        int j4 = __shfl(my, min(4 * 8 + g, lim));
        int j5 = __shfl(my, min(5 * 8 + g, lim));
        int j6 = __shfl(my, min(6 * 8 + g, lim));
        int j7 = __shfl(my, min(7 * 8 + g, lim));
        d4 = *(const uint4*)(xsrc + (size_t)j4 * 64 + i * 8);
        d5 = *(const uint4*)(xsrc + (size_t)j5 * 64 + i * 8);
        d6 = *(const uint4*)(xsrc + (size_t)j6 * 64 + i * 8);
        d7 = *(const uint4*)(xsrc + (size_t)j7 * 64 + i * 8);
      }
      #define CONSUME(dd, c)                                              \
        {                                                                 \
          float mc = ((c) * 8 + g < cnw) ? 1.f : 0.f;                     \
          aa[0] = fmaf(__uint_as_float(dd.x << 16), mc, aa[0]);           \
          aa[1] = fmaf(__uint_as_float(dd.x & 0xFFFF0000u), mc, aa[1]);   \
          aa[2] = fmaf(__uint_as_float(dd.y << 16), mc, aa[2]);           \
          aa[3] = fmaf(__uint_as_float(dd.y & 0xFFFF0000u), mc, aa[3]);   \
          aa[4] = fmaf(__uint_as_float(dd.z << 16), mc, aa[4]);           \
          aa[5] = fmaf(__uint_as_float(dd.z & 0xFFFF0000u), mc, aa[5]);   \
          aa[6] = fmaf(__uint_as_float(dd.w << 16), mc, aa[6]);           \
          aa[7] = fmaf(__uint_as_float(dd.w & 0xFFFF0000u), mc, aa[7]);   \
        }
      CONSUME(d0, 0)
      CONSUME(d1, 1)
      if (mid) {
        CONSUME(d2, 2)
        CONSUME(d3, 3)
      }
      if (hi) {
        CONSUME(d4, 4)
        CONSUME(d5, 5)
        CONSUME(d6, 6)
        CONSUME(d7, 7)
      }
      #undef CONSUME
    }
  }
  #pragma unroll
  for (int m = 8; m <= 32; m <<= 1) {
    #pragma unroll
    for (int k = 0; k < 8; k++) aa[k] += __shfl_xor(aa[k], m);
  }
  float inv = 1.0f / fmaxf((float)(eN - s0), 1.0f);
  if (g == 0) {  // lanes 0..7: lane i holds features i*8..i*8+7
    uint4 o;
    o.x = pk2(aa[0] * inv, aa[1] * inv);
    o.y = pk2(aa[2] * inv, aa[3] * inv);
    o.z = pk2(aa[4] * inv, aa[5] * inv);
    o.w = pk2(aa[6] * inv, aa[7] * inv);
    *(uint4*)(meanT + ((size_t)w << 6) + i * 8) = o;
  }
}

// ---------- SAGE transform as MFMA GEMM ----------
// out[n][h] = (ReLU?) bias[h] + sum_k [mean|dv][n][k] * Wcat[h][k], K=128.
// Per wave: 16 nodes x 64 feats = 16x mfma_f32_16x16x32_bf16.
// A frag: row=lane&15, k=(lane>>4)*8+j (8 contiguous bf16 = 16B load).
// B frag: col(h)=lane&15, same k pattern -> row of Wcat, 16B load.
// D (verified m89): col=lane&15, row=(lane>>4)*4+reg.
// Epilogue: LDS transpose -> fully coalesced 128B bf16 row stores.
template <int RELU>
__global__ void __launch_bounds__(256)
k_sage_gemm(const unsigned short* __restrict__ meanT,
            const unsigned short* __restrict__ dvT,
            const unsigned short* __restrict__ Wc,   // [64][128] bf16
            const float* __restrict__ bias,
            unsigned short* __restrict__ outT, int N) {
  __shared__ float ot[4][16][68];
  int wv4 = threadIdx.x >> 6;
  int wvg = (blockIdx.x * blockDim.x + threadIdx.x) >> 6;
  int lane = threadIdx.x & 63;
  int n0 = wvg * 16;
  bool active = n0 < N;
  int rr = lane & 15;   // A row-in-tile / B col (h within htile)
  int ks = lane >> 4;   // K slot: k = ks*8 + j within each 32-K step

  if (active) {
    bf16x8 bf[4][4];
    #pragma unroll
    for (int t = 0; t < 4; t++)
      #pragma unroll
      for (int kk = 0; kk < 4; kk++)
        bf[t][kk] = *(const bf16x8*)(Wc + ((t * 16 + rr) << 7) + kk * 32 + ks * 8);
    f32x4 acc[4];
    #pragma unroll
    for (int t = 0; t < 4; t++) {
      float b = bias[t * 16 + rr];
      acc[t] = (f32x4){b, b, b, b};
    }
    const unsigned short* am = meanT + ((size_t)(n0 + rr) << 6);
    const unsigned short* ad = dvT + ((size_t)(n0 + rr) << 6);
    bf16x8 af[4];
    af[0] = *(const bf16x8*)(am + ks * 8);
    af[1] = *(const bf16x8*)(am + 32 + ks * 8);
    af[2] = *(const bf16x8*)(ad + ks * 8);
    af[3] = *(const bf16x8*)(ad + 32 + ks * 8);
    #pragma unroll
    for (int kk = 0; kk < 4; kk++)
      #pragma unroll
      for (int t = 0; t < 4; t++)
        acc[t] = __builtin_amdgcn_mfma_f32_16x16x32_bf16(af[kk], bf[t][kk], acc[t], 0, 0, 0);
    #pragma unroll
    for (int t = 0; t < 4; t++)
      #pragma unroll
      for (int r = 0; r < 4; r++) {
        float v = acc[t][r];
        if (RELU) v = fmaxf(v, 0.f);
        ot[wv4][(lane >> 4) * 4 + r][t * 16 + rr] = v;
      }
  }
  __syncthreads();
  if (active) {
    int nn = lane >> 2, c4 = lane & 3;
    const float* src = &ot[wv4][nn][c4 * 16];
    uint4 o0, o1;
    o0.x = pk2(src[0], src[1]);  o0.y = pk2(src[2], src[3]);
    o0.z = pk2(src[4], src[5]);  o0.w = pk2(src[6], src[7]);
    o1.x = pk2(src[8], src[9]);  o1.y = pk2(src[10], src[11]);
    o1.z = pk2(src[12], src[13]); o1.w = pk2(src[14], src[15]);
    unsigned short* dst = outT + ((size_t)(n0 + nn) << 6) + c4 * 16;
    *(uint4*)dst = o0;
    *(uint4*)(dst + 8) = o1;
  }
}

// 16 lanes per edge on bf16 rows; shfl_xor reduce within 16-lane group.
__global__ void __launch_bounds__(256)
k_dot(const unsigned short* __restrict__ u2, const unsigned short* __restrict__ m2,
      const int* __restrict__ eu, const int* __restrict__ em,
      float* __restrict__ out, int L) {
  int wave = (blockIdx.x * blockDim.x + threadIdx.x) >> 6;
  int lane = threadIdx.x & 63;
  int sub = lane & 15;
  int l = wave * 4 + (lane >> 4);
  int lc = l < L ? l : (L - 1);
  int iu = eu[lc], im = em[lc];
  uint2 a = *(const uint2*)(u2 + (size_t)iu * 64 + sub * 4);
  uint2 b = *(const uint2*)(m2 + (size_t)im * 64 + sub * 4);
  float s = __uint_as_float(a.x << 16) * __uint_as_float(b.x << 16)
          + __uint_as_float(a.x & 0xFFFF0000u) * __uint_as_float(b.x & 0xFFFF0000u)
          + __uint_as_float(a.y << 16) * __uint_as_float(b.y << 16)
          + __uint_as_float(a.y & 0xFFFF0000u) * __uint_as_float(b.y & 0xFFFF0000u);
  s += __shfl_xor(s, 1);
  s += __shfl_xor(s, 2);
  s += __shfl_xor(s, 4);
  s += __shfl_xor(s, 8);
  if (sub == 0 && l < L) out[l] = s;
}

extern "C" void kernel_launch(void* const* d_in, const int* in_sizes, int n_in,
                              void* d_out, int out_size, void* d_ws, size_t ws_size,
                              hipStream_t stream) {
  const float* movie_x   = (const float*)d_in[2];
  const int*   esrc      = (const int*)d_in[3];
  const int*   edst      = (const int*)d_in[4];
  const int*   eli_u     = (const int*)d_in[5];
  const int*   eli_m     = (const int*)d_in[6];
  const float* user_emb  = (const float*)d_in[7];
  const float* movie_emb = (const float*)d_in[8];
  const float* lin_W     = (const float*)d_in[9];
  const float* lin_b     = (const float*)d_in[10];
  const float* W1um_l = (const float*)d_in[11];
  const float* W1um_r = (const float*)d_in[12];
  const float* W1mu_l = (const float*)d_in[13];
  const float* W1mu_r = (const float*)d_in[14];
  const float* W2um_l = (const float*)d_in[15];
  const float* W2um_r = (const float*)d_in[16];
  const float* W2mu_l = (const float*)d_in[17];
  const float* W2mu_r = (const float*)d_in[18];
  const float* b1um = (const float*)d_in[19];
  const float* b1mu = (const float*)d_in[20];
  const float* b2um = (const float*)d_in[21];
  const float* b2mu = (const float*)d_in[22];
  const int E = in_sizes[3];
  const int L = in_sizes[5];

  char* ws = (char*)d_ws;
  size_t o = 0;
  auto alloc = [&](size_t bytes) -> void* {
    void* p = ws + o;
    o = (o + bytes + 255) & ~(size_t)255;
    return p;
  };
  unsigned short* uemb_bf   = (unsigned short*)alloc((size_t)NU * 64 * 2);
  unsigned short* xmovie_bf = (unsigned short*)alloc((size_t)NM * 64 * 2);
  unsigned short* m1_bf     = (unsigned short*)alloc((size_t)NM * 64 * 2);
  unsigned short* u1_bf     = (unsigned short*)alloc((size_t)NU * 64 * 2);
  unsigned short* m2_bf     = (unsigned short*)alloc((size_t)NM * 64 * 2);
  unsigned short* u2_bf     = (unsigned short*)alloc((size_t)NU * 64 * 2);
  unsigned short* mean_m    = (unsigned short*)alloc((size_t)NM * 64 * 2);
  unsigned short* mean_u    = (unsigned short*)alloc((size_t)NU * 64 * 2);
  unsigned short* wc1um = (unsigned short*)alloc(8192 * 2);
  unsigned short* wc1mu = (unsigned short*)alloc(8192 * 2);
  unsigned short* wc2um = (unsigned short*)alloc(8192 * 2);
  unsigned short* wc2mu = (unsigned short*)alloc(8192 * 2);
  const int NKM = NM * RM;
  const int NKU = NU * RU;
  int* cnt_m = (int*)alloc((size_t)NKM * 4);
  int* cnt_u = (int*)alloc((size_t)NKU * 4);
  int* off_m = (int*)alloc((size_t)(NKM + 1) * 4);
  int* off_u = (int*)alloc((size_t)(NKU + 1) * 4);
  int* cur_m = (int*)alloc((size_t)NKM * 4);   // scan_add dummy
  int* cur_u = (int*)alloc((size_t)NKU * 4);   // scan_add dummy
  int* bs    = (int*)alloc(4096);
  int* nbr_m = (int*)alloc((size_t)E * 4);
  int* nbr_u = (int*)alloc((size_t)E * 4);
  const int NH = NBKT * NBLK;
  int* hmat  = (int*)alloc((size_t)(NH + 1) * 4);
  int* hbase = (int*)alloc((size_t)(NH + 1) * 4);
  // rec (E x 8B = 20MB) overlays uemb/xmovie/m1 (25.6MB contiguous) --
  // dead until after both CSR builds; feature prep runs after the builds.
  uint2* rec = (uint2*)uemb_bf;

  int gScanH = (NH + 1 + 255) / 256;
  int nbH = (NH + 1023) / 1024;

  // ===== build movie-dest CSR (key=d, payload=s) =====
  k_hist<8><<<NBLK, 256, 0, stream>>>(edst, hmat, E);
  k_scan_part<<<nbH, 256, 0, stream>>>(hmat, hbase, bs, NH);
  k_scan_top<<<1, 64, 0, stream>>>(bs, nbH);
  k_scan_add<<<gScanH, 256, 0, stream>>>(hbase, hbase, bs, NH, E);
  k_part<8><<<NBLK, 256, 0, stream>>>(edst, esrc, hbase, rec, E);
  k_bcount<RM, 8><<<NBKT, 256, 0, stream>>>(rec, hbase, cnt_m, NM);
  {
    int nb = (NKM + 1023) / 1024;
    k_scan_part<<<nb, 256, 0, stream>>>(cnt_m, off_m, bs, NKM);
    k_scan_top<<<1, 64, 0, stream>>>(bs, nb);
    k_scan_add<<<(NKM + 1 + 255) / 256, 256, 0, stream>>>(off_m, cur_m, bs, NKM, E);
  }
  k_bscatter<RM, 8><<<NBKT, 256, 0, stream>>>(rec, hbase, off_m, nbr_m, NM);

  // ===== build user-dest CSR (key=s, payload=d) =====
  k_hist<9><<<NBLK, 256, 0, stream>>>(esrc, hmat, E);
  k_scan_part<<<nbH, 256, 0, stream>>>(hmat, hbase, bs, NH);
  k_scan_top<<<1, 64, 0, stream>>>(bs, nbH);
  k_scan_add<<<gScanH, 256, 0, stream>>>(hbase, hbase, bs, NH, E);
  k_part<9><<<NBLK, 256, 0, stream>>>(esrc, edst, hbase, rec, E);
  k_bcount<RU, 9><<<NBKT, 256, 0, stream>>>(rec, hbase, cnt_u, NU);
  {
    int nb = (NKU + 1023) / 1024;
    k_scan_part<<<nb, 256, 0, stream>>>(cnt_u, off_u, bs, NKU);
    k_scan_top<<<1, 64, 0, stream>>>(bs, nb);
    k_scan_add<<<(NKU + 1 + 255) / 256, 256, 0, stream>>>(off_u, cur_u, bs, NKU, E);
  }
  k_bscatter<RU, 9><<<NBKT, 256, 0, stream>>>(rec, hbase, off_u, nbr_u, NU);

  // ===== feature prep (after builds: rec overlays these tables) =====
  int n4u = NU * 16;
  k_tobf4<<<(n4u + 255) / 256, 256, 0, stream>>>((const float4*)user_emb, uemb_bf, n4u);
  k_movie_init<<<(NM + 3) / 4, 256, 0, stream>>>(movie_x, lin_W, lin_b, movie_emb, xmovie_bf);
  k_wcat<<<32, 256, 0, stream>>>(W1um_l, W1um_r, wc1um);
  k_wcat<<<32, 256, 0, stream>>>(W1mu_l, W1mu_r, wc1mu);
  k_wcat<<<32, 256, 0, stream>>>(W2um_l, W2um_r, wc2um);
  k_wcat<<<32, 256, 0, stream>>>(W2mu_l, W2mu_r, wc2mu);

  int gM = (NM + 3) / 4, gU = (NU + 3) / 4;
  int gGm = (NM / 16 + 3) / 4, gGu = (NU / 16 + 3) / 4;
  // layer 1
  k_gmean<RM><<<gM, 256, 0, stream>>>(uemb_bf, nbr_m, off_m, mean_m, NM);
  k_gmean<RU><<<gU, 256, 0, stream>>>(xmovie_bf, nbr_u, off_u, mean_u, NU);
  k_sage_gemm<1><<<gGm, 256, 0, stream>>>(mean_m, xmovie_bf, wc1um, b1um, m1_bf, NM);
  k_sage_gemm<1><<<gGu, 256, 0, stream>>>(mean_u, uemb_bf, wc1mu, b1mu, u1_bf, NU);
  // layer 2
  k_gmean<RM><<<gM, 256, 0, stream>>>(u1_bf, nbr_m, off_m, mean_m, NM);
  k_gmean<RU><<<gU, 256, 0, stream>>>(m1_bf, nbr_u, off_u, mean_u, NU);
  k_sage_gemm<0><<<gGm, 256, 0, stream>>>(mean_m, m1_bf, wc2um, b2um, m2_bf, NM);
  k_sage_gemm<0><<<gGu, 256, 0, stream>>>(mean_u, u1_bf, wc2mu, b2mu, u2_bf, NU);

  // 16 edges per 256-thread block
  k_dot<<<(L + 15) / 16, 256, 0, stream>>>(u2_bf, m2_bf, eli_u, eli_m, (float*)d_out, L);
}

// Round 11
// 442.625 us; speedup vs baseline: 4.9711x; 1.1975x over previous
//
#include <hip/hip_runtime.h>

#define NU 100000
#define NM 50000
#define RM 4      // user-table sub-ranges (movie-dest gather source)
#define RU 2      // movie-table sub-ranges (user-dest gather source)
#define NBLK 256  // partition blocks
#define NBKT 196  // coarse buckets (50000>>8 -> 196, 100000>>9 -> 196)
#define NH (NBKT * NBLK)
#define NKM (NM * RM)
#define NKU (NU * RU)

typedef __attribute__((ext_vector_type(8))) short bf16x8;
typedef __attribute__((ext_vector_type(4))) float f32x4;

__device__ __forceinline__ unsigned short f2bf(float f) {
  unsigned u = __float_as_uint(f);
  u = u + 0x7FFF + ((u >> 16) & 1);
  return (unsigned short)(u >> 16);
}
__device__ __forceinline__ float bf2f(unsigned short b) {
  return __uint_as_float(((unsigned)b) << 16);
}
__device__ __forceinline__ unsigned pk2(float a, float b) {
  return (unsigned)f2bf(a) | ((unsigned)f2bf(b) << 16);
}

// ---------- scan machinery ----------
__global__ void k_scan_part(const int* __restrict__ cnt, int* __restrict__ off,
                            int* __restrict__ bsum, int n) {
  __shared__ int wsum[4];
  int t = threadIdx.x;
  int base = blockIdx.x * 1024 + t * 4;
  int v0 = (base + 0 < n) ? cnt[base + 0] : 0;
  int v1 = (base + 1 < n) ? cnt[base + 1] : 0;
  int v2 = (base + 2 < n) ? cnt[base + 2] : 0;
  int v3 = (base + 3 < n) ? cnt[base + 3] : 0;
  int s = v0 + v1 + v2 + v3;
  int lane = t & 63;
  int inc = s;
  #pragma unroll
  for (int d = 1; d < 64; d <<= 1) {
    int x = __shfl_up(inc, d);
    if (lane >= d) inc += x;
  }
  int wid = t >> 6;
  if (lane == 63) wsum[wid] = inc;
  __syncthreads();
  int woff = 0;
  for (int i = 0; i < wid; i++) woff += wsum[i];
  int excl = woff + inc - s;
  if (base + 0 < n) off[base + 0] = excl;
  if (base + 1 < n) off[base + 1] = excl + v0;
  if (base + 2 < n) off[base + 2] = excl + v0 + v1;
  if (base + 3 < n) off[base + 3] = excl + v0 + v1 + v2;
  if (t == 255) bsum[blockIdx.x] = woff + inc;
}

__global__ void k_scan_top(int* bsum, int nb) {
  int lane = threadIdx.x;
  int carry = 0;
  for (int base = 0; base < nb; base += 64) {
    int i = base + lane;
    int v = (i < nb) ? bsum[i] : 0;
    int inc = v;
    #pragma unroll
    for (int d = 1; d < 64; d <<= 1) {
      int x = __shfl_up(inc, d);
      if (lane >= d) inc += x;
    }
    if (i < nb) bsum[i] = carry + inc - v;
    carry += __shfl(inc, 63);
  }
}

__global__ void k_scan_add(int* __restrict__ off, int* __restrict__ cur,
                           const int* __restrict__ bsum, int n, int total) {
  int i = blockIdx.x * blockDim.x + threadIdx.x;
  if (i < n) {
    int v = off[i] + bsum[i >> 10];
    off[i] = v;
    cur[i] = v;
  } else if (i == n) {
    off[n] = total;
  }
}

// ---------- merged radix-partition build (both CSRs per pass) ----------
__global__ void __launch_bounds__(256)
k_hist2(const int* __restrict__ esrc, const int* __restrict__ edst,
        int* __restrict__ hmat, int E) {
  __shared__ int hm[NBKT], hu[NBKT];
  int t = threadIdx.x;
  for (int b = t; b < NBKT; b += 256) { hm[b] = 0; hu[b] = 0; }
  __syncthreads();
  int chunk = (E + NBLK - 1) / NBLK;
  int beg = blockIdx.x * chunk;
  int end = min(beg + chunk, E);
  for (int e = beg + t; e < end; e += 256) {
    atomicAdd(&hm[edst[e] >> 8], 1);
    atomicAdd(&hu[esrc[e] >> 9], 1);
  }
  __syncthreads();
  for (int b = t; b < NBKT; b += 256) {
    hmat[b * NBLK + blockIdx.x] = hm[b];
    hmat[NH + b * NBLK + blockIdx.x] = hu[b];
  }
}

__global__ void __launch_bounds__(256)
k_part2(const int* __restrict__ esrc, const int* __restrict__ edst,
        const int* __restrict__ hbase, uint2* __restrict__ rec_m,
        uint2* __restrict__ rec_u, int E) {
  __shared__ int cm[NBKT], cu[NBKT];
  int t = threadIdx.x;
  for (int b = t; b < NBKT; b += 256) {
    cm[b] = hbase[b * NBLK + blockIdx.x];
    cu[b] = hbase[NH + b * NBLK + blockIdx.x] - E;  // user half offset by E
  }
  __syncthreads();
  int chunk = (E + NBLK - 1) / NBLK;
  int beg = blockIdx.x * chunk;
  int end = min(beg + chunk, E);
  for (int e = beg + t; e < end; e += 256) {
    int d = edst[e], s = esrc[e];
    int pm = atomicAdd(&cm[d >> 8], 1);
    rec_m[pm] = make_uint2((unsigned)d, (unsigned)s);
    int pu = atomicAdd(&cu[s >> 9], 1);
    rec_u[pu] = make_uint2((unsigned)s, (unsigned)d);
  }
}

// grid = 2*NBKT; blocks < NBKT handle movie-dest, rest user-dest.
__global__ void __launch_bounds__(256)
k_bcount2(const uint2* __restrict__ rec_m, const uint2* __restrict__ rec_u,
          const int* __restrict__ hbase, int* __restrict__ cnt, int E) {
  __shared__ int lcnt[1024];
  int b = blockIdx.x, t = threadIdx.x;
  bool mv = b < NBKT;
  int bb = mv ? b : b - NBKT;
  const uint2* rec = mv ? rec_m : rec_u;
  int R = mv ? RM : RU, SH = mv ? 8 : 9, N = mv ? NM : NU;
  int* cntb = cnt + (mv ? 0 : NKM);
  int rs = mv ? hbase[bb * NBLK] : hbase[NH + bb * NBLK] - E;
  int re = mv ? hbase[(bb + 1) * NBLK] : hbase[NH + (bb + 1) * NBLK] - E;
  int node_lo = bb << SH;
  int wlen = (min(N - node_lo, 1 << SH)) * R;
  for (int i = t; i < wlen; i += 256) lcnt[i] = 0;
  __syncthreads();
  for (int r = rs + t; r < re; r += 256) {
    uint2 q = rec[r];
    atomicAdd(&lcnt[((int)q.x - node_lo) * R + (int)(q.y / 25000u)], 1);
  }
  __syncthreads();
  for (int i = t; i < wlen; i += 256) cntb[node_lo * R + i] = lcnt[i];
}

__global__ void __launch_bounds__(256)
k_bscatter2(const uint2* __restrict__ rec_m, const uint2* __restrict__ rec_u,
            const int* __restrict__ hbase, const int* __restrict__ off,
            int* __restrict__ nbr, int E) {
  __shared__ int lcur[1024];
  int b = blockIdx.x, t = threadIdx.x;
  bool mv = b < NBKT;
  int bb = mv ? b : b - NBKT;
  const uint2* rec = mv ? rec_m : rec_u;
  int R = mv ? RM : RU, SH = mv ? 8 : 9, N = mv ? NM : NU;
  const int* offb = off + (mv ? 0 : NKM);
  int rs = mv ? hbase[bb * NBLK] : hbase[NH + bb * NBLK] - E;
  int re = mv ? hbase[(bb + 1) * NBLK] : hbase[NH + (bb + 1) * NBLK] - E;
  int node_lo = bb << SH;
  int wlen = (min(N - node_lo, 1 << SH)) * R;
  for (int i = t; i < wlen; i += 256) lcur[i] = offb[node_lo * R + i];
  __syncthreads();
  for (int r = rs + t; r < re; r += 256) {
    uint2 q = rec[r];
    int key = ((int)q.x - node_lo) * R + (int)(q.y / 25000u);
    int p = atomicAdd(&lcur[key], 1);
    nbr[p] = (int)q.y;   // absolute position in nbr[2E]
  }
}

// ---------- feature prep ----------
__global__ void k_tobf4(const float4* __restrict__ in, unsigned short* __restrict__ out, int n4) {
  int i = blockIdx.x * blockDim.x + threadIdx.x;
  if (i < n4) {
    float4 v = in[i];
    ushort4 o;
    o.x = f2bf(v.x); o.y = f2bf(v.y); o.z = f2bf(v.z); o.w = f2bf(v.w);
    *(ushort4*)(out + (size_t)i * 4) = o;
  }
}

__global__ void k_movie_init(const float* __restrict__ movie_x,
                             const float* __restrict__ lin_W,
                             const float* __restrict__ lin_b,
                             const float* __restrict__ movie_emb,
                             unsigned short* __restrict__ x_movie) {
  __shared__ float lwT[20 * 65];
  for (int gidx = threadIdx.x; gidx < 64 * 20; gidx += 256) {
    int h = gidx / 20;
    int f = gidx - h * 20;
    lwT[f * 65 + h] = lin_W[gidx];
  }
  __syncthreads();
  int w = (blockIdx.x * blockDim.x + threadIdx.x) >> 6;
  int h = threadIdx.x & 63;
  if (w >= NM) return;
  float acc = lin_b[h] + movie_emb[(size_t)w * 64 + h];
  const float* mx = movie_x + (size_t)w * 20;
  #pragma unroll
  for (int f = 0; f < 20; f++) acc += mx[f] * lwT[f * 65 + h];
  x_movie[(size_t)w * 64 + h] = f2bf(acc);
}

// pack all four [Wl|Wr] pairs into bf16 Wcat[64][128]; grid 128 blocks
__global__ void k_wcat_all(const float* __restrict__ Wl0, const float* __restrict__ Wr0,
                           const float* __restrict__ Wl1, const float* __restrict__ Wr1,
                           const float* __restrict__ Wl2, const float* __restrict__ Wr2,
                           const float* __restrict__ Wl3, const float* __restrict__ Wr3,
                           unsigned short* __restrict__ Wc /* 4 x 8192 */) {
  int which = blockIdx.x >> 5;
  const float* Wl = which == 0 ? Wl0 : which == 1 ? Wl1 : which == 2 ? Wl2 : Wl3;
  const float* Wr = which == 0 ? Wr0 : which == 1 ? Wr1 : which == 2 ? Wr2 : Wr3;
  int i = (blockIdx.x & 31) * 256 + threadIdx.x;
  if (i >= 8192) return;
  int h = i >> 7, k = i & 127;
  float v = (k < 64) ? Wl[h * 64 + k] : Wr[h * 64 + (k - 64)];
  Wc[which * 8192 + i] = f2bf(v);
}

// ---------- mean-gather: one wave per destination node ----------
// Segment-ordered CSR (R source sub-ranges, each ~3.2MB = L2-resident phase).
// 32-row windows with <=16-row guards: the avg (node,segment) run is ~12.5
// edges, so the old 64-row window paid ~200 VALU-instrs for ~12 rows; the
// 32-window with hi-guard pays ~60 for the same work, identical memory
// behavior. Packed gather: lane = (row-slot g=lane>>3, 16B-chunk i=lane&7).
template <int R>
__global__ void __launch_bounds__(256)
k_gmean(const unsigned short* __restrict__ xsrc, const int* __restrict__ nbr,
        const int* __restrict__ off, unsigned short* __restrict__ meanT, int ndst) {
  int w = (blockIdx.x * blockDim.x + threadIdx.x) >> 6;
  int lane = threadIdx.x & 63;
  if (w >= ndst) return;  // wave-uniform
  int g = lane >> 3;
  int i = lane & 7;
  float aa[8];
  #pragma unroll
  for (int k = 0; k < 8; k++) aa[k] = 0.f;

  int s0 = off[w * R];
  int eN = off[(w + 1) * R];
  for (int r = 0; r < R; ++r) {
    int sseg = off[w * R + r], eseg = off[w * R + r + 1];
    for (int base = sseg; base < eseg; base += 32) {
      int cnw = eseg - base;
      if (cnw > 32) cnw = 32;
      int lim = cnw - 1;
      int my = nbr[base + (lane < cnw ? lane : 0)];
      uint4 d0, d1, d2, d3;
      int j0 = __shfl(my, min(0 * 8 + g, lim));
      int j1 = __shfl(my, min(1 * 8 + g, lim));
      d0 = *(const uint4*)(xsrc + (size_t)j0 * 64 + i * 8);
      d1 = *(const uint4*)(xsrc + (size_t)j1 * 64 + i * 8);
      bool hi = cnw > 16;
      if (hi) {
        int j2 = __shfl(my, min(2 * 8 + g, lim));
        int j3 = __shfl(my, min(3 * 8 + g, lim));
        d2 = *(const uint4*)(xsrc + (size_t)j2 * 64 + i * 8);
        d3 = *(const uint4*)(xsrc + (size_t)j3 * 64 + i * 8);
      }
      #define CONSUME(dd, c)                                              \
        {                                                                 \
          float mc = ((c) * 8 + g < cnw) ? 1.f : 0.f;                     \
          aa[0] = fmaf(__uint_as_float(dd.x << 16), mc, aa[0]);           \
          aa[1] = fmaf(__uint_as_float(dd.x & 0xFFFF0000u), mc, aa[1]);   \
          aa[2] = fmaf(__uint_as_float(dd.y << 16), mc, aa[2]);           \
          aa[3] = fmaf(__uint_as_float(dd.y & 0xFFFF0000u), mc, aa[3]);   \
          aa[4] = fmaf(__uint_as_float(dd.z << 16), mc, aa[4]);           \
          aa[5] = fmaf(__uint_as_float(dd.z & 0xFFFF0000u), mc, aa[5]);   \
          aa[6] = fmaf(__uint_as_float(dd.w << 16), mc, aa[6]);           \
          aa[7] = fmaf(__uint_as_float(dd.w & 0xFFFF0000u), mc, aa[7]);   \
        }
      CONSUME(d0, 0)
      CONSUME(d1, 1)
      if (hi) {
        CONSUME(d2, 2)
        CONSUME(d3, 3)
      }
      #undef CONSUME
    }
  }
  #pragma unroll
  for (int m = 8; m <= 32; m <<= 1) {
    #pragma unroll
    for (int k = 0; k < 8; k++) aa[k] += __shfl_xor(aa[k], m);
  }
  float inv = 1.0f / fmaxf((float)(eN - s0), 1.0f);
  if (g == 0) {
    uint4 o;
    o.x = pk2(aa[0] * inv, aa[1] * inv);
    o.y = pk2(aa[2] * inv, aa[3] * inv);
    o.z = pk2(aa[4] * inv, aa[5] * inv);
    o.w = pk2(aa[6] * inv, aa[7] * inv);
    *(uint4*)(meanT + ((size_t)w << 6) + i * 8) = o;
  }
}

// ---------- SAGE transform as MFMA GEMM, both relations in one dispatch ----------
// out[n][h] = (ReLU?) bias[h] + sum_k [mean|dv][n][k] * Wcat[h][k], K=128.
// 16 nodes/wave, 16x mfma_f32_16x16x32_bf16; D layout col=lane&15,
// row=(lane>>4)*4+reg (verified); LDS transpose epilogue -> 128B row stores.
template <int RELU>
__global__ void __launch_bounds__(256)
k_sage_gemm2(const unsigned short* __restrict__ meanM, const unsigned short* __restrict__ dvM,
             const unsigned short* __restrict__ WcM, const float* __restrict__ biasM,
             unsigned short* __restrict__ outM,
             const unsigned short* __restrict__ meanU, const unsigned short* __restrict__ dvU,
             const unsigned short* __restrict__ WcU, const float* __restrict__ biasU,
             unsigned short* __restrict__ outU) {
  __shared__ float ot[4][16][68];
  const int tM = NM / 16, tU = NU / 16;
  int wv4 = threadIdx.x >> 6;
  int wvg = (blockIdx.x * blockDim.x + threadIdx.x) >> 6;
  int lane = threadIdx.x & 63;
  bool active = wvg < tM + tU;
  bool mv = wvg < tM;
  const unsigned short* meanT = mv ? meanM : meanU;
  const unsigned short* dvT = mv ? dvM : dvU;
  const unsigned short* Wc = mv ? WcM : WcU;
  const float* bias = mv ? biasM : biasU;
  unsigned short* outT = mv ? outM : outU;
  int n0 = (mv ? wvg : wvg - tM) * 16;
  int rr = lane & 15;
  int ks = lane >> 4;

  if (active) {
    bf16x8 bf[4][4];
    #pragma unroll
    for (int t = 0; t < 4; t++)
      #pragma unroll
      for (int kk = 0; kk < 4; kk++)
        bf[t][kk] = *(const bf16x8*)(Wc + ((t * 16 + rr) << 7) + kk * 32 + ks * 8);
    f32x4 acc[4];
    #pragma unroll
    for (int t = 0; t < 4; t++) {
      float b = bias[t * 16 + rr];
      acc[t] = (f32x4){b, b, b, b};
    }
    const unsigned short* am = meanT + ((size_t)(n0 + rr) << 6);
    const unsigned short* ad = dvT + ((size_t)(n0 + rr) << 6);
    bf16x8 af[4];
    af[0] = *(const bf16x8*)(am + ks * 8);
    af[1] = *(const bf16x8*)(am + 32 + ks * 8);
    af[2] = *(const bf16x8*)(ad + ks * 8);
    af[3] = *(const bf16x8*)(ad + 32 + ks * 8);
    #pragma unroll
    for (int kk = 0; kk < 4; kk++)
      #pragma unroll
      for (int t = 0; t < 4; t++)
        acc[t] = __builtin_amdgcn_mfma_f32_16x16x32_bf16(af[kk], bf[t][kk], acc[t], 0, 0, 0);
    #pragma unroll
    for (int t = 0; t < 4; t++)
      #pragma unroll
      for (int r = 0; r < 4; r++) {
        float v = acc[t][r];
        if (RELU) v = fmaxf(v, 0.f);
        ot[wv4][(lane >> 4) * 4 + r][t * 16 + rr] = v;
      }
  }
  __syncthreads();
  if (active) {
    int nn = lane >> 2, c4 = lane & 3;
    const float* src = &ot[wv4][nn][c4 * 16];
    uint4 o0, o1;
    o0.x = pk2(src[0], src[1]);  o0.y = pk2(src[2], src[3]);
    o0.z = pk2(src[4], src[5]);  o0.w = pk2(src[6], src[7]);
    o1.x = pk2(src[8], src[9]);  o1.y = pk2(src[10], src[11]);
    o1.z = pk2(src[12], src[13]); o1.w = pk2(src[14], src[15]);
    unsigned short* dst = outT + ((size_t)(n0 + nn) << 6) + c4 * 16;
    *(uint4*)dst = o0;
    *(uint4*)(dst + 8) = o1;
  }
}

// 16 lanes per edge on bf16 rows; shfl_xor reduce within 16-lane group.
__global__ void __launch_bounds__(256)
k_dot(const unsigned short* __restrict__ u2, const unsigned short* __restrict__ m2,
      const int* __restrict__ eu, const int* __restrict__ em,
      float* __restrict__ out, int L) {
  int wave = (blockIdx.x * blockDim.x + threadIdx.x) >> 6;
  int lane = threadIdx.x & 63;
  int sub = lane & 15;
  int l = wave * 4 + (lane >> 4);
  int lc = l < L ? l : (L - 1);
  int iu = eu[lc], im = em[lc];
  uint2 a = *(const uint2*)(u2 + (size_t)iu * 64 + sub * 4);
  uint2 b = *(const uint2*)(m2 + (size_t)im * 64 + sub * 4);
  float s = __uint_as_float(a.x << 16) * __uint_as_float(b.x << 16)
          + __uint_as_float(a.x & 0xFFFF0000u) * __uint_as_float(b.x & 0xFFFF0000u)
          + __uint_as_float(a.y << 16) * __uint_as_float(b.y << 16)
          + __uint_as_float(a.y & 0xFFFF0000u) * __uint_as_float(b.y & 0xFFFF0000u);
  s += __shfl_xor(s, 1);
  s += __shfl_xor(s, 2);
  s += __shfl_xor(s, 4);
  s += __shfl_xor(s, 8);
  if (sub == 0 && l < L) out[l] = s;
}

extern "C" void kernel_launch(void* const* d_in, const int* in_sizes, int n_in,
                              void* d_out, int out_size, void* d_ws, size_t ws_size,
                              hipStream_t stream) {
  const float* movie_x   = (const float*)d_in[2];
  const int*   esrc      = (const int*)d_in[3];
  const int*   edst      = (const int*)d_in[4];
  const int*   eli_u     = (const int*)d_in[5];
  const int*   eli_m     = (const int*)d_in[6];
  const float* user_emb  = (const float*)d_in[7];
  const float* movie_emb = (const float*)d_in[8];
  const float* lin_W     = (const float*)d_in[9];
  const float* lin_b     = (const float*)d_in[10];
  const float* W1um_l = (const float*)d_in[11];
  const float* W1um_r = (const float*)d_in[12];
  const float* W1mu_l = (const float*)d_in[13];
  const float* W1mu_r = (const float*)d_in[14];
  const float* W2um_l = (const float*)d_in[15];
  const float* W2um_r = (const float*)d_in[16];
  const float* W2mu_l = (const float*)d_in[17];
  const float* W2mu_r = (const float*)d_in[18];
  const float* b1um = (const float*)d_in[19];
  const float* b1mu = (const float*)d_in[20];
  const float* b2um = (const float*)d_in[21];
  const float* b2mu = (const float*)d_in[22];
  const int E = in_sizes[3];
  const int L = in_sizes[5];

  char* ws = (char*)d_ws;
  size_t o = 0;
  auto alloc = [&](size_t bytes) -> void* {
    void* p = ws + o;
    o = (o + bytes + 255) & ~(size_t)255;
    return p;
  };
  unsigned short* uemb_bf   = (unsigned short*)alloc((size_t)NU * 64 * 2);
  unsigned short* xmovie_bf = (unsigned short*)alloc((size_t)NM * 64 * 2);
  unsigned short* m1_bf     = (unsigned short*)alloc((size_t)NM * 64 * 2);
  unsigned short* u1_bf     = (unsigned short*)alloc((size_t)NU * 64 * 2);
  unsigned short* m2_bf     = (unsigned short*)alloc((size_t)NM * 64 * 2);
  unsigned short* u2_bf     = (unsigned short*)alloc((size_t)NU * 64 * 2);
  unsigned short* mean_m    = (unsigned short*)alloc((size_t)NM * 64 * 2);
  unsigned short* mean_u    = (unsigned short*)alloc((size_t)NU * 64 * 2);
  unsigned short* wcat      = (unsigned short*)alloc(4 * 8192 * 2);
  int* cnt   = (int*)alloc((size_t)(NKM + NKU) * 4);
  int* off   = (int*)alloc((size_t)(NKM + NKU + 1) * 4);
  int* cur   = (int*)alloc((size_t)(NKM + NKU) * 4);   // scan_add dummy
  int* bs    = (int*)alloc(4096);
  int* nbr   = (int*)alloc((size_t)2 * E * 4);
  int* hmat  = (int*)alloc((size_t)(2 * NH + 1) * 4);
  int* hbase = (int*)alloc((size_t)(2 * NH + 1) * 4);
  // rec buffers (E x 8B = 20MB each) overlay dead table regions during build:
  // rec_m over uemb+xmovie+m1 (25.6MB), rec_u over u1+m2+u2 (32MB).
  uint2* rec_m = (uint2*)uemb_bf;
  uint2* rec_u = (uint2*)u1_bf;

  // ===== merged CSR build =====
  k_hist2<<<NBLK, 256, 0, stream>>>(esrc, edst, hmat, E);
  {
    int n = 2 * NH, nb = (n + 1023) / 1024;
    k_scan_part<<<nb, 256, 0, stream>>>(hmat, hbase, bs, n);
    k_scan_top<<<1, 64, 0, stream>>>(bs, nb);
    k_scan_add<<<(n + 1 + 255) / 256, 256, 0, stream>>>(hbase, cur, bs, n, 2 * E);
  }
  k_part2<<<NBLK, 256, 0, stream>>>(esrc, edst, hbase, rec_m, rec_u, E);
  k_bcount2<<<2 * NBKT, 256, 0, stream>>>(rec_m, rec_u, hbase, cnt, E);
  {
    int n = NKM + NKU, nb = (n + 1023) / 1024;
    k_scan_part<<<nb, 256, 0, stream>>>(cnt, off, bs, n);
    k_scan_top<<<1, 64, 0, stream>>>(bs, nb);
    k_scan_add<<<(n + 1 + 255) / 256, 256, 0, stream>>>(off, cur, bs, n, 2 * E);
  }
  k_bscatter2<<<2 * NBKT, 256, 0, stream>>>(rec_m, rec_u, hbase, off, nbr, E);

  // ===== feature prep (rec overlays now dead) =====
  int n4u = NU * 16;
  k_tobf4<<<(n4u + 255) / 256, 256, 0, stream>>>((const float4*)user_emb, uemb_bf, n4u);
  k_movie_init<<<(NM + 3) / 4, 256, 0, stream>>>(movie_x, lin_W, lin_b, movie_emb, xmovie_bf);
  k_wcat_all<<<128, 256, 0, stream>>>(W1um_l, W1um_r, W1mu_l, W1mu_r,
                                      W2um_l, W2um_r, W2mu_l, W2mu_r, wcat);
  unsigned short* wc1um = wcat;
  unsigned short* wc1mu = wcat + 8192;
  unsigned short* wc2um = wcat + 16384;
  unsigned short* wc2mu = wcat + 24576;

  int gM = (NM + 3) / 4, gU = (NU + 3) / 4;
  int gG = ((NM / 16 + NU / 16) + 3) / 4;
  // layer 1
  k_gmean<RM><<<gM, 256, 0, stream>>>(uemb_bf, nbr, off, mean_m, NM);
  k_gmean<RU><<<gU, 256, 0, stream>>>(xmovie_bf, nbr, off + NKM, mean_u, NU);
  k_sage_gemm2<1><<<gG, 256, 0, stream>>>(mean_m, xmovie_bf, wc1um, b1um, m1_bf,
                                          mean_u, uemb_bf, wc1mu, b1mu, u1_bf);
  // layer 2
  k_gmean<RM><<<gM, 256, 0, stream>>>(u1_bf, nbr, off, mean_m, NM);
  k_gmean<RU><<<gU, 256, 0, stream>>>(m1_bf, nbr, off + NKM, mean_u, NU);
  k_sage_gemm2<0><<<gG, 256, 0, stream>>>(mean_m, m1_bf, wc2um, b2um, m2_bf,
                                          mean_u, u1_bf, wc2mu, b2mu, u2_bf);

  // 16 edges per 256-thread block
  k_dot<<<(L + 15) / 16, 256, 0, stream>>>(u2_bf, m2_bf, eli_u, eli_m, (float*)d_out, L);
}

// Round 12
// 393.821 us; speedup vs baseline: 5.5872x; 1.1239x over previous
//
#include <hip/hip_runtime.h>

#define NU 100000
#define NM 50000
#define RM 4      // user-table sub-ranges (movie-dest gather source)
#define RU 2      // movie-table sub-ranges (user-dest gather source)
#define NBLK 256  // partition blocks
#define NBKT 196  // coarse buckets (50000>>8 -> 196, 100000>>9 -> 196)
#define NH (NBKT * NBLK)
#define NKM (NM * RM)
#define NKU (NU * RU)

typedef __attribute__((ext_vector_type(8))) short bf16x8;
typedef __attribute__((ext_vector_type(4))) float f32x4;

__device__ __forceinline__ unsigned short f2bf(float f) {
  unsigned u = __float_as_uint(f);
  u = u + 0x7FFF + ((u >> 16) & 1);
  return (unsigned short)(u >> 16);
}
__device__ __forceinline__ float bf2f(unsigned short b) {
  return __uint_as_float(((unsigned)b) << 16);
}
__device__ __forceinline__ unsigned pk2(float a, float b) {
  return (unsigned)f2bf(a) | ((unsigned)f2bf(b) << 16);
}

// ---------- scan machinery ----------
__global__ void k_scan_part(const int* __restrict__ cnt, int* __restrict__ off,
                            int* __restrict__ bsum, int n) {
  __shared__ int wsum[4];
  int t = threadIdx.x;
  int base = blockIdx.x * 1024 + t * 4;
  int v0 = (base + 0 < n) ? cnt[base + 0] : 0;
  int v1 = (base + 1 < n) ? cnt[base + 1] : 0;
  int v2 = (base + 2 < n) ? cnt[base + 2] : 0;
  int v3 = (base + 3 < n) ? cnt[base + 3] : 0;
  int s = v0 + v1 + v2 + v3;
  int lane = t & 63;
  int inc = s;
  #pragma unroll
  for (int d = 1; d < 64; d <<= 1) {
    int x = __shfl_up(inc, d);
    if (lane >= d) inc += x;
  }
  int wid = t >> 6;
  if (lane == 63) wsum[wid] = inc;
  __syncthreads();
  int woff = 0;
  for (int i = 0; i < wid; i++) woff += wsum[i];
  int excl = woff + inc - s;
  if (base + 0 < n) off[base + 0] = excl;
  if (base + 1 < n) off[base + 1] = excl + v0;
  if (base + 2 < n) off[base + 2] = excl + v0 + v1;
  if (base + 3 < n) off[base + 3] = excl + v0 + v1 + v2;
  if (t == 255) bsum[blockIdx.x] = woff + inc;
}

__global__ void k_scan_top(int* bsum, int nb) {
  int lane = threadIdx.x;
  int carry = 0;
  for (int base = 0; base < nb; base += 64) {
    int i = base + lane;
    int v = (i < nb) ? bsum[i] : 0;
    int inc = v;
    #pragma unroll
    for (int d = 1; d < 64; d <<= 1) {
      int x = __shfl_up(inc, d);
      if (lane >= d) inc += x;
    }
    if (i < nb) bsum[i] = carry + inc - v;
    carry += __shfl(inc, 63);
  }
}

__global__ void k_scan_add(int* __restrict__ off, const int* __restrict__ bsum,
                           int n, int total) {
  int i = blockIdx.x * blockDim.x + threadIdx.x;
  if (i < n) {
    off[i] = off[i] + bsum[i >> 10];
  } else if (i == n) {
    off[n] = total;
  }
}

// ---------- merged radix-partition build (both CSRs per pass) ----------
__global__ void __launch_bounds__(256)
k_hist2(const int* __restrict__ esrc, const int* __restrict__ edst,
        int* __restrict__ hmat, int E) {
  __shared__ int hm[NBKT], hu[NBKT];
  int t = threadIdx.x;
  for (int b = t; b < NBKT; b += 256) { hm[b] = 0; hu[b] = 0; }
  __syncthreads();
  int chunk = (E + NBLK - 1) / NBLK;
  int beg = blockIdx.x * chunk;
  int end = min(beg + chunk, E);
  for (int e = beg + t; e < end; e += 256) {
    atomicAdd(&hm[edst[e] >> 8], 1);
    atomicAdd(&hu[esrc[e] >> 9], 1);
  }
  __syncthreads();
  for (int b = t; b < NBKT; b += 256) {
    hmat[b * NBLK + blockIdx.x] = hm[b];
    hmat[NH + b * NBLK + blockIdx.x] = hu[b];
  }
}

// 4B packed records: (lkey << 17) | payload; lkey = in-bucket-node * R + range
// (<=10 bits), payload <= 17 bits. Halves rec traffic vs uint2.
__global__ void __launch_bounds__(256)
k_part2(const int* __restrict__ esrc, const int* __restrict__ edst,
        const int* __restrict__ hbase, unsigned* __restrict__ rec_m,
        unsigned* __restrict__ rec_u, int E) {
  __shared__ int cm[NBKT], cu[NBKT];
  int t = threadIdx.x;
  for (int b = t; b < NBKT; b += 256) {
    cm[b] = hbase[b * NBLK + blockIdx.x];
    cu[b] = hbase[NH + b * NBLK + blockIdx.x] - E;  // user half offset by E
  }
  __syncthreads();
  int chunk = (E + NBLK - 1) / NBLK;
  int beg = blockIdx.x * chunk;
  int end = min(beg + chunk, E);
  for (int e = beg + t; e < end; e += 256) {
    int d = edst[e], s = esrc[e];
    unsigned lm = (unsigned)(d & 255) * RM + (unsigned)s / 25000u;
    int pm = atomicAdd(&cm[d >> 8], 1);
    rec_m[pm] = (lm << 17) | (unsigned)s;
    unsigned lu = (unsigned)(s & 511) * RU + (unsigned)d / 25000u;
    int pu = atomicAdd(&cu[s >> 9], 1);
    rec_u[pu] = (lu << 17) | (unsigned)d;
  }
}

// grid = 2*NBKT; blocks < NBKT handle movie-dest, rest user-dest.
__global__ void __launch_bounds__(256)
k_bcount2(const unsigned* __restrict__ rec_m, const unsigned* __restrict__ rec_u,
          const int* __restrict__ hbase, int* __restrict__ cnt, int E) {
  __shared__ int lcnt[1024];
  int b = blockIdx.x, t = threadIdx.x;
  bool mv = b < NBKT;
  int bb = mv ? b : b - NBKT;
  const unsigned* rec = mv ? rec_m : rec_u;
  int R = mv ? RM : RU, SH = mv ? 8 : 9, N = mv ? NM : NU;
  int* cntb = cnt + (mv ? 0 : NKM);
  int rs = mv ? hbase[bb * NBLK] : hbase[NH + bb * NBLK] - E;
  int re = mv ? hbase[(bb + 1) * NBLK] : hbase[NH + (bb + 1) * NBLK] - E;
  int node_lo = bb << SH;
  int wlen = (min(N - node_lo, 1 << SH)) * R;
  for (int i = t; i < wlen; i += 256) lcnt[i] = 0;
  __syncthreads();
  for (int r = rs + t; r < re; r += 256)
    atomicAdd(&lcnt[rec[r] >> 17], 1);
  __syncthreads();
  for (int i = t; i < wlen; i += 256) cntb[node_lo * R + i] = lcnt[i];
}

__global__ void __launch_bounds__(256)
k_bscatter2(const unsigned* __restrict__ rec_m, const unsigned* __restrict__ rec_u,
            const int* __restrict__ hbase, const int* __restrict__ off,
            int* __restrict__ nbr, int E) {
  __shared__ int lcur[1024];
  int b = blockIdx.x, t = threadIdx.x;
  bool mv = b < NBKT;
  int bb = mv ? b : b - NBKT;
  const unsigned* rec = mv ? rec_m : rec_u;
  int R = mv ? RM : RU, SH = mv ? 8 : 9, N = mv ? NM : NU;
  const int* offb = off + (mv ? 0 : NKM);
  int rs = mv ? hbase[bb * NBLK] : hbase[NH + bb * NBLK] - E;
  int re = mv ? hbase[(bb + 1) * NBLK] : hbase[NH + (bb + 1) * NBLK] - E;
  int node_lo = bb << SH;
  int wlen = (min(N - node_lo, 1 << SH)) * R;
  for (int i = t; i < wlen; i += 256) lcur[i] = offb[node_lo * R + i];
  __syncthreads();
  for (int r = rs + t; r < re; r += 256) {
    unsigned q = rec[r];
    int p = atomicAdd(&lcur[q >> 17], 1);
    nbr[p] = (int)(q & 0x1FFFFu);
  }
}

// ---------- feature prep ----------
__global__ void k_tobf4(const float4* __restrict__ in, unsigned short* __restrict__ out, int n4) {
  int i = blockIdx.x * blockDim.x + threadIdx.x;
  if (i < n4) {
    float4 v = in[i];
    ushort4 o;
    o.x = f2bf(v.x); o.y = f2bf(v.y); o.z = f2bf(v.z); o.w = f2bf(v.w);
    *(ushort4*)(out + (size_t)i * 4) = o;
  }
}

__global__ void k_movie_init(const float* __restrict__ movie_x,
                             const float* __restrict__ lin_W,
                             const float* __restrict__ lin_b,
                             const float* __restrict__ movie_emb,
                             unsigned short* __restrict__ x_movie) {
  __shared__ float lwT[20 * 65];
  for (int gidx = threadIdx.x; gidx < 64 * 20; gidx += 256) {
    int h = gidx / 20;
    int f = gidx - h * 20;
    lwT[f * 65 + h] = lin_W[gidx];
  }
  __syncthreads();
  int w = (blockIdx.x * blockDim.x + threadIdx.x) >> 6;
  int h = threadIdx.x & 63;
  if (w >= NM) return;
  float acc = lin_b[h] + movie_emb[(size_t)w * 64 + h];
  const float* mx = movie_x + (size_t)w * 20;
  #pragma unroll
  for (int f = 0; f < 20; f++) acc += mx[f] * lwT[f * 65 + h];
  x_movie[(size_t)w * 64 + h] = f2bf(acc);
}

// pack all four [Wl|Wr] pairs into bf16 Wcat[64][128]; grid 128 blocks
__global__ void k_wcat_all(const float* __restrict__ Wl0, const float* __restrict__ Wr0,
                           const float* __restrict__ Wl1, const float* __restrict__ Wr1,
                           const float* __restrict__ Wl2, const float* __restrict__ Wr2,
                           const float* __restrict__ Wl3, const float* __restrict__ Wr3,
                           unsigned short* __restrict__ Wc /* 4 x 8192 */) {
  int which = blockIdx.x >> 5;
  const float* Wl = which == 0 ? Wl0 : which == 1 ? Wl1 : which == 2 ? Wl2 : Wl3;
  const float* Wr = which == 0 ? Wr0 : which == 1 ? Wr1 : which == 2 ? Wr2 : Wr3;
  int i = (blockIdx.x & 31) * 256 + threadIdx.x;
  if (i >= 8192) return;
  int h = i >> 7, k = i & 127;
  float v = (k < 64) ? Wl[h * 64 + k] : Wr[h * 64 + (k - 64)];
  Wc[which * 8192 + i] = f2bf(v);
}

// ---------- mean-gather, both relations in one dispatch ----------
// One wave per destination node (movie waves then user waves). The CSR is
// segment-SORTED within each node (by the build), so the gather order is
// identical whether or not the window loop restarts at segment boundaries.
// LINEAR 32-row windows across the whole node range: movie 4->2 windows/node,
// user 2->1 -- halves the per-window fixed cost that dominated (VALU 74%).
// Packed gather: lane = (row-slot g=lane>>3, 16B-chunk i=lane&7).
__global__ void __launch_bounds__(256)
k_gmean2(const unsigned short* __restrict__ xsrcM,  // movie-dest gathers (user table)
         const unsigned short* __restrict__ xsrcU,  // user-dest gathers (movie table)
         const int* __restrict__ nbr, const int* __restrict__ off,
         unsigned short* __restrict__ meanM, unsigned short* __restrict__ meanU) {
  int gw = (blockIdx.x * blockDim.x + threadIdx.x) >> 6;
  int lane = threadIdx.x & 63;
  if (gw >= NM + NU) return;  // wave-uniform
  bool mv = gw < NM;
  const unsigned short* xsrc = mv ? xsrcM : xsrcU;
  const int* offb = mv ? off : off + NKM;
  int w = mv ? gw : gw - NM;
  int R = mv ? RM : RU;
  unsigned short* meanT = mv ? meanM : meanU;
  int g = lane >> 3;
  int i = lane & 7;
  float aa[8];
  #pragma unroll
  for (int k = 0; k < 8; k++) aa[k] = 0.f;

  int s0 = offb[w * R];
  int eN = offb[(w + 1) * R];
  for (int base = s0; base < eN; base += 32) {
    int cnw = eN - base;
    if (cnw > 32) cnw = 32;
    int lim = cnw - 1;
    int my = nbr[base + (lane < cnw ? lane : 0)];
    uint4 d0, d1, d2, d3;
    int j0 = __shfl(my, min(0 * 8 + g, lim));
    int j1 = __shfl(my, min(1 * 8 + g, lim));
    d0 = *(const uint4*)(xsrc + (size_t)j0 * 64 + i * 8);
    d1 = *(const uint4*)(xsrc + (size_t)j1 * 64 + i * 8);
    bool hi = cnw > 16;
    if (hi) {
      int j2 = __shfl(my, min(2 * 8 + g, lim));
      int j3 = __shfl(my, min(3 * 8 + g, lim));
      d2 = *(const uint4*)(xsrc + (size_t)j2 * 64 + i * 8);
      d3 = *(const uint4*)(xsrc + (size_t)j3 * 64 + i * 8);
    }
    #define CONSUME(dd, c)                                              \
      {                                                                 \
        float mc = ((c) * 8 + g < cnw) ? 1.f : 0.f;                     \
        aa[0] = fmaf(__uint_as_float(dd.x << 16), mc, aa[0]);           \
        aa[1] = fmaf(__uint_as_float(dd.x & 0xFFFF0000u), mc, aa[1]);   \
        aa[2] = fmaf(__uint_as_float(dd.y << 16), mc, aa[2]);           \
        aa[3] = fmaf(__uint_as_float(dd.y & 0xFFFF0000u), mc, aa[3]);   \
        aa[4] = fmaf(__uint_as_float(dd.z << 16), mc, aa[4]);           \
        aa[5] = fmaf(__uint_as_float(dd.z & 0xFFFF0000u), mc, aa[5]);   \
        aa[6] = fmaf(__uint_as_float(dd.w << 16), mc, aa[6]);           \
        aa[7] = fmaf(__uint_as_float(dd.w & 0xFFFF0000u), mc, aa[7]);   \
      }
    CONSUME(d0, 0)
    CONSUME(d1, 1)
    if (hi) {
      CONSUME(d2, 2)
      CONSUME(d3, 3)
    }
    #undef CONSUME
  }
  #pragma unroll
  for (int m = 8; m <= 32; m <<= 1) {
    #pragma unroll
    for (int k = 0; k < 8; k++) aa[k] += __shfl_xor(aa[k], m);
  }
  float inv = 1.0f / fmaxf((float)(eN - s0), 1.0f);
  if (g == 0) {
    uint4 o;
    o.x = pk2(aa[0] * inv, aa[1] * inv);
    o.y = pk2(aa[2] * inv, aa[3] * inv);
    o.z = pk2(aa[4] * inv, aa[5] * inv);
    o.w = pk2(aa[6] * inv, aa[7] * inv);
    *(uint4*)(meanT + ((size_t)w << 6) + i * 8) = o;
  }
}

// ---------- SAGE transform as MFMA GEMM, both relations in one dispatch ----------
template <int RELU>
__global__ void __launch_bounds__(256)
k_sage_gemm2(const unsigned short* __restrict__ meanM, const unsigned short* __restrict__ dvM,
             const unsigned short* __restrict__ WcM, const float* __restrict__ biasM,
             unsigned short* __restrict__ outM,
             const unsigned short* __restrict__ meanU, const unsigned short* __restrict__ dvU,
             const unsigned short* __restrict__ WcU, const float* __restrict__ biasU,
             unsigned short* __restrict__ outU) {
  __shared__ float ot[4][16][68];
  const int tM = NM / 16, tU = NU / 16;
  int wv4 = threadIdx.x >> 6;
  int wvg = (blockIdx.x * blockDim.x + threadIdx.x) >> 6;
  int lane = threadIdx.x & 63;
  bool active = wvg < tM + tU;
  bool mv = wvg < tM;
  const unsigned short* meanT = mv ? meanM : meanU;
  const unsigned short* dvT = mv ? dvM : dvU;
  const unsigned short* Wc = mv ? WcM : WcU;
  const float* bias = mv ? biasM : biasU;
  unsigned short* outT = mv ? outM : outU;
  int n0 = (mv ? wvg : wvg - tM) * 16;
  int rr = lane & 15;
  int ks = lane >> 4;

  if (active) {
    bf16x8 bf[4][4];
    #pragma unroll
    for (int t = 0; t < 4; t++)
      #pragma unroll
      for (int kk = 0; kk < 4; kk++)
        bf[t][kk] = *(const bf16x8*)(Wc + ((t * 16 + rr) << 7) + kk * 32 + ks * 8);
    f32x4 acc[4];
    #pragma unroll
    for (int t = 0; t < 4; t++) {
      float b = bias[t * 16 + rr];
      acc[t] = (f32x4){b, b, b, b};
    }
    const unsigned short* am = meanT + ((size_t)(n0 + rr) << 6);
    const unsigned short* ad = dvT + ((size_t)(n0 + rr) << 6);
    bf16x8 af[4];
    af[0] = *(const bf16x8*)(am + ks * 8);
    af[1] = *(const bf16x8*)(am + 32 + ks * 8);
    af[2] = *(const bf16x8*)(ad + ks * 8);
    af[3] = *(const bf16x8*)(ad + 32 + ks * 8);
    #pragma unroll
    for (int kk = 0; kk < 4; kk++)
      #pragma unroll
      for (int t = 0; t < 4; t++)
        acc[t] = __builtin_amdgcn_mfma_f32_16x16x32_bf16(af[kk], bf[t][kk], acc[t], 0, 0, 0);
    #pragma unroll
    for (int t = 0; t < 4; t++)
      #pragma unroll
      for (int r = 0; r < 4; r++) {
        float v = acc[t][r];
        if (RELU) v = fmaxf(v, 0.f);
        ot[wv4][(lane >> 4) * 4 + r][t * 16 + rr] = v;
      }
  }
  __syncthreads();
  if (active) {
    int nn = lane >> 2, c4 = lane & 3;
    const float* src = &ot[wv4][nn][c4 * 16];
    uint4 o0, o1;
    o0.x = pk2(src[0], src[1]);  o0.y = pk2(src[2], src[3]);
    o0.z = pk2(src[4], src[5]);  o0.w = pk2(src[6], src[7]);
    o1.x = pk2(src[8], src[9]);  o1.y = pk2(src[10], src[11]);
    o1.z = pk2(src[12], src[13]); o1.w = pk2(src[14], src[15]);
    unsigned short* dst = outT + ((size_t)(n0 + nn) << 6) + c4 * 16;
    *(uint4*)dst = o0;
    *(uint4*)(dst + 8) = o1;
  }
}

// 16 lanes per edge on bf16 rows; shfl_xor reduce within 16-lane group.
__global__ void __launch_bounds__(256)
k_dot(const unsigned short* __restrict__ u2, const unsigned short* __restrict__ m2,
      const int* __restrict__ eu, const int* __restrict__ em,
      float* __restrict__ out, int L) {
  int wave = (blockIdx.x * blockDim.x + threadIdx.x) >> 6;
  int lane = threadIdx.x & 63;
  int sub = lane & 15;
  int l = wave * 4 + (lane >> 4);
  int lc = l < L ? l : (L - 1);
  int iu = eu[lc], im = em[lc];
  uint2 a = *(const uint2*)(u2 + (size_t)iu * 64 + sub * 4);
  uint2 b = *(const uint2*)(m2 + (size_t)im * 64 + sub * 4);
  float s = __uint_as_float(a.x << 16) * __uint_as_float(b.x << 16)
          + __uint_as_float(a.x & 0xFFFF0000u) * __uint_as_float(b.x & 0xFFFF0000u)
          + __uint_as_float(a.y << 16) * __uint_as_float(b.y << 16)
          + __uint_as_float(a.y & 0xFFFF0000u) * __uint_as_float(b.y & 0xFFFF0000u);
  s += __shfl_xor(s, 1);
  s += __shfl_xor(s, 2);
  s += __shfl_xor(s, 4);
  s += __shfl_xor(s, 8);
  if (sub == 0 && l < L) out[l] = s;
}

extern "C" void kernel_launch(void* const* d_in, const int* in_sizes, int n_in,
                              void* d_out, int out_size, void* d_ws, size_t ws_size,
                              hipStream_t stream) {
  const float* movie_x   = (const float*)d_in[2];
  const int*   esrc      = (const int*)d_in[3];
  const int*   edst      = (const int*)d_in[4];
  const int*   eli_u     = (const int*)d_in[5];
  const int*   eli_m     = (const int*)d_in[6];
  const float* user_emb  = (const float*)d_in[7];
  const float* movie_emb = (const float*)d_in[8];
  const float* lin_W     = (const float*)d_in[9];
  const float* lin_b     = (const float*)d_in[10];
  const float* W1um_l = (const float*)d_in[11];
  const float* W1um_r = (const float*)d_in[12];
  const float* W1mu_l = (const float*)d_in[13];
  const float* W1mu_r = (const float*)d_in[14];
  const float* W2um_l = (const float*)d_in[15];
  const float* W2um_r = (const float*)d_in[16];
  const float* W2mu_l = (const float*)d_in[17];
  const float* W2mu_r = (const float*)d_in[18];
  const float* b1um = (const float*)d_in[19];
  const float* b1mu = (const float*)d_in[20];
  const float* b2um = (const float*)d_in[21];
  const float* b2mu = (const float*)d_in[22];
  const int E = in_sizes[3];
  const int L = in_sizes[5];

  char* ws = (char*)d_ws;
  size_t o = 0;
  auto alloc = [&](size_t bytes) -> void* {
    void* p = ws + o;
    o = (o + bytes + 255) & ~(size_t)255;
    return p;
  };
  unsigned short* uemb_bf   = (unsigned short*)alloc((size_t)NU * 64 * 2);
  unsigned short* xmovie_bf = (unsigned short*)alloc((size_t)NM * 64 * 2);
  unsigned short* m1_bf     = (unsigned short*)alloc((size_t)NM * 64 * 2);
  unsigned short* u1_bf     = (unsigned short*)alloc((size_t)NU * 64 * 2);
  unsigned short* m2_bf     = (unsigned short*)alloc((size_t)NM * 64 * 2);
  unsigned short* u2_bf     = (unsigned short*)alloc((size_t)NU * 64 * 2);
  unsigned short* mean_m    = (unsigned short*)alloc((size_t)NM * 64 * 2);
  unsigned short* mean_u    = (unsigned short*)alloc((size_t)NU * 64 * 2);
  unsigned short* wcat      = (unsigned short*)alloc(4 * 8192 * 2);
  int* cnt   = (int*)alloc((size_t)(NKM + NKU) * 4);
  int* off   = (int*)alloc((size_t)(NKM + NKU + 1) * 4);
  int* bs    = (int*)alloc(4096);
  int* nbr   = (int*)alloc((size_t)2 * E * 4);
  int* hmat  = (int*)alloc((size_t)(2 * NH + 1) * 4);
  int* hbase = (int*)alloc((size_t)(2 * NH + 1) * 4);
  // rec buffers (E x 4B = 10MB each) overlay dead table regions during build.
  unsigned* rec_m = (unsigned*)uemb_bf;
  unsigned* rec_u = (unsigned*)u1_bf;

  // ===== merged CSR build =====
  k_hist2<<<NBLK, 256, 0, stream>>>(esrc, edst, hmat, E);
  {
    int n = 2 * NH, nb = (n + 1023) / 1024;
    k_scan_part<<<nb, 256, 0, stream>>>(hmat, hbase, bs, n);
    k_scan_top<<<1, 64, 0, stream>>>(bs, nb);
    k_scan_add<<<(n + 1 + 255) / 256, 256, 0, stream>>>(hbase, bs, n, 2 * E);
  }
  k_part2<<<NBLK, 256, 0, stream>>>(esrc, edst, hbase, rec_m, rec_u, E);
  k_bcount2<<<2 * NBKT, 256, 0, stream>>>(rec_m, rec_u, hbase, cnt, E);
  {
    int n = NKM + NKU, nb = (n + 1023) / 1024;
    k_scan_part<<<nb, 256, 0, stream>>>(cnt, off, bs, n);
    k_scan_top<<<1, 64, 0, stream>>>(bs, nb);
    k_scan_add<<<(n + 1 + 255) / 256, 256, 0, stream>>>(off, bs, n, 2 * E);
  }
  k_bscatter2<<<2 * NBKT, 256, 0, stream>>>(rec_m, rec_u, hbase, off, nbr, E);

  // ===== feature prep (rec overlays now dead) =====
  int n4u = NU * 16;
  k_tobf4<<<(n4u + 255) / 256, 256, 0, stream>>>((const float4*)user_emb, uemb_bf, n4u);
  k_movie_init<<<(NM + 3) / 4, 256, 0, stream>>>(movie_x, lin_W, lin_b, movie_emb, xmovie_bf);
  k_wcat_all<<<128, 256, 0, stream>>>(W1um_l, W1um_r, W1mu_l, W1mu_r,
                                      W2um_l, W2um_r, W2mu_l, W2mu_r, wcat);
  unsigned short* wc1um = wcat;
  unsigned short* wc1mu = wcat + 8192;
  unsigned short* wc2um = wcat + 16384;
  unsigned short* wc2mu = wcat + 24576;

  int gGm = (NM + NU + 3) / 4;
  int gG = ((NM / 16 + NU / 16) + 3) / 4;
  // layer 1
  k_gmean2<<<gGm, 256, 0, stream>>>(uemb_bf, xmovie_bf, nbr, off, mean_m, mean_u);
  k_sage_gemm2<1><<<gG, 256, 0, stream>>>(mean_m, xmovie_bf, wc1um, b1um, m1_bf,
                                          mean_u, uemb_bf, wc1mu, b1mu, u1_bf);
  // layer 2
  k_gmean2<<<gGm, 256, 0, stream>>>(u1_bf, m1_bf, nbr, off, mean_m, mean_u);
  k_sage_gemm2<0><<<gG, 256, 0, stream>>>(mean_m, m1_bf, wc2um, b2um, m2_bf,
                                          mean_u, u1_bf, wc2mu, b2mu, u2_bf);

  // 16 edges per 256-thread block
  k_dot<<<(L + 15) / 16, 256, 0, stream>>>(u2_bf, m2_bf, eli_u, eli_m, (float*)d_out, L);
}

// Round 13
// 385.144 us; speedup vs baseline: 5.7130x; 1.0225x over previous
//
#include <hip/hip_runtime.h>
#include <hip/hip_fp16.h>

#define NU 100000
#define NM 50000
#define RM 4      // user-table sub-ranges (movie-dest gather source)
#define RU 2      // movie-table sub-ranges (user-dest gather source)
#define NBLK 256  // partition blocks
#define NBKT 196  // coarse buckets (50000>>8 -> 196, 100000>>9 -> 196)
#define NH (NBKT * NBLK)
#define NKM (NM * RM)
#define NKU (NU * RU)

typedef __attribute__((ext_vector_type(8))) _Float16 f16x8;
typedef __attribute__((ext_vector_type(4))) float f32x4;

__device__ __forceinline__ unsigned pk2h(float a, float b) {
  return __builtin_bit_cast(unsigned, __floats2half2_rn(a, b));
}

// ---------- scan machinery ----------
__global__ void k_scan_part(const int* __restrict__ cnt, int* __restrict__ off,
                            int* __restrict__ bsum, int n) {
  __shared__ int wsum[4];
  int t = threadIdx.x;
  int base = blockIdx.x * 1024 + t * 4;
  int v0 = (base + 0 < n) ? cnt[base + 0] : 0;
  int v1 = (base + 1 < n) ? cnt[base + 1] : 0;
  int v2 = (base + 2 < n) ? cnt[base + 2] : 0;
  int v3 = (base + 3 < n) ? cnt[base + 3] : 0;
  int s = v0 + v1 + v2 + v3;
  int lane = t & 63;
  int inc = s;
  #pragma unroll
  for (int d = 1; d < 64; d <<= 1) {
    int x = __shfl_up(inc, d);
    if (lane >= d) inc += x;
  }
  int wid = t >> 6;
  if (lane == 63) wsum[wid] = inc;
  __syncthreads();
  int woff = 0;
  for (int i = 0; i < wid; i++) woff += wsum[i];
  int excl = woff + inc - s;
  if (base + 0 < n) off[base + 0] = excl;
  if (base + 1 < n) off[base + 1] = excl + v0;
  if (base + 2 < n) off[base + 2] = excl + v0 + v1;
  if (base + 3 < n) off[base + 3] = excl + v0 + v1 + v2;
  if (t == 255) bsum[blockIdx.x] = woff + inc;
}

__global__ void k_scan_top(int* bsum, int nb) {
  int lane = threadIdx.x;
  int carry = 0;
  for (int base = 0; base < nb; base += 64) {
    int i = base + lane;
    int v = (i < nb) ? bsum[i] : 0;
    int inc = v;
    #pragma unroll
    for (int d = 1; d < 64; d <<= 1) {
      int x = __shfl_up(inc, d);
      if (lane >= d) inc += x;
    }
    if (i < nb) bsum[i] = carry + inc - v;
    carry += __shfl(inc, 63);
  }
}

__global__ void k_scan_add(int* __restrict__ off, const int* __restrict__ bsum,
                           int n, int total) {
  int i = blockIdx.x * blockDim.x + threadIdx.x;
  if (i < n) {
    off[i] = off[i] + bsum[i >> 10];
  } else if (i == n) {
    off[n] = total;
  }
}

// ---------- merged radix-partition build (both CSRs per pass) ----------
__global__ void __launch_bounds__(256)
k_hist2(const int* __restrict__ esrc, const int* __restrict__ edst,
        int* __restrict__ hmat, int E) {
  __shared__ int hm[NBKT], hu[NBKT];
  int t = threadIdx.x;
  for (int b = t; b < NBKT; b += 256) { hm[b] = 0; hu[b] = 0; }
  __syncthreads();
  int chunk = (E + NBLK - 1) / NBLK;
  int beg = blockIdx.x * chunk;
  int end = min(beg + chunk, E);
  for (int e = beg + t; e < end; e += 256) {
    atomicAdd(&hm[edst[e] >> 8], 1);
    atomicAdd(&hu[esrc[e] >> 9], 1);
  }
  __syncthreads();
  for (int b = t; b < NBKT; b += 256) {
    hmat[b * NBLK + blockIdx.x] = hm[b];
    hmat[NH + b * NBLK + blockIdx.x] = hu[b];
  }
}

// 4B packed records: (lkey << 17) | payload
__global__ void __launch_bounds__(256)
k_part2(const int* __restrict__ esrc, const int* __restrict__ edst,
        const int* __restrict__ hbase, unsigned* __restrict__ rec_m,
        unsigned* __restrict__ rec_u, int E) {
  __shared__ int cm[NBKT], cu[NBKT];
  int t = threadIdx.x;
  for (int b = t; b < NBKT; b += 256) {
    cm[b] = hbase[b * NBLK + blockIdx.x];
    cu[b] = hbase[NH + b * NBLK + blockIdx.x] - E;
  }
  __syncthreads();
  int chunk = (E + NBLK - 1) / NBLK;
  int beg = blockIdx.x * chunk;
  int end = min(beg + chunk, E);
  for (int e = beg + t; e < end; e += 256) {
    int d = edst[e], s = esrc[e];
    unsigned lm = (unsigned)(d & 255) * RM + (unsigned)s / 25000u;
    int pm = atomicAdd(&cm[d >> 8], 1);
    rec_m[pm] = (lm << 17) | (unsigned)s;
    unsigned lu = (unsigned)(s & 511) * RU + (unsigned)d / 25000u;
    int pu = atomicAdd(&cu[s >> 9], 1);
    rec_u[pu] = (lu << 17) | (unsigned)d;
  }
}

// grid = 2*NBKT; blocks < NBKT handle movie-dest, rest user-dest.
__global__ void __launch_bounds__(256)
k_bcount2(const unsigned* __restrict__ rec_m, const unsigned* __restrict__ rec_u,
          const int* __restrict__ hbase, int* __restrict__ cnt, int E) {
  __shared__ int lcnt[1024];
  int b = blockIdx.x, t = threadIdx.x;
  bool mv = b < NBKT;
  int bb = mv ? b : b - NBKT;
  const unsigned* rec = mv ? rec_m : rec_u;
  int R = mv ? RM : RU, SH = mv ? 8 : 9, N = mv ? NM : NU;
  int* cntb = cnt + (mv ? 0 : NKM);
  int rs = mv ? hbase[bb * NBLK] : hbase[NH + bb * NBLK] - E;
  int re = mv ? hbase[(bb + 1) * NBLK] : hbase[NH + (bb + 1) * NBLK] - E;
  int node_lo = bb << SH;
  int wlen = (min(N - node_lo, 1 << SH)) * R;
  for (int i = t; i < wlen; i += 256) lcnt[i] = 0;
  __syncthreads();
  for (int r = rs + t; r < re; r += 256)
    atomicAdd(&lcnt[rec[r] >> 17], 1);
  __syncthreads();
  for (int i = t; i < wlen; i += 256) cntb[node_lo * R + i] = lcnt[i];
}

__global__ void __launch_bounds__(256)
k_bscatter2(const unsigned* __restrict__ rec_m, const unsigned* __restrict__ rec_u,
            const int* __restrict__ hbase, const int* __restrict__ off,
            int* __restrict__ nbr, int E) {
  __shared__ int lcur[1024];
  int b = blockIdx.x, t = threadIdx.x;
  bool mv = b < NBKT;
  int bb = mv ? b : b - NBKT;
  const unsigned* rec = mv ? rec_m : rec_u;
  int R = mv ? RM : RU, SH = mv ? 8 : 9, N = mv ? NM : NU;
  const int* offb = off + (mv ? 0 : NKM);
  int rs = mv ? hbase[bb * NBLK] : hbase[NH + bb * NBLK] - E;
  int re = mv ? hbase[(bb + 1) * NBLK] : hbase[NH + (bb + 1) * NBLK] - E;
  int node_lo = bb << SH;
  int wlen = (min(N - node_lo, 1 << SH)) * R;
  for (int i = t; i < wlen; i += 256) lcur[i] = offb[node_lo * R + i];
  __syncthreads();
  for (int r = rs + t; r < re; r += 256) {
    unsigned q = rec[r];
    int p = atomicAdd(&lcur[q >> 17], 1);
    nbr[p] = (int)(q & 0x1FFFFu);
  }
}

// ---------- fused feature prep: user-emb f32->f16 | movie init | weight pack ----------
#define PREP_U 6250    // NU*64/4/256
#define PREP_M 12500   // (NM+3)/4
__global__ void __launch_bounds__(256)
k_prep(const float4* __restrict__ uemb4, unsigned short* __restrict__ uemb_h,
       const float* __restrict__ movie_x, const float* __restrict__ lin_W,
       const float* __restrict__ lin_b, const float* __restrict__ movie_emb,
       unsigned short* __restrict__ x_movie,
       const float* __restrict__ Wl0, const float* __restrict__ Wr0,
       const float* __restrict__ Wl1, const float* __restrict__ Wr1,
       const float* __restrict__ Wl2, const float* __restrict__ Wr2,
       const float* __restrict__ Wl3, const float* __restrict__ Wr3,
       unsigned short* __restrict__ Wc) {
  __shared__ float lwT[20 * 65];
  int b = blockIdx.x;
  if (b < PREP_U) {
    int i = b * 256 + threadIdx.x;  // < NU*16
    float4 v = uemb4[i];
    uint2 o;
    o.x = pk2h(v.x, v.y);
    o.y = pk2h(v.z, v.w);
    *(uint2*)(uemb_h + (size_t)i * 4) = o;
  } else if (b < PREP_U + PREP_M) {
    int bb = b - PREP_U;
    for (int gidx = threadIdx.x; gidx < 64 * 20; gidx += 256) {
      int h = gidx / 20;
      int f = gidx - h * 20;
      lwT[f * 65 + h] = lin_W[gidx];
    }
    __syncthreads();
    int w = (bb * 256 + (int)threadIdx.x) >> 6;
    int h = threadIdx.x & 63;
    if (w >= NM) return;
    float acc = lin_b[h] + movie_emb[(size_t)w * 64 + h];
    const float* mx = movie_x + (size_t)w * 20;
    #pragma unroll
    for (int f = 0; f < 20; f++) acc += mx[f] * lwT[f * 65 + h];
    x_movie[(size_t)w * 64 + h] = __builtin_bit_cast(unsigned short, (__half)__float2half(acc));
  } else {
    int wb = b - PREP_U - PREP_M;  // 0..127
    int which = wb >> 5;
    const float* Wl = which == 0 ? Wl0 : which == 1 ? Wl1 : which == 2 ? Wl2 : Wl3;
    const float* Wr = which == 0 ? Wr0 : which == 1 ? Wr1 : which == 2 ? Wr2 : Wr3;
    int i = (wb & 31) * 256 + threadIdx.x;
    if (i >= 8192) return;
    int h = i >> 7, k = i & 127;
    float v = (k < 64) ? Wl[h * 64 + k] : Wr[h * 64 + (k - 64)];
    Wc[which * 8192 + i] = __builtin_bit_cast(unsigned short, (__half)__float2half(v));
  }
}

// ---------- mean-gather, both relations in one dispatch, f16 tables ----------
// f16 accumulate path: fmaf(__low2float(h2), mc, acc) folds the half-select
// into v_fma_mix_f32 -- deletes the 32 per-window unpack ops the bf16 path
// paid (VALUBusy was 80%). Memory structure identical to round 12.
__global__ void __launch_bounds__(256)
k_gmean2(const unsigned short* __restrict__ xsrcM,
         const unsigned short* __restrict__ xsrcU,
         const int* __restrict__ nbr, const int* __restrict__ off,
         unsigned short* __restrict__ meanM, unsigned short* __restrict__ meanU) {
  int gw = (blockIdx.x * blockDim.x + threadIdx.x) >> 6;
  int lane = threadIdx.x & 63;
  if (gw >= NM + NU) return;  // wave-uniform
  bool mv = gw < NM;
  const unsigned short* xsrc = mv ? xsrcM : xsrcU;
  const int* offb = mv ? off : off + NKM;
  int w = mv ? gw : gw - NM;
  int R = mv ? RM : RU;
  unsigned short* meanT = mv ? meanM : meanU;
  int g = lane >> 3;
  int i = lane & 7;
  float aa[8];
  #pragma unroll
  for (int k = 0; k < 8; k++) aa[k] = 0.f;

  int s0 = offb[w * R];
  int eN = offb[(w + 1) * R];
  for (int base = s0; base < eN; base += 32) {
    int cnw = eN - base;
    if (cnw > 32) cnw = 32;
    int lim = cnw - 1;
    int my = nbr[base + (lane < cnw ? lane : 0)];
    uint4 d0, d1, d2, d3;
    int j0 = __shfl(my, min(0 * 8 + g, lim));
    int j1 = __shfl(my, min(1 * 8 + g, lim));
    d0 = *(const uint4*)(xsrc + (size_t)j0 * 64 + i * 8);
    d1 = *(const uint4*)(xsrc + (size_t)j1 * 64 + i * 8);
    bool hi = cnw > 16;
    if (hi) {
      int j2 = __shfl(my, min(2 * 8 + g, lim));
      int j3 = __shfl(my, min(3 * 8 + g, lim));
      d2 = *(const uint4*)(xsrc + (size_t)j2 * 64 + i * 8);
      d3 = *(const uint4*)(xsrc + (size_t)j3 * 64 + i * 8);
    }
    #define CONSUME(dd, c)                                                  \
      {                                                                     \
        float mc = ((c) * 8 + g < cnw) ? 1.f : 0.f;                         \
        __half2 h0 = __builtin_bit_cast(__half2, dd.x);                     \
        __half2 h1 = __builtin_bit_cast(__half2, dd.y);                     \
        __half2 h2 = __builtin_bit_cast(__half2, dd.z);                     \
        __half2 h3 = __builtin_bit_cast(__half2, dd.w);                     \
        aa[0] = fmaf(__low2float(h0), mc, aa[0]);                           \
        aa[1] = fmaf(__high2float(h0), mc, aa[1]);                          \
        aa[2] = fmaf(__low2float(h1), mc, aa[2]);                           \
        aa[3] = fmaf(__high2float(h1), mc, aa[3]);                          \
        aa[4] = fmaf(__low2float(h2), mc, aa[4]);                           \
        aa[5] = fmaf(__high2float(h2), mc, aa[5]);                          \
        aa[6] = fmaf(__low2float(h3), mc, aa[6]);                           \
        aa[7] = fmaf(__high2float(h3), mc, aa[7]);                          \
      }
    CONSUME(d0, 0)
    CONSUME(d1, 1)
    if (hi) {
      CONSUME(d2, 2)
      CONSUME(d3, 3)
    }
    #undef CONSUME
  }
  #pragma unroll
  for (int m = 8; m <= 32; m <<= 1) {
    #pragma unroll
    for (int k = 0; k < 8; k++) aa[k] += __shfl_xor(aa[k], m);
  }
  float inv = 1.0f / fmaxf((float)(eN - s0), 1.0f);
  if (g == 0) {
    uint4 o;
    o.x = pk2h(aa[0] * inv, aa[1] * inv);
    o.y = pk2h(aa[2] * inv, aa[3] * inv);
    o.z = pk2h(aa[4] * inv, aa[5] * inv);
    o.w = pk2h(aa[6] * inv, aa[7] * inv);
    *(uint4*)(meanT + ((size_t)w << 6) + i * 8) = o;
  }
}

// ---------- SAGE transform as f16 MFMA GEMM, both relations in one dispatch ----------
// out[n][h] = (ReLU?) bias[h] + sum_k [mean|dv][n][k] * Wcat[h][k], K=128.
// mfma_f32_16x16x32_f16; C/D layout dtype-independent (verified m89).
template <int RELU>
__global__ void __launch_bounds__(256)
k_sage_gemm2(const unsigned short* __restrict__ meanM, const unsigned short* __restrict__ dvM,
             const unsigned short* __restrict__ WcM, const float* __restrict__ biasM,
             unsigned short* __restrict__ outM,
             const unsigned short* __restrict__ meanU, const unsigned short* __restrict__ dvU,
             const unsigned short* __restrict__ WcU, const float* __restrict__ biasU,
             unsigned short* __restrict__ outU) {
  __shared__ float ot[4][16][68];
  const int tM = NM / 16, tU = NU / 16;
  int wv4 = threadIdx.x >> 6;
  int wvg = (blockIdx.x * blockDim.x + threadIdx.x) >> 6;
  int lane = threadIdx.x & 63;
  bool active = wvg < tM + tU;
  bool mv = wvg < tM;
  const unsigned short* meanT = mv ? meanM : meanU;
  const unsigned short* dvT = mv ? dvM : dvU;
  const unsigned short* Wc = mv ? WcM : WcU;
  const float* bias = mv ? biasM : biasU;
  unsigned short* outT = mv ? outM : outU;
  int n0 = (mv ? wvg : wvg - tM) * 16;
  int rr = lane & 15;
  int ks = lane >> 4;

  if (active) {
    f16x8 bf[4][4];
    #pragma unroll
    for (int t = 0; t < 4; t++)
      #pragma unroll
      for (int kk = 0; kk < 4; kk++)
        bf[t][kk] = *(const f16x8*)(Wc + ((t * 16 + rr) << 7) + kk * 32 + ks * 8);
    f32x4 acc[4];
    #pragma unroll
    for (int t = 0; t < 4; t++) {
      float b = bias[t * 16 + rr];
      acc[t] = (f32x4){b, b, b, b};
    }
    const unsigned short* am = meanT + ((size_t)(n0 + rr) << 6);
    const unsigned short* ad = dvT + ((size_t)(n0 + rr) << 6);
    f16x8 af[4];
    af[0] = *(const f16x8*)(am + ks * 8);
    af[1] = *(const f16x8*)(am + 32 + ks * 8);
    af[2] = *(const f16x8*)(ad + ks * 8);
    af[3] = *(const f16x8*)(ad + 32 + ks * 8);
    #pragma unroll
    for (int kk = 0; kk < 4; kk++)
      #pragma unroll
      for (int t = 0; t < 4; t++)
        acc[t] = __builtin_amdgcn_mfma_f32_16x16x32_f16(af[kk], bf[t][kk], acc[t], 0, 0, 0);
    #pragma unroll
    for (int t = 0; t < 4; t++)
      #pragma unroll
      for (int r = 0; r < 4; r++) {
        float v = acc[t][r];
        if (RELU) v = fmaxf(v, 0.f);
        ot[wv4][(lane >> 4) * 4 + r][t * 16 + rr] = v;
      }
  }
  __syncthreads();
  if (active) {
    int nn = lane >> 2, c4 = lane & 3;
    const float* src = &ot[wv4][nn][c4 * 16];
    uint4 o0, o1;
    o0.x = pk2h(src[0], src[1]);  o0.y = pk2h(src[2], src[3]);
    o0.z = pk2h(src[4], src[5]);  o0.w = pk2h(src[6], src[7]);
    o1.x = pk2h(src[8], src[9]);  o1.y = pk2h(src[10], src[11]);
    o1.z = pk2h(src[12], src[13]); o1.w = pk2h(src[14], src[15]);
    unsigned short* dst = outT + ((size_t)(n0 + nn) << 6) + c4 * 16;
    *(uint4*)dst = o0;
    *(uint4*)(dst + 8) = o1;
  }
}

// 16 lanes per edge on f16 rows; shfl_xor reduce within 16-lane group.
__global__ void __launch_bounds__(256)
k_dot(const unsigned short* __restrict__ u2, const unsigned short* __restrict__ m2,
      const int* __restrict__ eu, const int* __restrict__ em,
      float* __restrict__ out, int L) {
  int wave = (blockIdx.x * blockDim.x + threadIdx.x) >> 6;
  int lane = threadIdx.x & 63;
  int sub = lane & 15;
  int l = wave * 4 + (lane >> 4);
  int lc = l < L ? l : (L - 1);
  int iu = eu[lc], im = em[lc];
  uint2 a = *(const uint2*)(u2 + (size_t)iu * 64 + sub * 4);
  uint2 b = *(const uint2*)(m2 + (size_t)im * 64 + sub * 4);
  float2 a0 = __half22float2(__builtin_bit_cast(__half2, a.x));
  float2 a1 = __half22float2(__builtin_bit_cast(__half2, a.y));
  float2 b0 = __half22float2(__builtin_bit_cast(__half2, b.x));
  float2 b1 = __half22float2(__builtin_bit_cast(__half2, b.y));
  float s = a0.x * b0.x + a0.y * b0.y + a1.x * b1.x + a1.y * b1.y;
  s += __shfl_xor(s, 1);
  s += __shfl_xor(s, 2);
  s += __shfl_xor(s, 4);
  s += __shfl_xor(s, 8);
  if (sub == 0 && l < L) out[l] = s;
}

extern "C" void kernel_launch(void* const* d_in, const int* in_sizes, int n_in,
                              void* d_out, int out_size, void* d_ws, size_t ws_size,
                              hipStream_t stream) {
  const float* movie_x   = (const float*)d_in[2];
  const int*   esrc      = (const int*)d_in[3];
  const int*   edst      = (const int*)d_in[4];
  const int*   eli_u     = (const int*)d_in[5];
  const int*   eli_m     = (const int*)d_in[6];
  const float* user_emb  = (const float*)d_in[7];
  const float* movie_emb = (const float*)d_in[8];
  const float* lin_W     = (const float*)d_in[9];
  const float* lin_b     = (const float*)d_in[10];
  const float* W1um_l = (const float*)d_in[11];
  const float* W1um_r = (const float*)d_in[12];
  const float* W1mu_l = (const float*)d_in[13];
  const float* W1mu_r = (const float*)d_in[14];
  const float* W2um_l = (const float*)d_in[15];
  const float* W2um_r = (const float*)d_in[16];
  const float* W2mu_l = (const float*)d_in[17];
  const float* W2mu_r = (const float*)d_in[18];
  const float* b1um = (const float*)d_in[19];
  const float* b1mu = (const float*)d_in[20];
  const float* b2um = (const float*)d_in[21];
  const float* b2mu = (const float*)d_in[22];
  const int E = in_sizes[3];
  const int L = in_sizes[5];

  char* ws = (char*)d_ws;
  size_t o = 0;
  auto alloc = [&](size_t bytes) -> void* {
    void* p = ws + o;
    o = (o + bytes + 255) & ~(size_t)255;
    return p;
  };
  unsigned short* uemb_h   = (unsigned short*)alloc((size_t)NU * 64 * 2);
  unsigned short* xmovie_h = (unsigned short*)alloc((size_t)NM * 64 * 2);
  unsigned short* m1_h     = (unsigned short*)alloc((size_t)NM * 64 * 2);
  unsigned short* u1_h     = (unsigned short*)alloc((size_t)NU * 64 * 2);
  unsigned short* m2_h     = (unsigned short*)alloc((size_t)NM * 64 * 2);
  unsigned short* u2_h     = (unsigned short*)alloc((size_t)NU * 64 * 2);
  unsigned short* mean_m   = (unsigned short*)alloc((size_t)NM * 64 * 2);
  unsigned short* mean_u   = (unsigned short*)alloc((size_t)NU * 64 * 2);
  unsigned short* wcat     = (unsigned short*)alloc(4 * 8192 * 2);
  int* cnt   = (int*)alloc((size_t)(NKM + NKU) * 4);
  int* off   = (int*)alloc((size_t)(NKM + NKU + 1) * 4);
  int* bs    = (int*)alloc(4096);
  int* nbr   = (int*)alloc((size_t)2 * E * 4);
  int* hmat  = (int*)alloc((size_t)(2 * NH + 1) * 4);
  int* hbase = (int*)alloc((size_t)(2 * NH + 1) * 4);
  // rec buffers (E x 4B = 10MB each) overlay dead table regions during build.
  unsigned* rec_m = (unsigned*)uemb_h;
  unsigned* rec_u = (unsigned*)u1_h;

  // ===== merged CSR build =====
  k_hist2<<<NBLK, 256, 0, stream>>>(esrc, edst, hmat, E);
  {
    int n = 2 * NH, nb = (n + 1023) / 1024;
    k_scan_part<<<nb, 256, 0, stream>>>(hmat, hbase, bs, n);
    k_scan_top<<<1, 64, 0, stream>>>(bs, nb);
    k_scan_add<<<(n + 1 + 255) / 256, 256, 0, stream>>>(hbase, bs, n, 2 * E);
  }
  k_part2<<<NBLK, 256, 0, stream>>>(esrc, edst, hbase, rec_m, rec_u, E);
  k_bcount2<<<2 * NBKT, 256, 0, stream>>>(rec_m, rec_u, hbase, cnt, E);
  {
    int n = NKM + NKU, nb = (n + 1023) / 1024;
    k_scan_part<<<nb, 256, 0, stream>>>(cnt, off, bs, n);
    k_scan_top<<<1, 64, 0, stream>>>(bs, nb);
    k_scan_add<<<(n + 1 + 255) / 256, 256, 0, stream>>>(off, bs, n, 2 * E);
  }
  k_bscatter2<<<2 * NBKT, 256, 0, stream>>>(rec_m, rec_u, hbase, off, nbr, E);

  // ===== fused feature prep (rec overlays now dead) =====
  k_prep<<<PREP_U + PREP_M + 128, 256, 0, stream>>>(
      (const float4*)user_emb, uemb_h, movie_x, lin_W, lin_b, movie_emb, xmovie_h,
      W1um_l, W1um_r, W1mu_l, W1mu_r, W2um_l, W2um_r, W2mu_l, W2mu_r, wcat);
  unsigned short* wc1um = wcat;
  unsigned short* wc1mu = wcat + 8192;
  unsigned short* wc2um = wcat + 16384;
  unsigned short* wc2mu = wcat + 24576;

  int gGm = (NM + NU + 3) / 4;
  int gG = ((NM / 16 + NU / 16) + 3) / 4;
  // layer 1
  k_gmean2<<<gGm, 256, 0, stream>>>(uemb_h, xmovie_h, nbr, off, mean_m, mean_u);
  k_sage_gemm2<1><<<gG, 256, 0, stream>>>(mean_m, xmovie_h, wc1um, b1um, m1_h,
                                          mean_u, uemb_h, wc1mu, b1mu, u1_h);
  // layer 2
  k_gmean2<<<gGm, 256, 0, stream>>>(u1_h, m1_h, nbr, off, mean_m, mean_u);
  k_sage_gemm2<0><<<gG, 256, 0, stream>>>(mean_m, m1_h, wc2um, b2um, m2_h,
                                          mean_u, u1_h, wc2mu, b2mu, u2_h);

  // 16 edges per 256-thread block
  k_dot<<<(L + 15) / 16, 256, 0, stream>>>(u2_h, m2_h, eli_u, eli_m, (float*)d_out, L);
}

// Round 14
// 375.124 us; speedup vs baseline: 5.8656x; 1.0267x over previous
//
#include <hip/hip_runtime.h>
#include <hip/hip_fp16.h>

#define NU 100000
#define NM 50000
#define RM 4      // user-table sub-ranges (movie-dest gather source)
#define RU 2      // movie-table sub-ranges (user-dest gather source)
#define NBLK 256  // partition blocks
#define NBKT 196  // coarse buckets (50000>>8 -> 196, 100000>>9 -> 196)
#define NH (NBKT * NBLK)
#define NKM (NM * RM)
#define NKU (NU * RU)

typedef __attribute__((ext_vector_type(8))) _Float16 f16x8;
typedef __attribute__((ext_vector_type(4))) float f32x4;

__device__ __forceinline__ unsigned pk2h(float a, float b) {
  return __builtin_bit_cast(unsigned, __floats2half2_rn(a, b));
}
__device__ __forceinline__ __half2 shfl_xor_h2(__half2 v, int m) {
  return __builtin_bit_cast(__half2, __shfl_xor(__builtin_bit_cast(int, v), m));
}

// ---------- scan machinery ----------
__global__ void k_scan_part(const int* __restrict__ cnt, int* __restrict__ off,
                            int* __restrict__ bsum, int n) {
  __shared__ int wsum[4];
  int t = threadIdx.x;
  int base = blockIdx.x * 1024 + t * 4;
  int v0 = (base + 0 < n) ? cnt[base + 0] : 0;
  int v1 = (base + 1 < n) ? cnt[base + 1] : 0;
  int v2 = (base + 2 < n) ? cnt[base + 2] : 0;
  int v3 = (base + 3 < n) ? cnt[base + 3] : 0;
  int s = v0 + v1 + v2 + v3;
  int lane = t & 63;
  int inc = s;
  #pragma unroll
  for (int d = 1; d < 64; d <<= 1) {
    int x = __shfl_up(inc, d);
    if (lane >= d) inc += x;
  }
  int wid = t >> 6;
  if (lane == 63) wsum[wid] = inc;
  __syncthreads();
  int woff = 0;
  for (int i = 0; i < wid; i++) woff += wsum[i];
  int excl = woff + inc - s;
  if (base + 0 < n) off[base + 0] = excl;
  if (base + 1 < n) off[base + 1] = excl + v0;
  if (base + 2 < n) off[base + 2] = excl + v0 + v1;
  if (base + 3 < n) off[base + 3] = excl + v0 + v1 + v2;
  if (t == 255) bsum[blockIdx.x] = woff + inc;
}

__global__ void k_scan_top(int* bsum, int nb) {
  int lane = threadIdx.x;
  int carry = 0;
  for (int base = 0; base < nb; base += 64) {
    int i = base + lane;
    int v = (i < nb) ? bsum[i] : 0;
    int inc = v;
    #pragma unroll
    for (int d = 1; d < 64; d <<= 1) {
      int x = __shfl_up(inc, d);
      if (lane >= d) inc += x;
    }
    if (i < nb) bsum[i] = carry + inc - v;
    carry += __shfl(inc, 63);
  }
}

__global__ void k_scan_add(int* __restrict__ off, const int* __restrict__ bsum,
                           int n, int total) {
  int i = blockIdx.x * blockDim.x + threadIdx.x;
  if (i < n) {
    off[i] = off[i] + bsum[i >> 10];
  } else if (i == n) {
    off[n] = total;
  }
}

// ---------- merged radix-partition build (both CSRs per pass) ----------
__global__ void __launch_bounds__(256)
k_hist2(const int* __restrict__ esrc, const int* __restrict__ edst,
        int* __restrict__ hmat, int E) {
  __shared__ int hm[NBKT], hu[NBKT];
  int t = threadIdx.x;
  for (int b = t; b < NBKT; b += 256) { hm[b] = 0; hu[b] = 0; }
  __syncthreads();
  int chunk = (E + NBLK - 1) / NBLK;
  int beg = blockIdx.x * chunk;
  int end = min(beg + chunk, E);
  for (int e = beg + t; e < end; e += 256) {
    atomicAdd(&hm[edst[e] >> 8], 1);
    atomicAdd(&hu[esrc[e] >> 9], 1);
  }
  __syncthreads();
  for (int b = t; b < NBKT; b += 256) {
    hmat[b * NBLK + blockIdx.x] = hm[b];
    hmat[NH + b * NBLK + blockIdx.x] = hu[b];
  }
}

// 4B packed records: (lkey << 17) | payload
__global__ void __launch_bounds__(256)
k_part2(const int* __restrict__ esrc, const int* __restrict__ edst,
        const int* __restrict__ hbase, unsigned* __restrict__ rec_m,
        unsigned* __restrict__ rec_u, int E) {
  __shared__ int cm[NBKT], cu[NBKT];
  int t = threadIdx.x;
  for (int b = t; b < NBKT; b += 256) {
    cm[b] = hbase[b * NBLK + blockIdx.x];
    cu[b] = hbase[NH + b * NBLK + blockIdx.x] - E;
  }
  __syncthreads();
  int chunk = (E + NBLK - 1) / NBLK;
  int beg = blockIdx.x * chunk;
  int end = min(beg + chunk, E);
  for (int e = beg + t; e < end; e += 256) {
    int d = edst[e], s = esrc[e];
    unsigned lm = (unsigned)(d & 255) * RM + (unsigned)s / 25000u;
    int pm = atomicAdd(&cm[d >> 8], 1);
    rec_m[pm] = (lm << 17) | (unsigned)s;
    unsigned lu = (unsigned)(s & 511) * RU + (unsigned)d / 25000u;
    int pu = atomicAdd(&cu[s >> 9], 1);
    rec_u[pu] = (lu << 17) | (unsigned)d;
  }
}

// grid = 2*NBKT; blocks < NBKT handle movie-dest, rest user-dest.
__global__ void __launch_bounds__(256)
k_bcount2(const unsigned* __restrict__ rec_m, const unsigned* __restrict__ rec_u,
          const int* __restrict__ hbase, int* __restrict__ cnt, int E) {
  __shared__ int lcnt[1024];
  int b = blockIdx.x, t = threadIdx.x;
  bool mv = b < NBKT;
  int bb = mv ? b : b - NBKT;
  const unsigned* rec = mv ? rec_m : rec_u;
  int R = mv ? RM : RU, SH = mv ? 8 : 9, N = mv ? NM : NU;
  int* cntb = cnt + (mv ? 0 : NKM);
  int rs = mv ? hbase[bb * NBLK] : hbase[NH + bb * NBLK] - E;
  int re = mv ? hbase[(bb + 1) * NBLK] : hbase[NH + (bb + 1) * NBLK] - E;
  int node_lo = bb << SH;
  int wlen = (min(N - node_lo, 1 << SH)) * R;
  for (int i = t; i < wlen; i += 256) lcnt[i] = 0;
  __syncthreads();
  for (int r = rs + t; r < re; r += 256)
    atomicAdd(&lcnt[rec[r] >> 17], 1);
  __syncthreads();
  for (int i = t; i < wlen; i += 256) cntb[node_lo * R + i] = lcnt[i];
}

__global__ void __launch_bounds__(256)
k_bscatter2(const unsigned* __restrict__ rec_m, const unsigned* __restrict__ rec_u,
            const int* __restrict__ hbase, const int* __restrict__ off,
            int* __restrict__ nbr, int E) {
  __shared__ int lcur[1024];
  int b = blockIdx.x, t = threadIdx.x;
  bool mv = b < NBKT;
  int bb = mv ? b : b - NBKT;
  const unsigned* rec = mv ? rec_m : rec_u;
  int R = mv ? RM : RU, SH = mv ? 8 : 9, N = mv ? NM : NU;
  const int* offb = off + (mv ? 0 : NKM);
  int rs = mv ? hbase[bb * NBLK] : hbase[NH + bb * NBLK] - E;
  int re = mv ? hbase[(bb + 1) * NBLK] : hbase[NH + (bb + 1) * NBLK] - E;
  int node_lo = bb << SH;
  int wlen = (min(N - node_lo, 1 << SH)) * R;
  for (int i = t; i < wlen; i += 256) lcur[i] = offb[node_lo * R + i];
  __syncthreads();
  for (int r = rs + t; r < re; r += 256) {
    unsigned q = rec[r];
    int p = atomicAdd(&lcur[q >> 17], 1);
    nbr[p] = (int)(q & 0x1FFFFu);
  }
}

// ---------- fused feature prep: user-emb f32->f16 | movie init | weight pack ----------
#define PREP_U 6250    // NU*64/4/256
#define PREP_M 12500   // (NM+3)/4
__global__ void __launch_bounds__(256)
k_prep(const float4* __restrict__ uemb4, unsigned short* __restrict__ uemb_h,
       const float* __restrict__ movie_x, const float* __restrict__ lin_W,
       const float* __restrict__ lin_b, const float* __restrict__ movie_emb,
       unsigned short* __restrict__ x_movie,
       const float* __restrict__ Wl0, const float* __restrict__ Wr0,
       const float* __restrict__ Wl1, const float* __restrict__ Wr1,
       const float* __restrict__ Wl2, const float* __restrict__ Wr2,
       const float* __restrict__ Wl3, const float* __restrict__ Wr3,
       unsigned short* __restrict__ Wc) {
  __shared__ float lwT[20 * 65];
  int b = blockIdx.x;
  if (b < PREP_U) {
    int i = b * 256 + threadIdx.x;  // < NU*16
    float4 v = uemb4[i];
    uint2 o;
    o.x = pk2h(v.x, v.y);
    o.y = pk2h(v.z, v.w);
    *(uint2*)(uemb_h + (size_t)i * 4) = o;
  } else if (b < PREP_U + PREP_M) {
    int bb = b - PREP_U;
    for (int gidx = threadIdx.x; gidx < 64 * 20; gidx += 256) {
      int h = gidx / 20;
      int f = gidx - h * 20;
      lwT[f * 65 + h] = lin_W[gidx];
    }
    __syncthreads();
    int w = (bb * 256 + (int)threadIdx.x) >> 6;
    int h = threadIdx.x & 63;
    if (w >= NM) return;
    float acc = lin_b[h] + movie_emb[(size_t)w * 64 + h];
    const float* mx = movie_x + (size_t)w * 20;
    #pragma unroll
    for (int f = 0; f < 20; f++) acc += mx[f] * lwT[f * 65 + h];
    x_movie[(size_t)w * 64 + h] = __builtin_bit_cast(unsigned short, (__half)__float2half(acc));
  } else {
    int wb = b - PREP_U - PREP_M;  // 0..127
    int which = wb >> 5;
    const float* Wl = which == 0 ? Wl0 : which == 1 ? Wl1 : which == 2 ? Wl2 : Wl3;
    const float* Wr = which == 0 ? Wr0 : which == 1 ? Wr1 : which == 2 ? Wr2 : Wr3;
    int i = (wb & 31) * 256 + threadIdx.x;
    if (i >= 8192) return;
    int h = i >> 7, k = i & 127;
    float v = (k < 64) ? Wl[h * 64 + k] : Wr[h * 64 + (k - 64)];
    Wc[which * 8192 + i] = __builtin_bit_cast(unsigned short, (__half)__float2half(v));
  }
}

// ---------- mean-gather, both relations in one dispatch ----------
// Packed-f16 accumulation: __hfma2 -> v_pk_fma_f16, ONE instruction per 2
// feature-MACs with no unpack (round-13 post-mortem: both bf16 shift+fma
// and f16 cvt+fma paths cost 2 VALU ops/feature; pk_fma costs 0.5).
// Mask folded in as half2 {1,1}/{0,0}. Cross-lane reduce and mean scale
// also in half2 (error after deg-division ~4e-4, margin is 6x).
__global__ void __launch_bounds__(256)
k_gmean2(const unsigned short* __restrict__ xsrcM,
         const unsigned short* __restrict__ xsrcU,
         const int* __restrict__ nbr, const int* __restrict__ off,
         unsigned short* __restrict__ meanM, unsigned short* __restrict__ meanU) {
  int gw = (blockIdx.x * blockDim.x + threadIdx.x) >> 6;
  int lane = threadIdx.x & 63;
  if (gw >= NM + NU) return;  // wave-uniform
  bool mv = gw < NM;
  const unsigned short* xsrc = mv ? xsrcM : xsrcU;
  const int* offb = mv ? off : off + NKM;
  int w = mv ? gw : gw - NM;
  int R = mv ? RM : RU;
  unsigned short* meanT = mv ? meanM : meanU;
  int g = lane >> 3;
  int i = lane & 7;
  __half2 aa2[4];
  #pragma unroll
  for (int k = 0; k < 4; k++) aa2[k] = __builtin_bit_cast(__half2, 0u);

  int s0 = offb[w * R];
  int eN = offb[(w + 1) * R];
  for (int base = s0; base < eN; base += 32) {
    int cnw = eN - base;
    if (cnw > 32) cnw = 32;
    int lim = cnw - 1;
    int my = nbr[base + (lane < cnw ? lane : 0)];
    uint4 d0, d1, d2, d3;
    int j0 = __shfl(my, min(0 * 8 + g, lim));
    int j1 = __shfl(my, min(1 * 8 + g, lim));
    d0 = *(const uint4*)(xsrc + (size_t)j0 * 64 + i * 8);
    d1 = *(const uint4*)(xsrc + (size_t)j1 * 64 + i * 8);
    bool hi = cnw > 16;
    if (hi) {
      int j2 = __shfl(my, min(2 * 8 + g, lim));
      int j3 = __shfl(my, min(3 * 8 + g, lim));
      d2 = *(const uint4*)(xsrc + (size_t)j2 * 64 + i * 8);
      d3 = *(const uint4*)(xsrc + (size_t)j3 * 64 + i * 8);
    }
    #define CONSUME(dd, c)                                                    \
      {                                                                       \
        unsigned mcu = ((c) * 8 + g < cnw) ? 0x3C003C00u : 0u;                \
        __half2 mc2 = __builtin_bit_cast(__half2, mcu);                       \
        aa2[0] = __hfma2(__builtin_bit_cast(__half2, dd.x), mc2, aa2[0]);     \
        aa2[1] = __hfma2(__builtin_bit_cast(__half2, dd.y), mc2, aa2[1]);     \
        aa2[2] = __hfma2(__builtin_bit_cast(__half2, dd.z), mc2, aa2[2]);     \
        aa2[3] = __hfma2(__builtin_bit_cast(__half2, dd.w), mc2, aa2[3]);     \
      }
    CONSUME(d0, 0)
    CONSUME(d1, 1)
    if (hi) {
      CONSUME(d2, 2)
      CONSUME(d3, 3)
    }
    #undef CONSUME
  }
  // cross-row-slot reduce over g (lane bits 3..5), packed adds
  #pragma unroll
  for (int m = 8; m <= 32; m <<= 1) {
    #pragma unroll
    for (int k = 0; k < 4; k++) aa2[k] = __hadd2(aa2[k], shfl_xor_h2(aa2[k], m));
  }
  float inv = 1.0f / fmaxf((float)(eN - s0), 1.0f);
  if (g == 0) {
    __half2 invh = __float2half2_rn(inv);
    uint4 o;
    o.x = __builtin_bit_cast(unsigned, __hmul2(aa2[0], invh));
    o.y = __builtin_bit_cast(unsigned, __hmul2(aa2[1], invh));
    o.z = __builtin_bit_cast(unsigned, __hmul2(aa2[2], invh));
    o.w = __builtin_bit_cast(unsigned, __hmul2(aa2[3], invh));
    *(uint4*)(meanT + ((size_t)w << 6) + i * 8) = o;
  }
}

// ---------- SAGE transform as f16 MFMA GEMM, both relations in one dispatch ----------
template <int RELU>
__global__ void __launch_bounds__(256)
k_sage_gemm2(const unsigned short* __restrict__ meanM, const unsigned short* __restrict__ dvM,
             const unsigned short* __restrict__ WcM, const float* __restrict__ biasM,
             unsigned short* __restrict__ outM,
             const unsigned short* __restrict__ meanU, const unsigned short* __restrict__ dvU,
             const unsigned short* __restrict__ WcU, const float* __restrict__ biasU,
             unsigned short* __restrict__ outU) {
  __shared__ float ot[4][16][68];
  const int tM = NM / 16, tU = NU / 16;
  int wv4 = threadIdx.x >> 6;
  int wvg = (blockIdx.x * blockDim.x + threadIdx.x) >> 6;
  int lane = threadIdx.x & 63;
  bool active = wvg < tM + tU;
  bool mv = wvg < tM;
  const unsigned short* meanT = mv ? meanM : meanU;
  const unsigned short* dvT = mv ? dvM : dvU;
  const unsigned short* Wc = mv ? WcM : WcU;
  const float* bias = mv ? biasM : biasU;
  unsigned short* outT = mv ? outM : outU;
  int n0 = (mv ? wvg : wvg - tM) * 16;
  int rr = lane & 15;
  int ks = lane >> 4;

  if (active) {
    f16x8 bf[4][4];
    #pragma unroll
    for (int t = 0; t < 4; t++)
      #pragma unroll
      for (int kk = 0; kk < 4; kk++)
        bf[t][kk] = *(const f16x8*)(Wc + ((t * 16 + rr) << 7) + kk * 32 + ks * 8);
    f32x4 acc[4];
    #pragma unroll
    for (int t = 0; t < 4; t++) {
      float b = bias[t * 16 + rr];
      acc[t] = (f32x4){b, b, b, b};
    }
    const unsigned short* am = meanT + ((size_t)(n0 + rr) << 6);
    const unsigned short* ad = dvT + ((size_t)(n0 + rr) << 6);
    f16x8 af[4];
    af[0] = *(const f16x8*)(am + ks * 8);
    af[1] = *(const f16x8*)(am + 32 + ks * 8);
    af[2] = *(const f16x8*)(ad + ks * 8);
    af[3] = *(const f16x8*)(ad + 32 + ks * 8);
    #pragma unroll
    for (int kk = 0; kk < 4; kk++)
      #pragma unroll
      for (int t = 0; t < 4; t++)
        acc[t] = __builtin_amdgcn_mfma_f32_16x16x32_f16(af[kk], bf[t][kk], acc[t], 0, 0, 0);
    #pragma unroll
    for (int t = 0; t < 4; t++)
      #pragma unroll
      for (int r = 0; r < 4; r++) {
        float v = acc[t][r];
        if (RELU) v = fmaxf(v, 0.f);
        ot[wv4][(lane >> 4) * 4 + r][t * 16 + rr] = v;
      }
  }
  __syncthreads();
  if (active) {
    int nn = lane >> 2, c4 = lane & 3;
    const float* src = &ot[wv4][nn][c4 * 16];
    uint4 o0, o1;
    o0.x = pk2h(src[0], src[1]);  o0.y = pk2h(src[2], src[3]);
    o0.z = pk2h(src[4], src[5]);  o0.w = pk2h(src[6], src[7]);
    o1.x = pk2h(src[8], src[9]);  o1.y = pk2h(src[10], src[11]);
    o1.z = pk2h(src[12], src[13]); o1.w = pk2h(src[14], src[15]);
    unsigned short* dst = outT + ((size_t)(n0 + nn) << 6) + c4 * 16;
    *(uint4*)dst = o0;
    *(uint4*)(dst + 8) = o1;
  }
}

// 16 lanes per edge on f16 rows; shfl_xor reduce within 16-lane group.
__global__ void __launch_bounds__(256)
k_dot(const unsigned short* __restrict__ u2, const unsigned short* __restrict__ m2,
      const int* __restrict__ eu, const int* __restrict__ em,
      float* __restrict__ out, int L) {
  int wave = (blockIdx.x * blockDim.x + threadIdx.x) >> 6;
  int lane = threadIdx.x & 63;
  int sub = lane & 15;
  int l = wave * 4 + (lane >> 4);
  int lc = l < L ? l : (L - 1);
  int iu = eu[lc], im = em[lc];
  uint2 a = *(const uint2*)(u2 + (size_t)iu * 64 + sub * 4);
  uint2 b = *(const uint2*)(m2 + (size_t)im * 64 + sub * 4);
  float2 a0 = __half22float2(__builtin_bit_cast(__half2, a.x));
  float2 a1 = __half22float2(__builtin_bit_cast(__half2, a.y));
  float2 b0 = __half22float2(__builtin_bit_cast(__half2, b.x));
  float2 b1 = __half22float2(__builtin_bit_cast(__half2, b.y));
  float s = a0.x * b0.x + a0.y * b0.y + a1.x * b1.x + a1.y * b1.y;
  s += __shfl_xor(s, 1);
  s += __shfl_xor(s, 2);
  s += __shfl_xor(s, 4);
  s += __shfl_xor(s, 8);
  if (sub == 0 && l < L) out[l] = s;
}

extern "C" void kernel_launch(void* const* d_in, const int* in_sizes, int n_in,
                              void* d_out, int out_size, void* d_ws, size_t ws_size,
                              hipStream_t stream) {
  const float* movie_x   = (const float*)d_in[2];
  const int*   esrc      = (const int*)d_in[3];
  const int*   edst      = (const int*)d_in[4];
  const int*   eli_u     = (const int*)d_in[5];
  const int*   eli_m     = (const int*)d_in[6];
  const float* user_emb  = (const float*)d_in[7];
  const float* movie_emb = (const float*)d_in[8];
  const float* lin_W     = (const float*)d_in[9];
  const float* lin_b     = (const float*)d_in[10];
  const float* W1um_l = (const float*)d_in[11];
  const float* W1um_r = (const float*)d_in[12];
  const float* W1mu_l = (const float*)d_in[13];
  const float* W1mu_r = (const float*)d_in[14];
  const float* W2um_l = (const float*)d_in[15];
  const float* W2um_r = (const float*)d_in[16];
  const float* W2mu_l = (const float*)d_in[17];
  const float* W2mu_r = (const float*)d_in[18];
  const float* b1um = (const float*)d_in[19];
  const float* b1mu = (const float*)d_in[20];
  const float* b2um = (const float*)d_in[21];
  const float* b2mu = (const float*)d_in[22];
  const int E = in_sizes[3];
  const int L = in_sizes[5];

  char* ws = (char*)d_ws;
  size_t o = 0;
  auto alloc = [&](size_t bytes) -> void* {
    void* p = ws + o;
    o = (o + bytes + 255) & ~(size_t)255;
    return p;
  };
  unsigned short* uemb_h   = (unsigned short*)alloc((size_t)NU * 64 * 2);
  unsigned short* xmovie_h = (unsigned short*)alloc((size_t)NM * 64 * 2);
  unsigned short* m1_h     = (unsigned short*)alloc((size_t)NM * 64 * 2);
  unsigned short* u1_h     = (unsigned short*)alloc((size_t)NU * 64 * 2);
  unsigned short* m2_h     = (unsigned short*)alloc((size_t)NM * 64 * 2);
  unsigned short* u2_h     = (unsigned short*)alloc((size_t)NU * 64 * 2);
  unsigned short* mean_m   = (unsigned short*)alloc((size_t)NM * 64 * 2);
  unsigned short* mean_u   = (unsigned short*)alloc((size_t)NU * 64 * 2);
  unsigned short* wcat     = (unsigned short*)alloc(4 * 8192 * 2);
  int* cnt   = (int*)alloc((size_t)(NKM + NKU) * 4);
  int* off   = (int*)alloc((size_t)(NKM + NKU + 1) * 4);
  int* bs    = (int*)alloc(4096);
  int* nbr   = (int*)alloc((size_t)2 * E * 4);
  int* hmat  = (int*)alloc((size_t)(2 * NH + 1) * 4);
  int* hbase = (int*)alloc((size_t)(2 * NH + 1) * 4);
  // rec buffers (E x 4B = 10MB each) overlay dead table regions during build.
  unsigned* rec_m = (unsigned*)uemb_h;
  unsigned* rec_u = (unsigned*)u1_h;

  // ===== merged CSR build =====
  k_hist2<<<NBLK, 256, 0, stream>>>(esrc, edst, hmat, E);
  {
    int n = 2 * NH, nb = (n + 1023) / 1024;
    k_scan_part<<<nb, 256, 0, stream>>>(hmat, hbase, bs, n);
    k_scan_top<<<1, 64, 0, stream>>>(bs, nb);
    k_scan_add<<<(n + 1 + 255) / 256, 256, 0, stream>>>(hbase, bs, n, 2 * E);
  }
  k_part2<<<NBLK, 256, 0, stream>>>(esrc, edst, hbase, rec_m, rec_u, E);
  k_bcount2<<<2 * NBKT, 256, 0, stream>>>(rec_m, rec_u, hbase, cnt, E);
  {
    int n = NKM + NKU, nb = (n + 1023) / 1024;
    k_scan_part<<<nb, 256, 0, stream>>>(cnt, off, bs, n);
    k_scan_top<<<1, 64, 0, stream>>>(bs, nb);
    k_scan_add<<<(n + 1 + 255) / 256, 256, 0, stream>>>(off, bs, n, 2 * E);
  }
  k_bscatter2<<<2 * NBKT, 256, 0, stream>>>(rec_m, rec_u, hbase, off, nbr, E);

  // ===== fused feature prep (rec overlays now dead) =====
  k_prep<<<PREP_U + PREP_M + 128, 256, 0, stream>>>(
      (const float4*)user_emb, uemb_h, movie_x, lin_W, lin_b, movie_emb, xmovie_h,
      W1um_l, W1um_r, W1mu_l, W1mu_r, W2um_l, W2um_r, W2mu_l, W2mu_r, wcat);
  unsigned short* wc1um = wcat;
  unsigned short* wc1mu = wcat + 8192;
  unsigned short* wc2um = wcat + 16384;
  unsigned short* wc2mu = wcat + 24576;

  int gGm = (NM + NU + 3) / 4;
  int gG = ((NM / 16 + NU / 16) + 3) / 4;
  // layer 1
  k_gmean2<<<gGm, 256, 0, stream>>>(uemb_h, xmovie_h, nbr, off, mean_m, mean_u);
  k_sage_gemm2<1><<<gG, 256, 0, stream>>>(mean_m, xmovie_h, wc1um, b1um, m1_h,
                                          mean_u, uemb_h, wc1mu, b1mu, u1_h);
  // layer 2
  k_gmean2<<<gGm, 256, 0, stream>>>(u1_h, m1_h, nbr, off, mean_m, mean_u);
  k_sage_gemm2<0><<<gG, 256, 0, stream>>>(mean_m, m1_h, wc2um, b2um, m2_h,
                                          mean_u, u1_h, wc2mu, b2mu, u2_h);

  // 16 edges per 256-thread block
  k_dot<<<(L + 15) / 16, 256, 0, stream>>>(u2_h, m2_h, eli_u, eli_m, (float*)d_out, L);
}

// Round 15
// 344.638 us; speedup vs baseline: 6.3845x; 1.0885x over previous
//
#include <hip/hip_runtime.h>
#include <hip/hip_fp16.h>

#define NU 100000
#define NM 50000
#define RM 4      // user-table sub-ranges (movie-dest gather source)
#define RU 2      // movie-table sub-ranges (user-dest gather source)
#define NBLK 256  // partition blocks
#define NBKT 196  // coarse buckets (50000>>8 -> 196, 100000>>9 -> 196)
#define NH (NBKT * NBLK)

typedef __attribute__((ext_vector_type(8))) _Float16 f16x8;
typedef __attribute__((ext_vector_type(4))) float f32x4;

__device__ __forceinline__ unsigned pk2h(float a, float b) {
  return __builtin_bit_cast(unsigned, __floats2half2_rn(a, b));
}
__device__ __forceinline__ __half2 shfl_xor_h2(__half2 v, int m) {
  return __builtin_bit_cast(__half2, __shfl_xor(__builtin_bit_cast(int, v), m));
}
__device__ __forceinline__ __half2 u2h2(unsigned v) {
  return __builtin_bit_cast(__half2, v);
}

// ---------- scan machinery (for the coarse hist matrix only) ----------
__global__ void k_scan_part(const int* __restrict__ cnt, int* __restrict__ off,
                            int* __restrict__ bsum, int n) {
  __shared__ int wsum[4];
  int t = threadIdx.x;
  int base = blockIdx.x * 1024 + t * 4;
  int v0 = (base + 0 < n) ? cnt[base + 0] : 0;
  int v1 = (base + 1 < n) ? cnt[base + 1] : 0;
  int v2 = (base + 2 < n) ? cnt[base + 2] : 0;
  int v3 = (base + 3 < n) ? cnt[base + 3] : 0;
  int s = v0 + v1 + v2 + v3;
  int lane = t & 63;
  int inc = s;
  #pragma unroll
  for (int d = 1; d < 64; d <<= 1) {
    int x = __shfl_up(inc, d);
    if (lane >= d) inc += x;
  }
  int wid = t >> 6;
  if (lane == 63) wsum[wid] = inc;
  __syncthreads();
  int woff = 0;
  for (int i = 0; i < wid; i++) woff += wsum[i];
  int excl = woff + inc - s;
  if (base + 0 < n) off[base + 0] = excl;
  if (base + 1 < n) off[base + 1] = excl + v0;
  if (base + 2 < n) off[base + 2] = excl + v0 + v1;
  if (base + 3 < n) off[base + 3] = excl + v0 + v1 + v2;
  if (t == 255) bsum[blockIdx.x] = woff + inc;
}

__global__ void k_scan_top(int* bsum, int nb) {
  int lane = threadIdx.x;
  int carry = 0;
  for (int base = 0; base < nb; base += 64) {
    int i = base + lane;
    int v = (i < nb) ? bsum[i] : 0;
    int inc = v;
    #pragma unroll
    for (int d = 1; d < 64; d <<= 1) {
      int x = __shfl_up(inc, d);
      if (lane >= d) inc += x;
    }
    if (i < nb) bsum[i] = carry + inc - v;
    carry += __shfl(inc, 63);
  }
}

__global__ void k_scan_add(int* __restrict__ off, const int* __restrict__ bsum,
                           int n, int total) {
  int i = blockIdx.x * blockDim.x + threadIdx.x;
  if (i < n) {
    off[i] = off[i] + bsum[i >> 10];
  } else if (i == n) {
    off[n] = total;
  }
}

// ---------- merged radix-partition build (both CSRs per pass) ----------
__global__ void __launch_bounds__(256)
k_hist2(const int* __restrict__ esrc, const int* __restrict__ edst,
        int* __restrict__ hmat, int E) {
  __shared__ int hm[NBKT], hu[NBKT];
  int t = threadIdx.x;
  for (int b = t; b < NBKT; b += 256) { hm[b] = 0; hu[b] = 0; }
  __syncthreads();
  int chunk = (E + NBLK - 1) / NBLK;
  int beg = blockIdx.x * chunk;
  int end = min(beg + chunk, E);
  for (int e = beg + t; e < end; e += 256) {
    atomicAdd(&hm[edst[e] >> 8], 1);
    atomicAdd(&hu[esrc[e] >> 9], 1);
  }
  __syncthreads();
  for (int b = t; b < NBKT; b += 256) {
    hmat[b * NBLK + blockIdx.x] = hm[b];
    hmat[NH + b * NBLK + blockIdx.x] = hu[b];
  }
}

// 4B packed records: (lkey << 17) | payload
__global__ void __launch_bounds__(256)
k_part2(const int* __restrict__ esrc, const int* __restrict__ edst,
        const int* __restrict__ hbase, unsigned* __restrict__ rec_m,
        unsigned* __restrict__ rec_u, int E) {
  __shared__ int cm[NBKT], cu[NBKT];
  int t = threadIdx.x;
  for (int b = t; b < NBKT; b += 256) {
    cm[b] = hbase[b * NBLK + blockIdx.x];
    cu[b] = hbase[NH + b * NBLK + blockIdx.x] - E;
  }
  __syncthreads();
  int chunk = (E + NBLK - 1) / NBLK;
  int beg = blockIdx.x * chunk;
  int end = min(beg + chunk, E);
  for (int e = beg + t; e < end; e += 256) {
    int d = edst[e], s = esrc[e];
    unsigned lm = (unsigned)(d & 255) * RM + (unsigned)s / 25000u;
    int pm = atomicAdd(&cm[d >> 8], 1);
    rec_m[pm] = (lm << 17) | (unsigned)s;
    unsigned lu = (unsigned)(s & 511) * RU + (unsigned)d / 25000u;
    int pu = atomicAdd(&cu[s >> 9], 1);
    rec_u[pu] = (lu << 17) | (unsigned)d;
  }
}

// Merged count + LOCAL scan + scatter. Key fact: rec is bucket-major and the
// CSR is node-major with IDENTICAL bucket boundaries, so this bucket's CSR
// region starts exactly at its rec start (rs) -- the 500K global scan is
// bucket-local (<=1024 elems, in LDS). Writes node-level offsets for gmean2.
// Second rec pass is L2-hot (bucket chunk ~51KB). grid = 2*NBKT.
__global__ void __launch_bounds__(256)
k_bcsr(const unsigned* __restrict__ rec_m, const unsigned* __restrict__ rec_u,
       const int* __restrict__ hbase, int* __restrict__ nbr,
       int* __restrict__ nodeoffM, int* __restrict__ nodeoffU, int E) {
  __shared__ int lcnt[1024];
  __shared__ int wsum[4];
  int b = blockIdx.x, t = threadIdx.x;
  bool mv = b < NBKT;
  int bb = mv ? b : b - NBKT;
  const unsigned* rec = mv ? rec_m : rec_u;
  int R = mv ? RM : RU, SH = mv ? 8 : 9, N = mv ? NM : NU;
  int* nodeoff = mv ? nodeoffM : nodeoffU;
  int rs = mv ? hbase[bb * NBLK] : hbase[NH + bb * NBLK] - E;
  int re = mv ? hbase[(bb + 1) * NBLK] : hbase[NH + (bb + 1) * NBLK] - E;
  int nbase = mv ? 0 : E;  // nbr region offset for this half
  int node_lo = bb << SH;
  int node_hi = min(node_lo + (1 << SH), N);
  for (int i = t; i < 1024; i += 256) lcnt[i] = 0;
  __syncthreads();
  for (int r = rs + t; r < re; r += 256)
    atomicAdd(&lcnt[rec[r] >> 17], 1);
  __syncthreads();
  // block-wide exclusive scan of lcnt (4 elems/thread), rebased to nbase+rs
  int i0 = t * 4;
  int v0 = lcnt[i0], v1 = lcnt[i0 + 1], v2 = lcnt[i0 + 2], v3 = lcnt[i0 + 3];
  int s = v0 + v1 + v2 + v3;
  int lane = t & 63;
  int inc = s;
  #pragma unroll
  for (int d = 1; d < 64; d <<= 1) {
    int x = __shfl_up(inc, d);
    if (lane >= d) inc += x;
  }
  int wid = t >> 6;
  if (lane == 63) wsum[wid] = inc;
  __syncthreads();
  int woff = 0;
  for (int k = 0; k < wid; k++) woff += wsum[k];
  int p0 = nbase + rs + woff + inc - s;
  int p1 = p0 + v0, p2 = p1 + v1, p3 = p2 + v2;
  lcnt[i0] = p0; lcnt[i0 + 1] = p1; lcnt[i0 + 2] = p2; lcnt[i0 + 3] = p3;
  // publish node-level offsets (keys i with i%R==0 -> node node_lo+i/R)
  if (R == 4) {
    int node = node_lo + (i0 >> 2);
    if (node < node_hi) nodeoff[node] = p0;
  } else {
    int node = node_lo + (i0 >> 1);
    if (node < node_hi) nodeoff[node] = p0;
    if (node + 1 < node_hi) nodeoff[node + 1] = p2;
  }
  if (t == 0) nodeoff[node_hi] = nbase + re;  // benign same-value race with next bucket
  __syncthreads();
  // scatter (rec chunk now L2-hot)
  for (int r = rs + t; r < re; r += 256) {
    unsigned q = rec[r];
    int p = atomicAdd(&lcnt[q >> 17], 1);
    nbr[p] = (int)(q & 0x1FFFFu);
  }
}

// ---------- fused feature prep: user-emb f32->f16 | movie init | weight pack ----------
#define PREP_U 6250    // NU*64/4/256
#define PREP_M 12500   // (NM+3)/4
__global__ void __launch_bounds__(256)
k_prep(const float4* __restrict__ uemb4, unsigned short* __restrict__ uemb_h,
       const float* __restrict__ movie_x, const float* __restrict__ lin_W,
       const float* __restrict__ lin_b, const float* __restrict__ movie_emb,
       unsigned short* __restrict__ x_movie,
       const float* __restrict__ Wl0, const float* __restrict__ Wr0,
       const float* __restrict__ Wl1, const float* __restrict__ Wr1,
       const float* __restrict__ Wl2, const float* __restrict__ Wr2,
       const float* __restrict__ Wl3, const float* __restrict__ Wr3,
       unsigned short* __restrict__ Wc) {
  __shared__ float lwT[20 * 65];
  int b = blockIdx.x;
  if (b < PREP_U) {
    int i = b * 256 + threadIdx.x;  // < NU*16
    float4 v = uemb4[i];
    uint2 o;
    o.x = pk2h(v.x, v.y);
    o.y = pk2h(v.z, v.w);
    *(uint2*)(uemb_h + (size_t)i * 4) = o;
  } else if (b < PREP_U + PREP_M) {
    int bb = b - PREP_U;
    for (int gidx = threadIdx.x; gidx < 64 * 20; gidx += 256) {
      int h = gidx / 20;
      int f = gidx - h * 20;
      lwT[f * 65 + h] = lin_W[gidx];
    }
    __syncthreads();
    int w = (bb * 256 + (int)threadIdx.x) >> 6;
    int h = threadIdx.x & 63;
    if (w >= NM) return;
    float acc = lin_b[h] + movie_emb[(size_t)w * 64 + h];
    const float* mx = movie_x + (size_t)w * 20;
    #pragma unroll
    for (int f = 0; f < 20; f++) acc += mx[f] * lwT[f * 65 + h];
    x_movie[(size_t)w * 64 + h] = __builtin_bit_cast(unsigned short, (__half)__float2half(acc));
  } else {
    int wb = b - PREP_U - PREP_M;  // 0..127
    int which = wb >> 5;
    const float* Wl = which == 0 ? Wl0 : which == 1 ? Wl1 : which == 2 ? Wl2 : Wl3;
    const float* Wr = which == 0 ? Wr0 : which == 1 ? Wr1 : which == 2 ? Wr2 : Wr3;
    int i = (wb & 31) * 256 + threadIdx.x;
    if (i >= 8192) return;
    int h = i >> 7, k = i & 127;
    float v = (k < 64) ? Wl[h * 64 + k] : Wr[h * 64 + (k - 64)];
    Wc[which * 8192 + i] = __builtin_bit_cast(unsigned short, (__half)__float2half(v));
  }
}

// ---------- mean-gather, both relations in one dispatch ----------
// Full-window fast path: deg>>5 windows with NO clamps/masks (hadd2), then
// one masked tail. Gathers use SGPR-base + unsigned 32-bit voffset
// ((j<<7)+i*16, tables < 16MB) -- saves the 64-bit addr chain per gather.
__global__ void __launch_bounds__(256)
k_gmean2(const unsigned short* __restrict__ xsrcM,
         const unsigned short* __restrict__ xsrcU,
         const int* __restrict__ nbr,
         const int* __restrict__ nodeoffM, const int* __restrict__ nodeoffU,
         unsigned short* __restrict__ meanM, unsigned short* __restrict__ meanU) {
  int gw = (blockIdx.x * blockDim.x + threadIdx.x) >> 6;
  int lane = threadIdx.x & 63;
  if (gw >= NM + NU) return;  // wave-uniform
  bool mv = gw < NM;
  const char* xb = (const char*)(mv ? xsrcM : xsrcU);
  const int* noff = mv ? nodeoffM : nodeoffU;
  int w = mv ? gw : gw - NM;
  unsigned short* meanT = mv ? meanM : meanU;
  int g = lane >> 3;
  unsigned ib = (unsigned)(lane & 7) * 16;  // byte sub-offset within 128B row
  __half2 aa2[4];
  #pragma unroll
  for (int k = 0; k < 4; k++) aa2[k] = u2h2(0u);

  int s0 = noff[w], eN = noff[w + 1];
  int deg = eN - s0;
  int base = s0;
  // full 32-row windows: no clamps, no masks
  for (int nf = deg >> 5; nf > 0; nf--, base += 32) {
    int my = nbr[base + (lane & 31)];
    int j0 = __shfl(my, 0 * 8 + g);
    int j1 = __shfl(my, 1 * 8 + g);
    int j2 = __shfl(my, 2 * 8 + g);
    int j3 = __shfl(my, 3 * 8 + g);
    uint4 d0 = *(const uint4*)(xb + ((unsigned)(j0 << 7) + ib));
    uint4 d1 = *(const uint4*)(xb + ((unsigned)(j1 << 7) + ib));
    uint4 d2 = *(const uint4*)(xb + ((unsigned)(j2 << 7) + ib));
    uint4 d3 = *(const uint4*)(xb + ((unsigned)(j3 << 7) + ib));
    #define ADD4(dd)                                   \
      aa2[0] = __hadd2(aa2[0], u2h2(dd.x));            \
      aa2[1] = __hadd2(aa2[1], u2h2(dd.y));            \
      aa2[2] = __hadd2(aa2[2], u2h2(dd.z));            \
      aa2[3] = __hadd2(aa2[3], u2h2(dd.w));
    ADD4(d0) ADD4(d1) ADD4(d2) ADD4(d3)
    #undef ADD4
  }
  // masked tail window (rem in [1,31])
  int rem = eN - base;
  if (rem > 0) {
    int lim = rem - 1;
    int my = nbr[base + (lane < rem ? lane : 0)];
    uint4 d0, d1, d2, d3;
    int j0 = __shfl(my, min(0 * 8 + g, lim));
    int j1 = __shfl(my, min(1 * 8 + g, lim));
    d0 = *(const uint4*)(xb + ((unsigned)(j0 << 7) + ib));
    d1 = *(const uint4*)(xb + ((unsigned)(j1 << 7) + ib));
    bool hi = rem > 16;
    if (hi) {
      int j2 = __shfl(my, min(2 * 8 + g, lim));
      int j3 = __shfl(my, min(3 * 8 + g, lim));
      d2 = *(const uint4*)(xb + ((unsigned)(j2 << 7) + ib));
      d3 = *(const uint4*)(xb + ((unsigned)(j3 << 7) + ib));
    }
    #define CONSUME(dd, c)                                              \
      {                                                                 \
        unsigned mcu = ((c) * 8 + g < rem) ? 0x3C003C00u : 0u;          \
        __half2 mc2 = u2h2(mcu);                                        \
        aa2[0] = __hfma2(u2h2(dd.x), mc2, aa2[0]);                      \
        aa2[1] = __hfma2(u2h2(dd.y), mc2, aa2[1]);                      \
        aa2[2] = __hfma2(u2h2(dd.z), mc2, aa2[2]);                      \
        aa2[3] = __hfma2(u2h2(dd.w), mc2, aa2[3]);                      \
      }
    CONSUME(d0, 0)
    CONSUME(d1, 1)
    if (hi) {
      CONSUME(d2, 2)
      CONSUME(d3, 3)
    }
    #undef CONSUME
  }
  // cross-row-slot reduce over g (lane bits 3..5), packed adds
  #pragma unroll
  for (int m = 8; m <= 32; m <<= 1) {
    #pragma unroll
    for (int k = 0; k < 4; k++) aa2[k] = __hadd2(aa2[k], shfl_xor_h2(aa2[k], m));
  }
  float inv = 1.0f / fmaxf((float)deg, 1.0f);
  if (g == 0) {
    __half2 invh = __float2half2_rn(inv);
    uint4 o;
    o.x = __builtin_bit_cast(unsigned, __hmul2(aa2[0], invh));
    o.y = __builtin_bit_cast(unsigned, __hmul2(aa2[1], invh));
    o.z = __builtin_bit_cast(unsigned, __hmul2(aa2[2], invh));
    o.w = __builtin_bit_cast(unsigned, __hmul2(aa2[3], invh));
    *(uint4*)((char*)meanT + ((unsigned)(w << 7) + ib)) = o;
  }
}

// ---------- SAGE transform as f16 MFMA GEMM, both relations in one dispatch ----------
template <int RELU>
__global__ void __launch_bounds__(256)
k_sage_gemm2(const unsigned short* __restrict__ meanM, const unsigned short* __restrict__ dvM,
             const unsigned short* __restrict__ WcM, const float* __restrict__ biasM,
             unsigned short* __restrict__ outM,
             const unsigned short* __restrict__ meanU, const unsigned short* __restrict__ dvU,
             const unsigned short* __restrict__ WcU, const float* __restrict__ biasU,
             unsigned short* __restrict__ outU) {
  __shared__ float ot[4][16][68];
  const int tM = NM / 16, tU = NU / 16;
  int wv4 = threadIdx.x >> 6;
  int wvg = (blockIdx.x * blockDim.x + threadIdx.x) >> 6;
  int lane = threadIdx.x & 63;
  bool active = wvg < tM + tU;
  bool mv = wvg < tM;
  const unsigned short* meanT = mv ? meanM : meanU;
  const unsigned short* dvT = mv ? dvM : dvU;
  const unsigned short* Wc = mv ? WcM : WcU;
  const float* bias = mv ? biasM : biasU;
  unsigned short* outT = mv ? outM : outU;
  int n0 = (mv ? wvg : wvg - tM) * 16;
  int rr = lane & 15;
  int ks = lane >> 4;

  if (active) {
    f16x8 bf[4][4];
    #pragma unroll
    for (int t = 0; t < 4; t++)
      #pragma unroll
      for (int kk = 0; kk < 4; kk++)
        bf[t][kk] = *(const f16x8*)((const char*)Wc + (unsigned)(((t * 16 + rr) << 8) + kk * 64 + ks * 16));
    f32x4 acc[4];
    #pragma unroll
    for (int t = 0; t < 4; t++) {
      float b = bias[t * 16 + rr];
      acc[t] = (f32x4){b, b, b, b};
    }
    const char* am = (const char*)meanT + (unsigned)((n0 + rr) << 7);
    const char* ad = (const char*)dvT + (unsigned)((n0 + rr) << 7);
    f16x8 af[4];
    af[0] = *(const f16x8*)(am + ks * 16);
    af[1] = *(const f16x8*)(am + 64 + ks * 16);
    af[2] = *(const f16x8*)(ad + ks * 16);
    af[3] = *(const f16x8*)(ad + 64 + ks * 16);
    #pragma unroll
    for (int kk = 0; kk < 4; kk++)
      #pragma unroll
      for (int t = 0; t < 4; t++)
        acc[t] = __builtin_amdgcn_mfma_f32_16x16x32_f16(af[kk], bf[t][kk], acc[t], 0, 0, 0);
    #pragma unroll
    for (int t = 0; t < 4; t++)
      #pragma unroll
      for (int r = 0; r < 4; r++) {
        float v = acc[t][r];
        if (RELU) v = fmaxf(v, 0.f);
        ot[wv4][(lane >> 4) * 4 + r][t * 16 + rr] = v;
      }
  }
  __syncthreads();
  if (active) {
    int nn = lane >> 2, c4 = lane & 3;
    const float* src = &ot[wv4][nn][c4 * 16];
    uint4 o0, o1;
    o0.x = pk2h(src[0], src[1]);  o0.y = pk2h(src[2], src[3]);
    o0.z = pk2h(src[4], src[5]);  o0.w = pk2h(src[6], src[7]);
    o1.x = pk2h(src[8], src[9]);  o1.y = pk2h(src[10], src[11]);
    o1.z = pk2h(src[12], src[13]); o1.w = pk2h(src[14], src[15]);
    unsigned short* dst = outT + ((size_t)(n0 + nn) << 6) + c4 * 16;
    *(uint4*)dst = o0;
    *(uint4*)(dst + 8) = o1;
  }
}

// 8 lanes per edge on f16 rows (one uint4 = 16B/lane, 128B/row), shfl_xor
// reduce within 8-lane group. 32 edges per 256-thread block.
__global__ void __launch_bounds__(256)
k_dot(const unsigned short* __restrict__ u2, const unsigned short* __restrict__ m2,
      const int* __restrict__ eu, const int* __restrict__ em,
      float* __restrict__ out, int L) {
  int wave = (blockIdx.x * blockDim.x + threadIdx.x) >> 6;
  int lane = threadIdx.x & 63;
  int sub = lane & 7;
  int l = wave * 8 + (lane >> 3);
  int lc = l < L ? l : (L - 1);
  int iu = eu[lc], im = em[lc];
  uint4 a = *(const uint4*)((const char*)u2 + ((unsigned)(iu << 7) + sub * 16));
  uint4 b = *(const uint4*)((const char*)m2 + ((unsigned)(im << 7) + sub * 16));
  float2 a0 = __half22float2(u2h2(a.x)), b0 = __half22float2(u2h2(b.x));
  float2 a1 = __half22float2(u2h2(a.y)), b1 = __half22float2(u2h2(b.y));
  float2 a2 = __half22float2(u2h2(a.z)), b2 = __half22float2(u2h2(b.z));
  float2 a3 = __half22float2(u2h2(a.w)), b3 = __half22float2(u2h2(b.w));
  float s = a0.x * b0.x + a0.y * b0.y + a1.x * b1.x + a1.y * b1.y
          + a2.x * b2.x + a2.y * b2.y + a3.x * b3.x + a3.y * b3.y;
  s += __shfl_xor(s, 1);
  s += __shfl_xor(s, 2);
  s += __shfl_xor(s, 4);
  if (sub == 0 && l < L) out[l] = s;
}

extern "C" void kernel_launch(void* const* d_in, const int* in_sizes, int n_in,
                              void* d_out, int out_size, void* d_ws, size_t ws_size,
                              hipStream_t stream) {
  const float* movie_x   = (const float*)d_in[2];
  const int*   esrc      = (const int*)d_in[3];
  const int*   edst      = (const int*)d_in[4];
  const int*   eli_u     = (const int*)d_in[5];
  const int*   eli_m     = (const int*)d_in[6];
  const float* user_emb  = (const float*)d_in[7];
  const float* movie_emb = (const float*)d_in[8];
  const float* lin_W     = (const float*)d_in[9];
  const float* lin_b     = (const float*)d_in[10];
  const float* W1um_l = (const float*)d_in[11];
  const float* W1um_r = (const float*)d_in[12];
  const float* W1mu_l = (const float*)d_in[13];
  const float* W1mu_r = (const float*)d_in[14];
  const float* W2um_l = (const float*)d_in[15];
  const float* W2um_r = (const float*)d_in[16];
  const float* W2mu_l = (const float*)d_in[17];
  const float* W2mu_r = (const float*)d_in[18];
  const float* b1um = (const float*)d_in[19];
  const float* b1mu = (const float*)d_in[20];
  const float* b2um = (const float*)d_in[21];
  const float* b2mu = (const float*)d_in[22];
  const int E = in_sizes[3];
  const int L = in_sizes[5];

  char* ws = (char*)d_ws;
  size_t o = 0;
  auto alloc = [&](size_t bytes) -> void* {
    void* p = ws + o;
    o = (o + bytes + 255) & ~(size_t)255;
    return p;
  };
  unsigned short* uemb_h   = (unsigned short*)alloc((size_t)NU * 64 * 2);
  unsigned short* xmovie_h = (unsigned short*)alloc((size_t)NM * 64 * 2);
  unsigned short* m1_h     = (unsigned short*)alloc((size_t)NM * 64 * 2);
  unsigned short* u1_h     = (unsigned short*)alloc((size_t)NU * 64 * 2);
  unsigned short* m2_h     = (unsigned short*)alloc((size_t)NM * 64 * 2);
  unsigned short* u2_h     = (unsigned short*)alloc((size_t)NU * 64 * 2);
  unsigned short* mean_m   = (unsigned short*)alloc((size_t)NM * 64 * 2);
  unsigned short* mean_u   = (unsigned short*)alloc((size_t)NU * 64 * 2);
  unsigned short* wcat     = (unsigned short*)alloc(4 * 8192 * 2);
  int* nodeoffM = (int*)alloc((size_t)(NM + 1) * 4);
  int* nodeoffU = (int*)alloc((size_t)(NU + 1) * 4);
  int* bs    = (int*)alloc(4096);
  int* nbr   = (int*)alloc((size_t)2 * E * 4);
  int* hmat  = (int*)alloc((size_t)(2 * NH + 1) * 4);
  int* hbase = (int*)alloc((size_t)(2 * NH + 1) * 4);
  // rec buffers (E x 4B = 10MB each) overlay dead table regions during build.
  unsigned* rec_m = (unsigned*)uemb_h;
  unsigned* rec_u = (unsigned*)u1_h;

  // ===== merged CSR build =====
  k_hist2<<<NBLK, 256, 0, stream>>>(esrc, edst, hmat, E);
  {
    int n = 2 * NH, nb = (n + 1023) / 1024;
    k_scan_part<<<nb, 256, 0, stream>>>(hmat, hbase, bs, n);
    k_scan_top<<<1, 64, 0, stream>>>(bs, nb);
    k_scan_add<<<(n + 1 + 255) / 256, 256, 0, stream>>>(hbase, bs, n, 2 * E);
  }
  k_part2<<<NBLK, 256, 0, stream>>>(esrc, edst, hbase, rec_m, rec_u, E);
  k_bcsr<<<2 * NBKT, 256, 0, stream>>>(rec_m, rec_u, hbase, nbr, nodeoffM, nodeoffU, E);

  // ===== fused feature prep (rec overlays now dead) =====
  k_prep<<<PREP_U + PREP_M + 128, 256, 0, stream>>>(
      (const float4*)user_emb, uemb_h, movie_x, lin_W, lin_b, movie_emb, xmovie_h,
      W1um_l, W1um_r, W1mu_l, W1mu_r, W2um_l, W2um_r, W2mu_l, W2mu_r, wcat);
  unsigned short* wc1um = wcat;
  unsigned short* wc1mu = wcat + 8192;
  unsigned short* wc2um = wcat + 16384;
  unsigned short* wc2mu = wcat + 24576;

  int gGm = (NM + NU + 3) / 4;
  int gG = ((NM / 16 + NU / 16) + 3) / 4;
  // layer 1
  k_gmean2<<<gGm, 256, 0, stream>>>(uemb_h, xmovie_h, nbr, nodeoffM, nodeoffU, mean_m, mean_u);
  k_sage_gemm2<1><<<gG, 256, 0, stream>>>(mean_m, xmovie_h, wc1um, b1um, m1_h,
                                          mean_u, uemb_h, wc1mu, b1mu, u1_h);
  // layer 2
  k_gmean2<<<gGm, 256, 0, stream>>>(u1_h, m1_h, nbr, nodeoffM, nodeoffU, mean_m, mean_u);
  k_sage_gemm2<0><<<gG, 256, 0, stream>>>(mean_m, m1_h, wc2um, b2um, m2_h,
                                          mean_u, u1_h, wc2mu, b2mu, u2_h);

  // 32 edges per 256-thread block
  k_dot<<<(L + 31) / 32, 256, 0, stream>>>(u2_h, m2_h, eli_u, eli_m, (float*)d_out, L);
}

// Round 16
// 312.866 us; speedup vs baseline: 7.0329x; 1.1016x over previous
//
#include <hip/hip_runtime.h>
#include <hip/hip_fp16.h>

#define NU 100000
#define NM 50000
#define RM 4      // user-table sub-ranges (movie-dest gather source)
#define RU 2      // movie-table sub-ranges (user-dest gather source)
#define NBLK 256  // partition blocks
#define NBKT 196  // coarse buckets (50000>>8 -> 196, 100000>>9 -> 196)
#define NH (NBKT * NBLK)

typedef __attribute__((ext_vector_type(8))) _Float16 f16x8;
typedef __attribute__((ext_vector_type(4))) float f32x4;

__device__ __forceinline__ unsigned pk2h(float a, float b) {
  return __builtin_bit_cast(unsigned, __floats2half2_rn(a, b));
}
__device__ __forceinline__ __half2 shfl_xor_h2(__half2 v, int m) {
  return __builtin_bit_cast(__half2, __shfl_xor(__builtin_bit_cast(int, v), m));
}
__device__ __forceinline__ __half2 u2h2(unsigned v) {
  return __builtin_bit_cast(__half2, v);
}

// ---------- scan machinery (for the coarse hist matrix only) ----------
__global__ void k_scan_part(const int* __restrict__ cnt, int* __restrict__ off,
                            int* __restrict__ bsum, int n) {
  __shared__ int wsum[4];
  int t = threadIdx.x;
  int base = blockIdx.x * 1024 + t * 4;
  int v0 = (base + 0 < n) ? cnt[base + 0] : 0;
  int v1 = (base + 1 < n) ? cnt[base + 1] : 0;
  int v2 = (base + 2 < n) ? cnt[base + 2] : 0;
  int v3 = (base + 3 < n) ? cnt[base + 3] : 0;
  int s = v0 + v1 + v2 + v3;
  int lane = t & 63;
  int inc = s;
  #pragma unroll
  for (int d = 1; d < 64; d <<= 1) {
    int x = __shfl_up(inc, d);
    if (lane >= d) inc += x;
  }
  int wid = t >> 6;
  if (lane == 63) wsum[wid] = inc;
  __syncthreads();
  int woff = 0;
  for (int i = 0; i < wid; i++) woff += wsum[i];
  int excl = woff + inc - s;
  if (base + 0 < n) off[base + 0] = excl;
  if (base + 1 < n) off[base + 1] = excl + v0;
  if (base + 2 < n) off[base + 2] = excl + v0 + v1;
  if (base + 3 < n) off[base + 3] = excl + v0 + v1 + v2;
  if (t == 255) bsum[blockIdx.x] = woff + inc;
}

__global__ void k_scan_top(int* bsum, int nb) {
  int lane = threadIdx.x;
  int carry = 0;
  for (int base = 0; base < nb; base += 64) {
    int i = base + lane;
    int v = (i < nb) ? bsum[i] : 0;
    int inc = v;
    #pragma unroll
    for (int d = 1; d < 64; d <<= 1) {
      int x = __shfl_up(inc, d);
      if (lane >= d) inc += x;
    }
    if (i < nb) bsum[i] = carry + inc - v;
    carry += __shfl(inc, 63);
  }
}

__global__ void k_scan_add(int* __restrict__ off, const int* __restrict__ bsum,
                           int n, int total) {
  int i = blockIdx.x * blockDim.x + threadIdx.x;
  if (i < n) {
    off[i] = off[i] + bsum[i >> 10];
  } else if (i == n) {
    off[n] = total;
  }
}

// ---------- merged radix-partition build (both CSRs per pass) ----------
// 1024-thread blocks: same NBLK grid (preserves ~200B contiguous rec runs)
// but 16 waves/CU instead of 4 -- round-15 profile showed these kernels at
// 1 block/CU (4 waves) streaming 20MB each.
__global__ void __launch_bounds__(1024)
k_hist2(const int* __restrict__ esrc, const int* __restrict__ edst,
        int* __restrict__ hmat, int E) {
  __shared__ int hm[NBKT], hu[NBKT];
  int t = threadIdx.x;
  for (int b = t; b < NBKT; b += 1024) { hm[b] = 0; hu[b] = 0; }
  __syncthreads();
  int chunk = (E + NBLK - 1) / NBLK;
  int beg = blockIdx.x * chunk;
  int end = min(beg + chunk, E);
  for (int e = beg + t; e < end; e += 1024) {
    atomicAdd(&hm[edst[e] >> 8], 1);
    atomicAdd(&hu[esrc[e] >> 9], 1);
  }
  __syncthreads();
  for (int b = t; b < NBKT; b += 1024) {
    hmat[b * NBLK + blockIdx.x] = hm[b];
    hmat[NH + b * NBLK + blockIdx.x] = hu[b];
  }
}

// 4B packed records: (lkey << 17) | payload
__global__ void __launch_bounds__(1024)
k_part2(const int* __restrict__ esrc, const int* __restrict__ edst,
        const int* __restrict__ hbase, unsigned* __restrict__ rec_m,
        unsigned* __restrict__ rec_u, int E) {
  __shared__ int cm[NBKT], cu[NBKT];
  int t = threadIdx.x;
  for (int b = t; b < NBKT; b += 1024) {
    cm[b] = hbase[b * NBLK + blockIdx.x];
    cu[b] = hbase[NH + b * NBLK + blockIdx.x] - E;
  }
  __syncthreads();
  int chunk = (E + NBLK - 1) / NBLK;
  int beg = blockIdx.x * chunk;
  int end = min(beg + chunk, E);
  for (int e = beg + t; e < end; e += 1024) {
    int d = edst[e], s = esrc[e];
    unsigned lm = (unsigned)(d & 255) * RM + (unsigned)s / 25000u;
    int pm = atomicAdd(&cm[d >> 8], 1);
    rec_m[pm] = (lm << 17) | (unsigned)s;
    unsigned lu = (unsigned)(s & 511) * RU + (unsigned)d / 25000u;
    int pu = atomicAdd(&cu[s >> 9], 1);
    rec_u[pu] = (lu << 17) | (unsigned)d;
  }
}

// Merged count + LOCAL scan + scatter (see round 14). 1024 threads: the
// in-LDS scan is exactly 1 element/thread (wlen == 1024 for both halves).
__global__ void __launch_bounds__(1024)
k_bcsr(const unsigned* __restrict__ rec_m, const unsigned* __restrict__ rec_u,
       const int* __restrict__ hbase, int* __restrict__ nbr,
       int* __restrict__ nodeoffM, int* __restrict__ nodeoffU, int E) {
  __shared__ int lcnt[1024];
  __shared__ int wsum[16];
  int b = blockIdx.x, t = threadIdx.x;
  bool mv = b < NBKT;
  int bb = mv ? b : b - NBKT;
  const unsigned* rec = mv ? rec_m : rec_u;
  int R = mv ? RM : RU, SH = mv ? 8 : 9, N = mv ? NM : NU;
  int* nodeoff = mv ? nodeoffM : nodeoffU;
  int rs = mv ? hbase[bb * NBLK] : hbase[NH + bb * NBLK] - E;
  int re = mv ? hbase[(bb + 1) * NBLK] : hbase[NH + (bb + 1) * NBLK] - E;
  int nbase = mv ? 0 : E;  // nbr region offset for this half
  int node_lo = bb << SH;
  int node_hi = min(node_lo + (1 << SH), N);
  lcnt[t] = 0;
  __syncthreads();
  for (int r = rs + t; r < re; r += 1024)
    atomicAdd(&lcnt[rec[r] >> 17], 1);
  __syncthreads();
  // block-wide exclusive scan of lcnt (1 elem/thread), rebased to nbase+rs
  int v = lcnt[t];
  int lane = t & 63;
  int inc = v;
  #pragma unroll
  for (int d = 1; d < 64; d <<= 1) {
    int x = __shfl_up(inc, d);
    if (lane >= d) inc += x;
  }
  int wid = t >> 6;
  if (lane == 63) wsum[wid] = inc;
  __syncthreads();
  int woff = 0;
  for (int k = 0; k < wid; k++) woff += wsum[k];
  int p = nbase + rs + woff + inc - v;  // exclusive prefix
  __syncthreads();
  lcnt[t] = p;
  // publish node-level offsets (keys with range==0)
  if (R == 4) {
    if ((t & 3) == 0) {
      int node = node_lo + (t >> 2);
      if (node < node_hi) nodeoff[node] = p;
    }
  } else {
    if ((t & 1) == 0) {
      int node = node_lo + (t >> 1);
      if (node < node_hi) nodeoff[node] = p;
    }
  }
  if (t == 0) nodeoff[node_hi] = nbase + re;  // benign same-value race with next bucket
  __syncthreads();
  // scatter (rec chunk L2-hot)
  for (int r = rs + t; r < re; r += 1024) {
    unsigned q = rec[r];
    int pp = atomicAdd(&lcnt[q >> 17], 1);
    nbr[pp] = (int)(q & 0x1FFFFu);
  }
}

// ---------- fused feature prep: user-emb f32->f16 | movie init | weight pack ----------
#define PREP_U 6250    // NU*64/4/256
#define PREP_M 12500   // (NM+3)/4
__global__ void __launch_bounds__(256)
k_prep(const float4* __restrict__ uemb4, unsigned short* __restrict__ uemb_h,
       const float* __restrict__ movie_x, const float* __restrict__ lin_W,
       const float* __restrict__ lin_b, const float* __restrict__ movie_emb,
       unsigned short* __restrict__ x_movie,
       const float* __restrict__ Wl0, const float* __restrict__ Wr0,
       const float* __restrict__ Wl1, const float* __restrict__ Wr1,
       const float* __restrict__ Wl2, const float* __restrict__ Wr2,
       const float* __restrict__ Wl3, const float* __restrict__ Wr3,
       unsigned short* __restrict__ Wc) {
  __shared__ float lwT[20 * 65];
  int b = blockIdx.x;
  if (b < PREP_U) {
    int i = b * 256 + threadIdx.x;  // < NU*16
    float4 v = uemb4[i];
    uint2 o;
    o.x = pk2h(v.x, v.y);
    o.y = pk2h(v.z, v.w);
    *(uint2*)(uemb_h + (size_t)i * 4) = o;
  } else if (b < PREP_U + PREP_M) {
    int bb = b - PREP_U;
    for (int gidx = threadIdx.x; gidx < 64 * 20; gidx += 256) {
      int h = gidx / 20;
      int f = gidx - h * 20;
      lwT[f * 65 + h] = lin_W[gidx];
    }
    __syncthreads();
    int w = (bb * 256 + (int)threadIdx.x) >> 6;
    int h = threadIdx.x & 63;
    if (w >= NM) return;
    float acc = lin_b[h] + movie_emb[(size_t)w * 64 + h];
    const float* mx = movie_x + (size_t)w * 20;
    #pragma unroll
    for (int f = 0; f < 20; f++) acc += mx[f] * lwT[f * 65 + h];
    x_movie[(size_t)w * 64 + h] = __builtin_bit_cast(unsigned short, (__half)__float2half(acc));
  } else {
    int wb = b - PREP_U - PREP_M;  // 0..127
    int which = wb >> 5;
    const float* Wl = which == 0 ? Wl0 : which == 1 ? Wl1 : which == 2 ? Wl2 : Wl3;
    const float* Wr = which == 0 ? Wr0 : which == 1 ? Wr1 : which == 2 ? Wr2 : Wr3;
    int i = (wb & 31) * 256 + threadIdx.x;
    if (i >= 8192) return;
    int h = i >> 7, k = i & 127;
    float v = (k < 64) ? Wl[h * 64 + k] : Wr[h * 64 + (k - 64)];
    Wc[which * 8192 + i] = __builtin_bit_cast(unsigned short, (__half)__float2half(v));
  }
}

// ---------- mean-gather, both relations in one dispatch ----------
__global__ void __launch_bounds__(256)
k_gmean2(const unsigned short* __restrict__ xsrcM,
         const unsigned short* __restrict__ xsrcU,
         const int* __restrict__ nbr,
         const int* __restrict__ nodeoffM, const int* __restrict__ nodeoffU,
         unsigned short* __restrict__ meanM, unsigned short* __restrict__ meanU) {
  int gw = (blockIdx.x * blockDim.x + threadIdx.x) >> 6;
  int lane = threadIdx.x & 63;
  if (gw >= NM + NU) return;  // wave-uniform
  bool mv = gw < NM;
  const char* xb = (const char*)(mv ? xsrcM : xsrcU);
  const int* noff = mv ? nodeoffM : nodeoffU;
  int w = mv ? gw : gw - NM;
  unsigned short* meanT = mv ? meanM : meanU;
  int g = lane >> 3;
  unsigned ib = (unsigned)(lane & 7) * 16;  // byte sub-offset within 128B row
  __half2 aa2[4];
  #pragma unroll
  for (int k = 0; k < 4; k++) aa2[k] = u2h2(0u);

  int s0 = noff[w], eN = noff[w + 1];
  int deg = eN - s0;
  int base = s0;
  // full 32-row windows: no clamps, no masks
  for (int nf = deg >> 5; nf > 0; nf--, base += 32) {
    int my = nbr[base + (lane & 31)];
    int j0 = __shfl(my, 0 * 8 + g);
    int j1 = __shfl(my, 1 * 8 + g);
    int j2 = __shfl(my, 2 * 8 + g);
    int j3 = __shfl(my, 3 * 8 + g);
    uint4 d0 = *(const uint4*)(xb + ((unsigned)(j0 << 7) + ib));
    uint4 d1 = *(const uint4*)(xb + ((unsigned)(j1 << 7) + ib));
    uint4 d2 = *(const uint4*)(xb + ((unsigned)(j2 << 7) + ib));
    uint4 d3 = *(const uint4*)(xb + ((unsigned)(j3 << 7) + ib));
    #define ADD4(dd)                                   \
      aa2[0] = __hadd2(aa2[0], u2h2(dd.x));            \
      aa2[1] = __hadd2(aa2[1], u2h2(dd.y));            \
      aa2[2] = __hadd2(aa2[2], u2h2(dd.z));            \
      aa2[3] = __hadd2(aa2[3], u2h2(dd.w));
    ADD4(d0) ADD4(d1) ADD4(d2) ADD4(d3)
    #undef ADD4
  }
  // masked tail window (rem in [1,31])
  int rem = eN - base;
  if (rem > 0) {
    int lim = rem - 1;
    int my = nbr[base + (lane < rem ? lane : 0)];
    uint4 d0, d1, d2, d3;
    int j0 = __shfl(my, min(0 * 8 + g, lim));
    int j1 = __shfl(my, min(1 * 8 + g, lim));
    d0 = *(const uint4*)(xb + ((unsigned)(j0 << 7) + ib));
    d1 = *(const uint4*)(xb + ((unsigned)(j1 << 7) + ib));
    bool hi = rem > 16;
    if (hi) {
      int j2 = __shfl(my, min(2 * 8 + g, lim));
      int j3 = __shfl(my, min(3 * 8 + g, lim));
      d2 = *(const uint4*)(xb + ((unsigned)(j2 << 7) + ib));
      d3 = *(const uint4*)(xb + ((unsigned)(j3 << 7) + ib));
    }
    #define CONSUME(dd, c)                                              \
      {                                                                 \
        unsigned mcu = ((c) * 8 + g < rem) ? 0x3C003C00u : 0u;          \
        __half2 mc2 = u2h2(mcu);                                        \
        aa2[0] = __hfma2(u2h2(dd.x), mc2, aa2[0]);                      \
        aa2[1] = __hfma2(u2h2(dd.y), mc2, aa2[1]);                      \
        aa2[2] = __hfma2(u2h2(dd.z), mc2, aa2[2]);                      \
        aa2[3] = __hfma2(u2h2(dd.w), mc2, aa2[3]);                      \
      }
    CONSUME(d0, 0)
    CONSUME(d1, 1)
    if (hi) {
      CONSUME(d2, 2)
      CONSUME(d3, 3)
    }
    #undef CONSUME
  }
  // cross-row-slot reduce over g (lane bits 3..5), packed adds
  #pragma unroll
  for (int m = 8; m <= 32; m <<= 1) {
    #pragma unroll
    for (int k = 0; k < 4; k++) aa2[k] = __hadd2(aa2[k], shfl_xor_h2(aa2[k], m));
  }
  float inv = 1.0f / fmaxf((float)deg, 1.0f);
  if (g == 0) {
    __half2 invh = __float2half2_rn(inv);
    uint4 o;
    o.x = __builtin_bit_cast(unsigned, __hmul2(aa2[0], invh));
    o.y = __builtin_bit_cast(unsigned, __hmul2(aa2[1], invh));
    o.z = __builtin_bit_cast(unsigned, __hmul2(aa2[2], invh));
    o.w = __builtin_bit_cast(unsigned, __hmul2(aa2[3], invh));
    *(uint4*)((char*)meanT + ((unsigned)(w << 7) + ib)) = o;
  }
}

// ---------- SAGE transform as f16 MFMA GEMM, both relations in one dispatch ----------
template <int RELU>
__global__ void __launch_bounds__(256)
k_sage_gemm2(const unsigned short* __restrict__ meanM, const unsigned short* __restrict__ dvM,
             const unsigned short* __restrict__ WcM, const float* __restrict__ biasM,
             unsigned short* __restrict__ outM,
             const unsigned short* __restrict__ meanU, const unsigned short* __restrict__ dvU,
             const unsigned short* __restrict__ WcU, const float* __restrict__ biasU,
             unsigned short* __restrict__ outU) {
  __shared__ float ot[4][16][68];
  const int tM = NM / 16, tU = NU / 16;
  int wv4 = threadIdx.x >> 6;
  int wvg = (blockIdx.x * blockDim.x + threadIdx.x) >> 6;
  int lane = threadIdx.x & 63;
  bool active = wvg < tM + tU;
  bool mv = wvg < tM;
  const unsigned short* meanT = mv ? meanM : meanU;
  const unsigned short* dvT = mv ? dvM : dvU;
  const unsigned short* Wc = mv ? WcM : WcU;
  const float* bias = mv ? biasM : biasU;
  unsigned short* outT = mv ? outM : outU;
  int n0 = (mv ? wvg : wvg - tM) * 16;
  int rr = lane & 15;
  int ks = lane >> 4;

  if (active) {
    f16x8 bf[4][4];
    #pragma unroll
    for (int t = 0; t < 4; t++)
      #pragma unroll
      for (int kk = 0; kk < 4; kk++)
        bf[t][kk] = *(const f16x8*)((const char*)Wc + (unsigned)(((t * 16 + rr) << 8) + kk * 64 + ks * 16));
    f32x4 acc[4];
    #pragma unroll
    for (int t = 0; t < 4; t++) {
      float b = bias[t * 16 + rr];
      acc[t] = (f32x4){b, b, b, b};
    }
    const char* am = (const char*)meanT + (unsigned)((n0 + rr) << 7);
    const char* ad = (const char*)dvT + (unsigned)((n0 + rr) << 7);
    f16x8 af[4];
    af[0] = *(const f16x8*)(am + ks * 16);
    af[1] = *(const f16x8*)(am + 64 + ks * 16);
    af[2] = *(const f16x8*)(ad + ks * 16);
    af[3] = *(const f16x8*)(ad + 64 + ks * 16);
    #pragma unroll
    for (int kk = 0; kk < 4; kk++)
      #pragma unroll
      for (int t = 0; t < 4; t++)
        acc[t] = __builtin_amdgcn_mfma_f32_16x16x32_f16(af[kk], bf[t][kk], acc[t], 0, 0, 0);
    #pragma unroll
    for (int t = 0; t < 4; t++)
      #pragma unroll
      for (int r = 0; r < 4; r++) {
        float v = acc[t][r];
        if (RELU) v = fmaxf(v, 0.f);
        ot[wv4][(lane >> 4) * 4 + r][t * 16 + rr] = v;
      }
  }
  __syncthreads();
  if (active) {
    int nn = lane >> 2, c4 = lane & 3;
    const float* src = &ot[wv4][nn][c4 * 16];
    uint4 o0, o1;
    o0.x = pk2h(src[0], src[1]);  o0.y = pk2h(src[2], src[3]);
    o0.z = pk2h(src[4], src[5]);  o0.w = pk2h(src[6], src[7]);
    o1.x = pk2h(src[8], src[9]);  o1.y = pk2h(src[10], src[11]);
    o1.z = pk2h(src[12], src[13]); o1.w = pk2h(src[14], src[15]);
    unsigned short* dst = outT + ((size_t)(n0 + nn) << 6) + c4 * 16;
    *(uint4*)dst = o0;
    *(uint4*)(dst + 8) = o1;
  }
}

// 8 lanes per edge on f16 rows (one uint4 = 16B/lane, 128B/row), shfl_xor
// reduce within 8-lane group. 32 edges per 256-thread block.
__global__ void __launch_bounds__(256)
k_dot(const unsigned short* __restrict__ u2, const unsigned short* __restrict__ m2,
      const int* __restrict__ eu, const int* __restrict__ em,
      float* __restrict__ out, int L) {
  int wave = (blockIdx.x * blockDim.x + threadIdx.x) >> 6;
  int lane = threadIdx.x & 63;
  int sub = lane & 7;
  int l = wave * 8 + (lane >> 3);
  int lc = l < L ? l : (L - 1);
  int iu = eu[lc], im = em[lc];
  uint4 a = *(const uint4*)((const char*)u2 + ((unsigned)(iu << 7) + sub * 16));
  uint4 b = *(const uint4*)((const char*)m2 + ((unsigned)(im << 7) + sub * 16));
  float2 a0 = __half22float2(u2h2(a.x)), b0 = __half22float2(u2h2(b.x));
  float2 a1 = __half22float2(u2h2(a.y)), b1 = __half22float2(u2h2(b.y));
  float2 a2 = __half22float2(u2h2(a.z)), b2 = __half22float2(u2h2(b.z));
  float2 a3 = __half22float2(u2h2(a.w)), b3 = __half22float2(u2h2(b.w));
  float s = a0.x * b0.x + a0.y * b0.y + a1.x * b1.x + a1.y * b1.y
          + a2.x * b2.x + a2.y * b2.y + a3.x * b3.x + a3.y * b3.y;
  s += __shfl_xor(s, 1);
  s += __shfl_xor(s, 2);
  s += __shfl_xor(s, 4);
  if (sub == 0 && l < L) out[l] = s;
}

extern "C" void kernel_launch(void* const* d_in, const int* in_sizes, int n_in,
                              void* d_out, int out_size, void* d_ws, size_t ws_size,
                              hipStream_t stream) {
  const float* movie_x   = (const float*)d_in[2];
  const int*   esrc      = (const int*)d_in[3];
  const int*   edst      = (const int*)d_in[4];
  const int*   eli_u     = (const int*)d_in[5];
  const int*   eli_m     = (const int*)d_in[6];
  const float* user_emb  = (const float*)d_in[7];
  const float* movie_emb = (const float*)d_in[8];
  const float* lin_W     = (const float*)d_in[9];
  const float* lin_b     = (const float*)d_in[10];
  const float* W1um_l = (const float*)d_in[11];
  const float* W1um_r = (const float*)d_in[12];
  const float* W1mu_l = (const float*)d_in[13];
  const float* W1mu_r = (const float*)d_in[14];
  const float* W2um_l = (const float*)d_in[15];
  const float* W2um_r = (const float*)d_in[16];
  const float* W2mu_l = (const float*)d_in[17];
  const float* W2mu_r = (const float*)d_in[18];
  const float* b1um = (const float*)d_in[19];
  const float* b1mu = (const float*)d_in[20];
  const float* b2um = (const float*)d_in[21];
  const float* b2mu = (const float*)d_in[22];
  const int E = in_sizes[3];
  const int L = in_sizes[5];

  char* ws = (char*)d_ws;
  size_t o = 0;
  auto alloc = [&](size_t bytes) -> void* {
    void* p = ws + o;
    o = (o + bytes + 255) & ~(size_t)255;
    return p;
  };
  unsigned short* uemb_h   = (unsigned short*)alloc((size_t)NU * 64 * 2);
  unsigned short* xmovie_h = (unsigned short*)alloc((size_t)NM * 64 * 2);
  unsigned short* m1_h     = (unsigned short*)alloc((size_t)NM * 64 * 2);
  unsigned short* u1_h     = (unsigned short*)alloc((size_t)NU * 64 * 2);
  unsigned short* m2_h     = (unsigned short*)alloc((size_t)NM * 64 * 2);
  unsigned short* u2_h     = (unsigned short*)alloc((size_t)NU * 64 * 2);
  unsigned short* mean_m   = (unsigned short*)alloc((size_t)NM * 64 * 2);
  unsigned short* mean_u   = (unsigned short*)alloc((size_t)NU * 64 * 2);
  unsigned short* wcat     = (unsigned short*)alloc(4 * 8192 * 2);
  int* nodeoffM = (int*)alloc((size_t)(NM + 1) * 4);
  int* nodeoffU = (int*)alloc((size_t)(NU + 1) * 4);
  int* bs    = (int*)alloc(4096);
  int* nbr   = (int*)alloc((size_t)2 * E * 4);
  int* hmat  = (int*)alloc((size_t)(2 * NH + 1) * 4);
  int* hbase = (int*)alloc((size_t)(2 * NH + 1) * 4);
  // rec buffers (E x 4B = 10MB each) overlay dead table regions during build.
  unsigned* rec_m = (unsigned*)uemb_h;
  unsigned* rec_u = (unsigned*)u1_h;

  // ===== merged CSR build =====
  k_hist2<<<NBLK, 1024, 0, stream>>>(esrc, edst, hmat, E);
  {
    int n = 2 * NH, nb = (n + 1023) / 1024;
    k_scan_part<<<nb, 256, 0, stream>>>(hmat, hbase, bs, n);
    k_scan_top<<<1, 64, 0, stream>>>(bs, nb);
    k_scan_add<<<(n + 1 + 255) / 256, 256, 0, stream>>>(hbase, bs, n, 2 * E);
  }
  k_part2<<<NBLK, 1024, 0, stream>>>(esrc, edst, hbase, rec_m, rec_u, E);
  k_bcsr<<<2 * NBKT, 1024, 0, stream>>>(rec_m, rec_u, hbase, nbr, nodeoffM, nodeoffU, E);

  // ===== fused feature prep (rec overlays now dead) =====
  k_prep<<<PREP_U + PREP_M + 128, 256, 0, stream>>>(
      (const float4*)user_emb, uemb_h, movie_x, lin_W, lin_b, movie_emb, xmovie_h,
      W1um_l, W1um_r, W1mu_l, W1mu_r, W2um_l, W2um_r, W2mu_l, W2mu_r, wcat);
  unsigned short* wc1um = wcat;
  unsigned short* wc1mu = wcat + 8192;
  unsigned short* wc2um = wcat + 16384;
  unsigned short* wc2mu = wcat + 24576;

  int gGm = (NM + NU + 3) / 4;
  int gG = ((NM / 16 + NU / 16) + 3) / 4;
  // layer 1
  k_gmean2<<<gGm, 256, 0, stream>>>(uemb_h, xmovie_h, nbr, nodeoffM, nodeoffU, mean_m, mean_u);
  k_sage_gemm2<1><<<gG, 256, 0, stream>>>(mean_m, xmovie_h, wc1um, b1um, m1_h,
                                          mean_u, uemb_h, wc1mu, b1mu, u1_h);
  // layer 2
  k_gmean2<<<gGm, 256, 0, stream>>>(u1_h, m1_h, nbr, nodeoffM, nodeoffU, mean_m, mean_u);
  k_sage_gemm2<0><<<gG, 256, 0, stream>>>(mean_m, m1_h, wc2um, b2um, m2_h,
                                          mean_u, u1_h, wc2mu, b2mu, u2_h);

  // 32 edges per 256-thread block
  k_dot<<<(L + 31) / 32, 256, 0, stream>>>(u2_h, m2_h, eli_u, eli_m, (float*)d_out, L);
}